// Round 1
// baseline (2547.018 us; speedup 1.0000x reference)
//
#include <hip/hip_runtime.h>

#define FIN 6
#define CC 64

// ---------------- CSR build ----------------
__global__ void k_hist(const int* __restrict__ dst, int* __restrict__ deg, int E) {
  int e = blockIdx.x * 256 + threadIdx.x;
  if (e < E) atomicAdd(&deg[dst[e]], 1);
}

__global__ __launch_bounds__(256) void k_scan_local(const int* __restrict__ in,
                                                    int* __restrict__ out,
                                                    int* __restrict__ bsum, int n) {
  __shared__ int lds[256];
  int t = threadIdx.x;
  int base = blockIdx.x * 1024 + t * 4;
  int v0 = 0, v1 = 0, v2 = 0, v3 = 0;
  if (base + 0 < n) v0 = in[base + 0];
  if (base + 1 < n) v1 = in[base + 1];
  if (base + 2 < n) v2 = in[base + 2];
  if (base + 3 < n) v3 = in[base + 3];
  int s = v0 + v1 + v2 + v3;
  lds[t] = s; __syncthreads();
  int acc = s;
  for (int o = 1; o < 256; o <<= 1) {
    int add = (t >= o) ? lds[t - o] : 0;
    __syncthreads();
    acc += add; lds[t] = acc;
    __syncthreads();
  }
  if (t == 255) bsum[blockIdx.x] = acc;
  int run = acc - s;  // exclusive prefix for this thread
  if (base + 0 < n) out[base + 0] = run; run += v0;
  if (base + 1 < n) out[base + 1] = run; run += v1;
  if (base + 2 < n) out[base + 2] = run; run += v2;
  if (base + 3 < n) out[base + 3] = run;
}

__global__ __launch_bounds__(256) void k_scan_bsum(int* bsum, int nb) {
  __shared__ int lds[256];
  int t = threadIdx.x;
  int s = (t < nb) ? bsum[t] : 0;
  lds[t] = s; __syncthreads();
  int acc = s;
  for (int o = 1; o < 256; o <<= 1) {
    int add = (t >= o) ? lds[t - o] : 0;
    __syncthreads();
    acc += add; lds[t] = acc;
    __syncthreads();
  }
  if (t < nb) bsum[t] = acc - s;  // exclusive
}

__global__ void k_scan_add(int* __restrict__ out, const int* __restrict__ bsum, int n) {
  int i = blockIdx.x * 256 + threadIdx.x;
  if (i < n) out[i] += bsum[i >> 10];
}

__global__ void k_cursor(int* __restrict__ off, int* __restrict__ cur, int n, int E) {
  int i = blockIdx.x * 256 + threadIdx.x;
  if (i < n) cur[i] = off[i];
  if (i == 0) off[n] = E;
}

__global__ void k_fill(const int* __restrict__ src, const int* __restrict__ dst,
                       int* __restrict__ cur, int* __restrict__ csr, int E) {
  int e = blockIdx.x * 256 + threadIdx.x;
  if (e < E) {
    int p = atomicAdd(&cur[dst[e]], 1);
    csr[p] = src[e];
  }
}

__global__ void k_bounds(const int* __restrict__ batch, int* __restrict__ gstart, int n, int G) {
  int i = blockIdx.x * 256 + threadIdx.x;
  if (i >= n) return;
  int b = batch[i];
  if (i == 0) { for (int g = 0; g <= b; ++g) gstart[g] = 0; }
  else { int pb = batch[i - 1]; for (int g = pb + 1; g <= b; ++g) gstart[g] = i; }
  if (i == n - 1) { for (int g = b + 1; g <= G; ++g) gstart[g] = n; }
}

// ---------------- GIN layer 1 (agg 6ch + MLP 6->64 relu ->64) ----------------
__global__ __launch_bounds__(256) void k_gin1(const float* __restrict__ x,
    const int* __restrict__ off, const int* __restrict__ csr,
    const float* __restrict__ W1, const float* __restrict__ b1,
    const float* __restrict__ W2, const float* __restrict__ b2,
    float* __restrict__ hout, int n) {
  __shared__ float sW1[FIN * 64], sW2[64 * 64], sb1[64], sb2[64], sh1[256];
  int t = threadIdx.x;
  for (int j = t; j < FIN * 64; j += 256) sW1[j] = W1[j];
  for (int j = t; j < 64 * 64; j += 256) sW2[j] = W2[j];
  if (t < 64) { sb1[t] = b1[t]; sb2[t] = b2[t]; }
  __syncthreads();
  int w = t >> 6, lane = t & 63;
  int i = blockIdx.x * 4 + w;
  bool alive = i < n;
  float h1 = 0.f;
  if (alive) {
    int e0 = off[i], e1 = off[i + 1];
    float a0 = 0, a1 = 0, a2 = 0, a3 = 0, a4 = 0, a5 = 0;
    for (int e = e0 + lane; e < e1; e += 64) {
      const float* xr = x + (size_t)csr[e] * FIN;
      a0 += xr[0]; a1 += xr[1]; a2 += xr[2]; a3 += xr[3]; a4 += xr[4]; a5 += xr[5];
    }
    #pragma unroll
    for (int m = 1; m < 64; m <<= 1) {
      a0 += __shfl_xor(a0, m); a1 += __shfl_xor(a1, m); a2 += __shfl_xor(a2, m);
      a3 += __shfl_xor(a3, m); a4 += __shfl_xor(a4, m); a5 += __shfl_xor(a5, m);
    }
    const float* xi = x + (size_t)i * FIN;
    float h0[FIN] = {xi[0] + a0, xi[1] + a1, xi[2] + a2, xi[3] + a3, xi[4] + a4, xi[5] + a5};
    h1 = sb1[lane];
    #pragma unroll
    for (int k = 0; k < FIN; ++k) h1 = fmaf(h0[k], sW1[k * 64 + lane], h1);
    h1 = fmaxf(h1, 0.f);
  }
  sh1[t] = h1;
  __syncthreads();
  if (alive) {
    float h2 = sb2[lane];
    #pragma unroll
    for (int k = 0; k < 64; ++k) h2 = fmaf(sh1[(t & 192) + k], sW2[k * 64 + lane], h2);
    hout[(size_t)i * 64 + lane] = h2;
  }
}

// ---------------- GIN layer 2 (agg 64ch + MLP 64->64 relu ->64) ----------------
__global__ __launch_bounds__(256) void k_gin2(const float* __restrict__ y,
    const int* __restrict__ off, const int* __restrict__ csr,
    const float* __restrict__ W3, const float* __restrict__ b3,
    const float* __restrict__ W4, const float* __restrict__ b4,
    float* __restrict__ zout, int n) {
  __shared__ float sW3[64 * 64], sW4[64 * 64], sb3[64], sb4[64], sh0[256], sh1[256];
  int t = threadIdx.x;
  for (int j = t; j < 64 * 64; j += 256) { sW3[j] = W3[j]; sW4[j] = W4[j]; }
  if (t < 64) { sb3[t] = b3[t]; sb4[t] = b4[t]; }
  __syncthreads();
  int w = t >> 6, lane = t & 63;
  int i = blockIdx.x * 4 + w;
  bool alive = i < n;
  float h0 = 0.f;
  if (alive) {
    int e0 = off[i], e1 = off[i + 1];
    float acc = y[(size_t)i * 64 + lane];   // self term
    int e = e0;
    for (; e + 4 <= e1; e += 4) {
      int s0 = csr[e], s1 = csr[e + 1], s2 = csr[e + 2], s3 = csr[e + 3];
      float v0 = y[(size_t)s0 * 64 + lane];
      float v1 = y[(size_t)s1 * 64 + lane];
      float v2 = y[(size_t)s2 * 64 + lane];
      float v3 = y[(size_t)s3 * 64 + lane];
      acc += v0; acc += v1; acc += v2; acc += v3;
    }
    for (; e < e1; ++e) acc += y[(size_t)csr[e] * 64 + lane];
    h0 = acc;
  }
  sh0[t] = h0;
  __syncthreads();
  float h1v = sb3[lane];
  #pragma unroll
  for (int k = 0; k < 64; ++k) h1v = fmaf(sh0[(t & 192) + k], sW3[k * 64 + lane], h1v);
  h1v = fmaxf(h1v, 0.f);
  sh1[t] = h1v;
  __syncthreads();
  if (alive) {
    float h2 = sb4[lane];
    #pragma unroll
    for (int k = 0; k < 64; ++k) h2 = fmaf(sh1[(t & 192) + k], sW4[k * 64 + lane], h2);
    zout[(size_t)i * 64 + lane] = h2;
  }
}

// ---------------- graph LayerNorm stats (block per graph) ----------------
__global__ __launch_bounds__(256) void k_ln_stats(const float* __restrict__ h,
    const int* __restrict__ gstart, float* __restrict__ gmean, float* __restrict__ ginv) {
  int g = blockIdx.x;
  int s0 = gstart[g], s1 = gstart[g + 1];
  size_t j0 = (size_t)s0 * 64, j1 = (size_t)s1 * 64;
  float s = 0.f, ss = 0.f;
  for (size_t j = j0 + threadIdx.x; j < j1; j += 256) {
    float v = h[j]; s += v; ss += v * v;
  }
  __shared__ float l1[256], l2[256];
  l1[threadIdx.x] = s; l2[threadIdx.x] = ss;
  __syncthreads();
  for (int o = 128; o > 0; o >>= 1) {
    if (threadIdx.x < o) { l1[threadIdx.x] += l1[threadIdx.x + o]; l2[threadIdx.x] += l2[threadIdx.x + o]; }
    __syncthreads();
  }
  if (threadIdx.x == 0) {
    float cnt = (float)(s1 - s0);
    float norm = fmaxf(cnt, 1.f) * 64.f;
    float mean = l1[0] / norm;
    float var = l2[0] / norm - mean * mean;
    var = fmaxf(var, 0.f);
    gmean[g] = mean;
    ginv[g] = rsqrtf(var + 1e-5f);
  }
}

// ---------------- LN apply + relu (in place) ----------------
__global__ void k_ln_apply_relu(float* __restrict__ h, const int* __restrict__ batch,
    const float* __restrict__ gmean, const float* __restrict__ ginv,
    const float* __restrict__ w, const float* __restrict__ bb, int n) {
  int tt = blockIdx.x * 256 + threadIdx.x;
  if (tt >= n * 64) return;
  int i = tt >> 6, c = tt & 63;
  int g = batch[i];
  float v = (h[tt] - gmean[g]) * ginv[g] * w[c] + bb[c];
  h[tt] = fmaxf(v, 0.f);
}

// ---------------- pool: emb = sum(relu(ln2(z))) + mean ----------------
__global__ __launch_bounds__(256) void k_pool(const float* __restrict__ z,
    const int* __restrict__ gstart, const float* __restrict__ gmean, const float* __restrict__ ginv,
    const float* __restrict__ w, const float* __restrict__ bb, float* __restrict__ emb) {
  int g = blockIdx.x;
  int s0 = gstart[g], s1 = gstart[g + 1];
  int t = threadIdx.x, c = t & 63, sub = t >> 6;
  float mean = gmean[g], inv = ginv[g], wc = w[c], bc = bb[c];
  float acc = 0.f;
  for (int i = s0 + sub; i < s1; i += 4) {
    float v = (z[(size_t)i * 64 + c] - mean) * inv * wc + bc;
    acc += fmaxf(v, 0.f);
  }
  __shared__ float lds[256];
  lds[t] = acc;
  __syncthreads();
  if (sub == 0) {
    float tot = lds[c] + lds[64 + c] + lds[128 + c] + lds[192 + c];
    float cnt = fmaxf((float)(s1 - s0), 1.f);
    emb[g * 64 + c] = tot + tot / cnt;
  }
}

// ---------------- head MLP: [138]->128 relu ->64 relu ->1 ----------------
__global__ __launch_bounds__(128) void k_head(const float* __restrict__ emb1,
    const float* __restrict__ emb2, const float* __restrict__ d1, const float* __restrict__ d2,
    const float* __restrict__ Wf1, const float* __restrict__ bf1,
    const float* __restrict__ Wf2, const float* __restrict__ bf2,
    const float* __restrict__ Wo, const float* __restrict__ bo, float* __restrict__ out) {
  int g = blockIdx.x, t = threadIdx.x;
  __shared__ float v[138], h1s[128], h2s[64];
  if (t < 64) v[t] = emb1[g * 64 + t];
  else v[t] = emb2[g * 64 + (t - 64)];
  if (t < 5) v[128 + t] = d1[g * 5 + t];
  else if (t < 10) v[133 + (t - 5)] = d2[g * 5 + (t - 5)];
  __syncthreads();
  float a = bf1[t];
  for (int k = 0; k < 138; ++k) a = fmaf(v[k], Wf1[k * 128 + t], a);
  h1s[t] = fmaxf(a, 0.f);
  __syncthreads();
  if (t < 64) {
    float a2 = bf2[t];
    #pragma unroll 8
    for (int k = 0; k < 128; ++k) a2 = fmaf(h1s[k], Wf2[k * 64 + t], a2);
    h2s[t] = fmaxf(a2, 0.f);
  }
  __syncthreads();
  if (t == 0) {
    float s = bo[0];
    for (int k = 0; k < 64; ++k) s += h2s[k] * Wo[k];
    out[g] = s;
  }
}

extern "C" void kernel_launch(void* const* d_in, const int* in_sizes, int n_in,
                              void* d_out, int out_size, void* d_ws, size_t ws_size,
                              hipStream_t stream) {
  const float* x1     = (const float*)d_in[0];
  const int*   ei1    = (const int*)d_in[1];
  const int*   batch1 = (const int*)d_in[2];
  const float* x2     = (const float*)d_in[3];
  const int*   ei2    = (const int*)d_in[4];
  const int*   batch2 = (const int*)d_in[5];
  const float* d1     = (const float*)d_in[6];
  const float* d2     = (const float*)d_in[7];
  const float* W1  = (const float*)d_in[8],  *b1  = (const float*)d_in[9];
  const float* W2  = (const float*)d_in[10], *b2  = (const float*)d_in[11];
  const float* ln1w = (const float*)d_in[12], *ln1b = (const float*)d_in[13];
  const float* W3  = (const float*)d_in[14], *b3  = (const float*)d_in[15];
  const float* W4  = (const float*)d_in[16], *b4  = (const float*)d_in[17];
  const float* ln2w = (const float*)d_in[18], *ln2b = (const float*)d_in[19];
  const float* Wf1 = (const float*)d_in[20], *bf1 = (const float*)d_in[21];
  const float* Wf2 = (const float*)d_in[22], *bf2 = (const float*)d_in[23];
  const float* Wo  = (const float*)d_in[24], *bo  = (const float*)d_in[25];
  float* out = (float*)d_out;

  const int N = in_sizes[0] / FIN;
  const int E = in_sizes[1] / 2;
  const int G = in_sizes[6] / 5;

  // workspace carve (256B aligned)
  char* p = (char*)d_ws;
  auto alloc = [&](size_t bytes) { void* r = p; p += (bytes + 255) & ~(size_t)255; return r; };
  int*   off    = (int*)alloc((size_t)(N + 1) * 4);
  int*   cur    = (int*)alloc((size_t)N * 4);
  int*   deg    = (int*)alloc((size_t)N * 4);
  int*   bsum   = (int*)alloc(1024 * 4);
  int*   csr    = (int*)alloc((size_t)E * 4);
  int*   gstart = (int*)alloc((size_t)(G + 1) * 4);
  float* gmean  = (float*)alloc((size_t)G * 4);
  float* ginv   = (float*)alloc((size_t)G * 4);
  float* h      = (float*)alloc((size_t)N * 64 * 4);
  float* z      = (float*)alloc((size_t)N * 64 * 4);
  float* emb1   = (float*)alloc((size_t)G * 64 * 4);
  float* emb2   = (float*)alloc((size_t)G * 64 * 4);

  const int NB      = (N + 1023) / 1024;
  const int GRID_N  = (N + 255) / 256;
  const int GRID_E  = (E + 255) / 256;
  const int GRID_W  = (N + 3) / 4;        // wave-per-node kernels
  const int GRID_NC = (N * 64 + 255) / 256;

  auto run_graph = [&](const float* x, const int* ei, const int* batch, float* emb) {
    const int* src = ei;
    const int* dst = ei + E;
    hipMemsetAsync(deg, 0, (size_t)N * 4, stream);
    k_hist<<<GRID_E, 256, 0, stream>>>(dst, deg, E);
    k_scan_local<<<NB, 256, 0, stream>>>(deg, off, bsum, N);
    k_scan_bsum<<<1, 256, 0, stream>>>(bsum, NB);
    k_scan_add<<<GRID_N, 256, 0, stream>>>(off, bsum, N);
    k_cursor<<<GRID_N, 256, 0, stream>>>(off, cur, N, E);
    k_fill<<<GRID_E, 256, 0, stream>>>(src, dst, cur, csr, E);
    k_bounds<<<GRID_N, 256, 0, stream>>>(batch, gstart, N, G);
    k_gin1<<<GRID_W, 256, 0, stream>>>(x, off, csr, W1, b1, W2, b2, h, N);
    k_ln_stats<<<G, 256, 0, stream>>>(h, gstart, gmean, ginv);
    k_ln_apply_relu<<<GRID_NC, 256, 0, stream>>>(h, batch, gmean, ginv, ln1w, ln1b, N);
    k_gin2<<<GRID_W, 256, 0, stream>>>(h, off, csr, W3, b3, W4, b4, z, N);
    k_ln_stats<<<G, 256, 0, stream>>>(z, gstart, gmean, ginv);
    k_pool<<<G, 256, 0, stream>>>(z, gstart, gmean, ginv, ln2w, ln2b, emb);
  };

  run_graph(x1, ei1, batch1, emb1);
  run_graph(x2, ei2, batch2, emb2);
  k_head<<<G, 128, 0, stream>>>(emb1, emb2, d1, d2, Wf1, bf1, Wf2, bf2, Wo, bo, out);
}

// Round 2
// 1836.670 us; speedup vs baseline: 1.3868x; 1.3868x over previous
//
#include <hip/hip_runtime.h>

typedef unsigned short ushort_t;

#define FIN 6

__device__ __forceinline__ float blo(unsigned u) { return __uint_as_float(u << 16); }
__device__ __forceinline__ float bhi(unsigned u) { return __uint_as_float(u & 0xffff0000u); }
__device__ __forceinline__ ushort_t f2b(float f) {
  unsigned u = __float_as_uint(f);
  unsigned r = (u + 0x7fffu + ((u >> 16) & 1u)) >> 16;
  return (ushort_t)r;
}
__device__ __forceinline__ float b2f(ushort_t s) { return __uint_as_float(((unsigned)s) << 16); }

// ---------------- CSR build ----------------
__global__ void k_hist(const int* __restrict__ dst, int* __restrict__ deg, int E) {
  int e = blockIdx.x * 256 + threadIdx.x;
  if (e < E) atomicAdd(&deg[dst[e]], 1);
}

__global__ __launch_bounds__(256) void k_scan_local(const int* __restrict__ in,
                                                    int* __restrict__ out,
                                                    int* __restrict__ bsum, int n) {
  __shared__ int lds[256];
  int t = threadIdx.x;
  int base = blockIdx.x * 1024 + t * 4;
  int v0 = 0, v1 = 0, v2 = 0, v3 = 0;
  if (base + 0 < n) v0 = in[base + 0];
  if (base + 1 < n) v1 = in[base + 1];
  if (base + 2 < n) v2 = in[base + 2];
  if (base + 3 < n) v3 = in[base + 3];
  int s = v0 + v1 + v2 + v3;
  lds[t] = s; __syncthreads();
  int acc = s;
  for (int o = 1; o < 256; o <<= 1) {
    int add = (t >= o) ? lds[t - o] : 0;
    __syncthreads();
    acc += add; lds[t] = acc;
    __syncthreads();
  }
  if (t == 255) bsum[blockIdx.x] = acc;
  int run = acc - s;
  if (base + 0 < n) out[base + 0] = run; run += v0;
  if (base + 1 < n) out[base + 1] = run; run += v1;
  if (base + 2 < n) out[base + 2] = run; run += v2;
  if (base + 3 < n) out[base + 3] = run;
}

__global__ __launch_bounds__(256) void k_scan_bsum(int* bsum, int nb) {
  __shared__ int lds[256];
  int t = threadIdx.x;
  int s = (t < nb) ? bsum[t] : 0;
  lds[t] = s; __syncthreads();
  int acc = s;
  for (int o = 1; o < 256; o <<= 1) {
    int add = (t >= o) ? lds[t - o] : 0;
    __syncthreads();
    acc += add; lds[t] = acc;
    __syncthreads();
  }
  if (t < nb) bsum[t] = acc - s;
}

__global__ void k_scan_add(int* __restrict__ out, const int* __restrict__ bsum, int n) {
  int i = blockIdx.x * 256 + threadIdx.x;
  if (i < n) out[i] += bsum[i >> 10];
}

__global__ void k_cursor(int* __restrict__ off, int* __restrict__ cur, int n, int E) {
  int i = blockIdx.x * 256 + threadIdx.x;
  if (i < n) cur[i] = off[i];
  if (i == 0) off[n] = E;
}

__global__ void k_fill(const int* __restrict__ src, const int* __restrict__ dst,
                       int* __restrict__ cur, int* __restrict__ csr, int E) {
  int e = blockIdx.x * 256 + threadIdx.x;
  if (e < E) {
    int p = atomicAdd(&cur[dst[e]], 1);
    csr[p] = src[e];
  }
}

__global__ void k_bounds(const int* __restrict__ batch, int* __restrict__ gstart, int n, int G) {
  int i = blockIdx.x * 256 + threadIdx.x;
  if (i >= n) return;
  int b = batch[i];
  if (i == 0) { for (int g = 0; g <= b; ++g) gstart[g] = 0; }
  else { int pb = batch[i - 1]; for (int g = pb + 1; g <= b; ++g) gstart[g] = i; }
  if (i == n - 1) { for (int g = b + 1; g <= G; ++g) gstart[g] = n; }
}

// ---------------- GIN1a: gather x (6ch) + Linear(6->64) + relu -> t1 (bf16) ----------------
// 8 lanes per node, 8 nodes per wave, 4 waves per block (32 nodes/block).
__global__ __launch_bounds__(256) void k_gin1a(const float* __restrict__ x,
    const int* __restrict__ off, const int* __restrict__ csr,
    const float* __restrict__ W1, const float* __restrict__ b1,
    ushort_t* __restrict__ t1, int n) {
  int t = threadIdx.x, w = t >> 6, lane = t & 63;
  int nd = lane >> 3, sl = lane & 7;
  int i = blockIdx.x * 32 + w * 8 + nd;

  // W1 column for output channel = lane
  float w1r[FIN];
  #pragma unroll
  for (int k = 0; k < FIN; ++k) w1r[k] = W1[k * 64 + lane];
  float bb1 = b1[lane];

  float a0 = 0, a1 = 0, a2 = 0, a3 = 0, a4 = 0, a5 = 0;
  if (i < n) {
    int e0 = off[i], e1 = off[i + 1];
    for (int e = e0 + sl; e < e1; e += 8) {
      const float* xr = x + (size_t)csr[e] * FIN;
      a0 += xr[0]; a1 += xr[1]; a2 += xr[2]; a3 += xr[3]; a4 += xr[4]; a5 += xr[5];
    }
    if (sl == 0) {
      const float* xi = x + (size_t)i * FIN;
      a0 += xi[0]; a1 += xi[1]; a2 += xi[2]; a3 += xi[3]; a4 += xi[4]; a5 += xi[5];
    }
  }
  #pragma unroll
  for (int m = 1; m < 8; m <<= 1) {
    a0 += __shfl_xor(a0, m); a1 += __shfl_xor(a1, m); a2 += __shfl_xor(a2, m);
    a3 += __shfl_xor(a3, m); a4 += __shfl_xor(a4, m); a5 += __shfl_xor(a5, m);
  }
  __shared__ float sh[4][8][FIN];
  if (sl < FIN) {
    float v = (sl == 0) ? a0 : (sl == 1) ? a1 : (sl == 2) ? a2 : (sl == 3) ? a3 : (sl == 4) ? a4 : a5;
    sh[w][nd][sl] = v;
  }
  // same-wave DS ops are in-order; no barrier needed (wave-private slice)
  #pragma unroll
  for (int nd2 = 0; nd2 < 8; ++nd2) {
    int node = blockIdx.x * 32 + w * 8 + nd2;
    if (node >= n) break;
    float h = bb1;
    #pragma unroll
    for (int k = 0; k < FIN; ++k) h = fmaf(sh[w][nd2][k], w1r[k], h);
    h = fmaxf(h, 0.f);
    t1[(size_t)node * 64 + lane] = f2b(h);
  }
}

// ---------------- k_lin: h_raw = t1 @ W2 + b2  (bf16 in, fp32 out) ----------------
// W2 column in 64 VGPRs; per-wave LDS broadcast of the input row.
__global__ __launch_bounds__(256) void k_lin(const ushort_t* __restrict__ in,
    const float* __restrict__ W, const float* __restrict__ b,
    float* __restrict__ out, int n) {
  __shared__ float sh[4][64];
  int t = threadIdx.x, w = t >> 6, lane = t & 63;
  float wr[64];
  #pragma unroll
  for (int k = 0; k < 64; ++k) wr[k] = W[k * 64 + lane];
  float bb = b[lane];
  int nw = gridDim.x * 4;
  int wid = blockIdx.x * 4 + w;
  const float4* s4 = (const float4*)(&sh[w][0]);
  float vcur = 0.f;
  if (wid < n) vcur = b2f(in[(size_t)wid * 64 + lane]);
  for (int i = wid; i < n; i += nw) {
    int inext = i + nw;
    float vnext = 0.f;
    if (inext < n) vnext = b2f(in[(size_t)inext * 64 + lane]);
    sh[w][lane] = vcur;
    float p0 = bb, p1 = 0, p2 = 0, p3 = 0;
    #pragma unroll
    for (int q = 0; q < 16; ++q) {
      float4 hv = s4[q];
      p0 = fmaf(hv.x, wr[4 * q + 0], p0);
      p1 = fmaf(hv.y, wr[4 * q + 1], p1);
      p2 = fmaf(hv.z, wr[4 * q + 2], p2);
      p3 = fmaf(hv.w, wr[4 * q + 3], p3);
    }
    out[(size_t)i * 64 + lane] = (p0 + p1) + (p2 + p3);
    vcur = vnext;
  }
}

// ---------------- k_agg64: aggb = h_b[i] + sum_j h_b[j]  (bf16 in/out, fp32 accum) ----------------
// wave per node; 4 groups x 16 lanes; each lane covers 4 channels (8B of the 128B row).
__global__ __launch_bounds__(256) void k_agg64(const ushort_t* __restrict__ hb,
    const int* __restrict__ off, const int* __restrict__ csr,
    ushort_t* __restrict__ aggb, int n) {
  int t = threadIdx.x, w = t >> 6, lane = t & 63;
  int i = blockIdx.x * 4 + w;
  if (i >= n) return;
  int grp = lane >> 4, sl = lane & 15;
  int e0 = off[i], e1 = off[i + 1];
  float a0 = 0, a1 = 0, a2 = 0, a3 = 0;
  int e = e0 + grp;
  for (; e + 4 < e1; e += 8) {
    int s0 = csr[e], s1 = csr[e + 4];
    uint2 u0 = *(const uint2*)(hb + (size_t)s0 * 64 + sl * 4);
    uint2 u1 = *(const uint2*)(hb + (size_t)s1 * 64 + sl * 4);
    a0 += blo(u0.x); a1 += bhi(u0.x); a2 += blo(u0.y); a3 += bhi(u0.y);
    a0 += blo(u1.x); a1 += bhi(u1.x); a2 += blo(u1.y); a3 += bhi(u1.y);
  }
  for (; e < e1; e += 4) {
    int s0 = csr[e];
    uint2 u0 = *(const uint2*)(hb + (size_t)s0 * 64 + sl * 4);
    a0 += blo(u0.x); a1 += bhi(u0.x); a2 += blo(u0.y); a3 += bhi(u0.y);
  }
  #pragma unroll
  for (int m = 16; m < 64; m <<= 1) {
    a0 += __shfl_xor(a0, m); a1 += __shfl_xor(a1, m);
    a2 += __shfl_xor(a2, m); a3 += __shfl_xor(a3, m);
  }
  if (grp == 0) {
    uint2 us = *(const uint2*)(hb + (size_t)i * 64 + sl * 4);
    a0 += blo(us.x); a1 += bhi(us.x); a2 += blo(us.y); a3 += bhi(us.y);
    ushort4 o;
    o.x = f2b(a0); o.y = f2b(a1); o.z = f2b(a2); o.w = f2b(a3);
    *(ushort4*)(aggb + (size_t)i * 64 + sl * 4) = o;
  }
}

// ---------------- k_mlp2: z = relu(aggb@W3+b3)@W4+b4  (bf16 in, fp32 out) ----------------
__global__ __launch_bounds__(256) void k_mlp2(const ushort_t* __restrict__ aggb,
    const float* __restrict__ W3, const float* __restrict__ b3,
    const float* __restrict__ W4, const float* __restrict__ b4,
    float* __restrict__ z, int n) {
  __shared__ float sh[4][64];
  int t = threadIdx.x, w = t >> 6, lane = t & 63;
  float w3r[64], w4r[64];
  #pragma unroll
  for (int k = 0; k < 64; ++k) { w3r[k] = W3[k * 64 + lane]; w4r[k] = W4[k * 64 + lane]; }
  float bb3 = b3[lane], bb4 = b4[lane];
  int nw = gridDim.x * 4;
  int wid = blockIdx.x * 4 + w;
  const float4* s4 = (const float4*)(&sh[w][0]);
  float vcur = 0.f;
  if (wid < n) vcur = b2f(aggb[(size_t)wid * 64 + lane]);
  for (int i = wid; i < n; i += nw) {
    int inext = i + nw;
    float vnext = 0.f;
    if (inext < n) vnext = b2f(aggb[(size_t)inext * 64 + lane]);
    sh[w][lane] = vcur;
    float p0 = bb3, p1 = 0, p2 = 0, p3 = 0;
    #pragma unroll
    for (int q = 0; q < 16; ++q) {
      float4 hv = s4[q];
      p0 = fmaf(hv.x, w3r[4 * q + 0], p0);
      p1 = fmaf(hv.y, w3r[4 * q + 1], p1);
      p2 = fmaf(hv.z, w3r[4 * q + 2], p2);
      p3 = fmaf(hv.w, w3r[4 * q + 3], p3);
    }
    float h1 = fmaxf((p0 + p1) + (p2 + p3), 0.f);
    sh[w][lane] = h1;   // same-wave DS in-order: prior reads complete before this write lands
    p0 = bb4; p1 = 0; p2 = 0; p3 = 0;
    #pragma unroll
    for (int q = 0; q < 16; ++q) {
      float4 hv = s4[q];
      p0 = fmaf(hv.x, w4r[4 * q + 0], p0);
      p1 = fmaf(hv.y, w4r[4 * q + 1], p1);
      p2 = fmaf(hv.z, w4r[4 * q + 2], p2);
      p3 = fmaf(hv.w, w4r[4 * q + 3], p3);
    }
    z[(size_t)i * 64 + lane] = (p0 + p1) + (p2 + p3);
    vcur = vnext;
  }
}

// ---------------- graph LayerNorm stats (block per graph) ----------------
__global__ __launch_bounds__(256) void k_ln_stats(const float* __restrict__ h,
    const int* __restrict__ gstart, float* __restrict__ gmean, float* __restrict__ ginv) {
  int g = blockIdx.x;
  int s0 = gstart[g], s1 = gstart[g + 1];
  size_t j0 = (size_t)s0 * 64, j1 = (size_t)s1 * 64;
  float s = 0.f, ss = 0.f;
  for (size_t j = j0 + threadIdx.x; j < j1; j += 256) {
    float v = h[j]; s += v; ss += v * v;
  }
  __shared__ float l1[256], l2[256];
  l1[threadIdx.x] = s; l2[threadIdx.x] = ss;
  __syncthreads();
  for (int o = 128; o > 0; o >>= 1) {
    if (threadIdx.x < o) { l1[threadIdx.x] += l1[threadIdx.x + o]; l2[threadIdx.x] += l2[threadIdx.x + o]; }
    __syncthreads();
  }
  if (threadIdx.x == 0) {
    float cnt = (float)(s1 - s0);
    float norm = fmaxf(cnt, 1.f) * 64.f;
    float mean = l1[0] / norm;
    float var = l2[0] / norm - mean * mean;
    var = fmaxf(var, 0.f);
    gmean[g] = mean;
    ginv[g] = rsqrtf(var + 1e-5f);
  }
}

// ---------------- LN apply + relu : h_raw (fp32) -> h_b (bf16) ----------------
__global__ void k_ln_apply_relu(const float* __restrict__ h, const int* __restrict__ batch,
    const float* __restrict__ gmean, const float* __restrict__ ginv,
    const float* __restrict__ w, const float* __restrict__ bb,
    ushort_t* __restrict__ hbout, int n) {
  int tt = blockIdx.x * 256 + threadIdx.x;
  if (tt >= n * 16) return;
  int i = tt >> 4, q = tt & 15;
  int g = batch[i];
  float mean = gmean[g], inv = ginv[g];
  float4 v = *(const float4*)(h + (size_t)i * 64 + q * 4);
  float4 wv = *(const float4*)(w + q * 4);
  float4 bv = *(const float4*)(bb + q * 4);
  ushort4 o;
  o.x = f2b(fmaxf((v.x - mean) * inv * wv.x + bv.x, 0.f));
  o.y = f2b(fmaxf((v.y - mean) * inv * wv.y + bv.y, 0.f));
  o.z = f2b(fmaxf((v.z - mean) * inv * wv.z + bv.z, 0.f));
  o.w = f2b(fmaxf((v.w - mean) * inv * wv.w + bv.w, 0.f));
  *(ushort4*)(hbout + (size_t)i * 64 + q * 4) = o;
}

// ---------------- pool: emb = sum(relu(ln2(z))) + mean ----------------
__global__ __launch_bounds__(256) void k_pool(const float* __restrict__ z,
    const int* __restrict__ gstart, const float* __restrict__ gmean, const float* __restrict__ ginv,
    const float* __restrict__ w, const float* __restrict__ bb, float* __restrict__ emb) {
  int g = blockIdx.x;
  int s0 = gstart[g], s1 = gstart[g + 1];
  int t = threadIdx.x, c = t & 63, sub = t >> 6;
  float mean = gmean[g], inv = ginv[g], wc = w[c], bc = bb[c];
  float acc = 0.f;
  for (int i = s0 + sub; i < s1; i += 4) {
    float v = (z[(size_t)i * 64 + c] - mean) * inv * wc + bc;
    acc += fmaxf(v, 0.f);
  }
  __shared__ float lds[256];
  lds[t] = acc;
  __syncthreads();
  if (sub == 0) {
    float tot = lds[c] + lds[64 + c] + lds[128 + c] + lds[192 + c];
    float cnt = fmaxf((float)(s1 - s0), 1.f);
    emb[g * 64 + c] = tot + tot / cnt;
  }
}

// ---------------- head MLP: [138]->128 relu ->64 relu ->1 ----------------
__global__ __launch_bounds__(128) void k_head(const float* __restrict__ emb1,
    const float* __restrict__ emb2, const float* __restrict__ d1, const float* __restrict__ d2,
    const float* __restrict__ Wf1, const float* __restrict__ bf1,
    const float* __restrict__ Wf2, const float* __restrict__ bf2,
    const float* __restrict__ Wo, const float* __restrict__ bo, float* __restrict__ out) {
  int g = blockIdx.x, t = threadIdx.x;
  __shared__ float v[138], h1s[128], h2s[64];
  if (t < 64) v[t] = emb1[g * 64 + t];
  else v[t] = emb2[g * 64 + (t - 64)];
  if (t < 5) v[128 + t] = d1[g * 5 + t];
  else if (t < 10) v[133 + (t - 5)] = d2[g * 5 + (t - 5)];
  __syncthreads();
  float a = bf1[t];
  for (int k = 0; k < 138; ++k) a = fmaf(v[k], Wf1[k * 128 + t], a);
  h1s[t] = fmaxf(a, 0.f);
  __syncthreads();
  if (t < 64) {
    float a2 = bf2[t];
    #pragma unroll 8
    for (int k = 0; k < 128; ++k) a2 = fmaf(h1s[k], Wf2[k * 64 + t], a2);
    h2s[t] = fmaxf(a2, 0.f);
  }
  __syncthreads();
  if (t == 0) {
    float s = bo[0];
    for (int k = 0; k < 64; ++k) s += h2s[k] * Wo[k];
    out[g] = s;
  }
}

extern "C" void kernel_launch(void* const* d_in, const int* in_sizes, int n_in,
                              void* d_out, int out_size, void* d_ws, size_t ws_size,
                              hipStream_t stream) {
  const float* x1     = (const float*)d_in[0];
  const int*   ei1    = (const int*)d_in[1];
  const int*   batch1 = (const int*)d_in[2];
  const float* x2     = (const float*)d_in[3];
  const int*   ei2    = (const int*)d_in[4];
  const int*   batch2 = (const int*)d_in[5];
  const float* d1     = (const float*)d_in[6];
  const float* d2     = (const float*)d_in[7];
  const float* W1  = (const float*)d_in[8],  *b1  = (const float*)d_in[9];
  const float* W2  = (const float*)d_in[10], *b2  = (const float*)d_in[11];
  const float* ln1w = (const float*)d_in[12], *ln1b = (const float*)d_in[13];
  const float* W3  = (const float*)d_in[14], *b3  = (const float*)d_in[15];
  const float* W4  = (const float*)d_in[16], *b4  = (const float*)d_in[17];
  const float* ln2w = (const float*)d_in[18], *ln2b = (const float*)d_in[19];
  const float* Wf1 = (const float*)d_in[20], *bf1 = (const float*)d_in[21];
  const float* Wf2 = (const float*)d_in[22], *bf2 = (const float*)d_in[23];
  const float* Wo  = (const float*)d_in[24], *bo  = (const float*)d_in[25];
  float* out = (float*)d_out;

  const int N = in_sizes[0] / FIN;
  const int G = in_sizes[6] / 5;
  const int E1 = in_sizes[1] / 2;
  const int E2 = in_sizes[4] / 2;
  const int Emax = (E1 > E2) ? E1 : E2;

  char* p = (char*)d_ws;
  auto alloc = [&](size_t bytes) { void* r = p; p += (bytes + 255) & ~(size_t)255; return r; };
  int*      off    = (int*)alloc((size_t)(N + 1) * 4);
  int*      cur    = (int*)alloc((size_t)N * 4);
  int*      deg    = (int*)alloc((size_t)N * 4);
  int*      bsum   = (int*)alloc(1024 * 4);
  int*      csr    = (int*)alloc((size_t)Emax * 4);
  int*      gstart = (int*)alloc((size_t)(G + 1) * 4);
  float*    gmean  = (float*)alloc((size_t)G * 4);
  float*    ginv   = (float*)alloc((size_t)G * 4);
  ushort_t* t1     = (ushort_t*)alloc((size_t)N * 64 * 2);  // aliased: aggb
  float*    hraw   = (float*)alloc((size_t)N * 64 * 4);     // aliased: z
  ushort_t* hb     = (ushort_t*)alloc((size_t)N * 64 * 2);
  float*    emb1   = (float*)alloc((size_t)G * 64 * 4);
  float*    emb2   = (float*)alloc((size_t)G * 64 * 4);
  ushort_t* aggb = t1;
  float*    z    = hraw;

  const int NB      = (N + 1023) / 1024;
  const int GRID_N  = (N + 255) / 256;
  const int GRID_W  = (N + 3) / 4;
  const int GRID_G1 = (N + 31) / 32;
  const int GRID_A  = (N * 16 + 255) / 256;

  auto run_graph = [&](const float* x, const int* ei, const int* batch, int E, float* emb) {
    const int* src = ei;
    const int* dst = ei + E;
    const int GRID_E = (E + 255) / 256;
    hipMemsetAsync(deg, 0, (size_t)N * 4, stream);
    k_hist<<<GRID_E, 256, 0, stream>>>(dst, deg, E);
    k_scan_local<<<NB, 256, 0, stream>>>(deg, off, bsum, N);
    k_scan_bsum<<<1, 256, 0, stream>>>(bsum, NB);
    k_scan_add<<<GRID_N, 256, 0, stream>>>(off, bsum, N);
    k_cursor<<<GRID_N, 256, 0, stream>>>(off, cur, N, E);
    k_fill<<<GRID_E, 256, 0, stream>>>(src, dst, cur, csr, E);
    k_bounds<<<GRID_N, 256, 0, stream>>>(batch, gstart, N, G);

    k_gin1a<<<GRID_G1, 256, 0, stream>>>(x, off, csr, W1, b1, t1, N);
    k_lin<<<2048, 256, 0, stream>>>(t1, W2, b2, hraw, N);
    k_ln_stats<<<G, 256, 0, stream>>>(hraw, gstart, gmean, ginv);
    k_ln_apply_relu<<<GRID_A, 256, 0, stream>>>(hraw, batch, gmean, ginv, ln1w, ln1b, hb, N);
    k_agg64<<<GRID_W, 256, 0, stream>>>(hb, off, csr, aggb, N);
    k_mlp2<<<2048, 256, 0, stream>>>(aggb, W3, b3, W4, b4, z, N);
    k_ln_stats<<<G, 256, 0, stream>>>(z, gstart, gmean, ginv);
    k_pool<<<G, 256, 0, stream>>>(z, gstart, gmean, ginv, ln2w, ln2b, emb);
  };

  run_graph(x1, ei1, batch1, E1, emb1);
  run_graph(x2, ei2, batch2, E2, emb2);
  k_head<<<G, 128, 0, stream>>>(emb1, emb2, d1, d2, Wf1, bf1, Wf2, bf2, Wo, bo, out);
}

// Round 3
// 1067.203 us; speedup vs baseline: 2.3866x; 1.7210x over previous
//
#include <hip/hip_runtime.h>

typedef unsigned short ushort_t;

#define FIN 6

__device__ __forceinline__ float blo(unsigned u) { return __uint_as_float(u << 16); }
__device__ __forceinline__ float bhi(unsigned u) { return __uint_as_float(u & 0xffff0000u); }
__device__ __forceinline__ ushort_t f2b(float f) {
  unsigned u = __float_as_uint(f);
  unsigned r = (u + 0x7fffu + ((u >> 16) & 1u)) >> 16;
  return (ushort_t)r;
}
__device__ __forceinline__ float b2f(ushort_t s) { return __uint_as_float(((unsigned)s) << 16); }

// ================= bucketed CSR build =================
// buckets of 1024 nodes by dst>>10; NBUK <= 256 (requires N <= 262144).
#define EPT 32          // edges per thread in count/scatter
#define TILE 8192       // 256 threads * EPT

__global__ __launch_bounds__(256) void k_bcount(const int* __restrict__ dst,
    int* __restrict__ ecount, int E, int nbuk) {
  __shared__ int cnt[256];
  int t = threadIdx.x;
  cnt[t] = 0;
  __syncthreads();
  int base = blockIdx.x * TILE;
  #pragma unroll
  for (int k = 0; k < EPT; ++k) {
    int e = base + k * 256 + t;
    if (e < E) atomicAdd(&cnt[dst[e] >> 10], 1);
  }
  __syncthreads();
  if (t < nbuk && cnt[t] > 0) atomicAdd(&ecount[t], cnt[t]);
}

__global__ __launch_bounds__(256) void k_bscan(const int* __restrict__ ecount,
    int* __restrict__ ebase, int* __restrict__ ecur, int* __restrict__ off,
    int nbuk, int N, int E) {
  __shared__ int lds[256];
  int t = threadIdx.x;
  int s = (t < nbuk) ? ecount[t] : 0;
  lds[t] = s; __syncthreads();
  int acc = s;
  for (int o = 1; o < 256; o <<= 1) {
    int add = (t >= o) ? lds[t - o] : 0;
    __syncthreads();
    acc += add; lds[t] = acc;
    __syncthreads();
  }
  int excl = acc - s;
  if (t < nbuk) { ebase[t] = excl; ecur[t] = excl; }
  if (t == nbuk - 1) ebase[nbuk] = excl + s;
  if (t == 0) off[N] = E;
}

__global__ __launch_bounds__(256) void k_bscatter(const int* __restrict__ src,
    const int* __restrict__ dst, int* __restrict__ ecur,
    unsigned* __restrict__ ebuf, int E, int nbuk) {
  __shared__ int cnt[256];
  __shared__ int gbase[256];
  int t = threadIdx.x;
  cnt[t] = 0;
  __syncthreads();
  int base = blockIdx.x * TILE;
  unsigned pk[EPT];   // bucket | rank<<8
  unsigned pv[EPT];   // (dst&1023)<<18 | src
  #pragma unroll
  for (int k = 0; k < EPT; ++k) {
    int e = base + k * 256 + t;
    if (e < E) {
      int d = dst[e];
      int b = d >> 10;
      int r = atomicAdd(&cnt[b], 1);
      pk[k] = (unsigned)b | ((unsigned)r << 8);
      pv[k] = ((unsigned)(d & 1023) << 18) | (unsigned)src[e];
    } else {
      pk[k] = 0xFFFFFFFFu;
    }
  }
  __syncthreads();
  if (t < nbuk && cnt[t] > 0) gbase[t] = atomicAdd(&ecur[t], cnt[t]);
  __syncthreads();
  #pragma unroll
  for (int k = 0; k < EPT; ++k) {
    if (pk[k] != 0xFFFFFFFFu) {
      int b = pk[k] & 255;
      int r = pk[k] >> 8;
      ebuf[gbase[b] + r] = pv[k];
    }
  }
}

// one block per bucket: local hist -> scan -> off + csr placement
__global__ __launch_bounds__(256) void k_bcsr(const unsigned* __restrict__ ebuf,
    const int* __restrict__ ebase, int* __restrict__ off, int* __restrict__ csr, int N) {
  __shared__ int hist[1024];
  __shared__ int lofs[1024];
  __shared__ int sc[256];
  int b = blockIdx.x, t = threadIdx.x;
  int nb0 = b << 10;
  int bn = N - nb0; if (bn > 1024) bn = 1024;
  int e0 = ebase[b], e1 = ebase[b + 1];
  #pragma unroll
  for (int k = 0; k < 4; ++k) hist[t * 4 + k] = 0;
  __syncthreads();
  for (int e = e0 + t; e < e1; e += 256) {
    atomicAdd(&hist[ebuf[e] >> 18], 1);
  }
  __syncthreads();
  int h0 = hist[t * 4 + 0], h1 = hist[t * 4 + 1], h2 = hist[t * 4 + 2], h3 = hist[t * 4 + 3];
  int s = h0 + h1 + h2 + h3;
  sc[t] = s; __syncthreads();
  int acc = s;
  for (int o = 1; o < 256; o <<= 1) {
    int add = (t >= o) ? sc[t - o] : 0;
    __syncthreads();
    acc += add; sc[t] = acc;
    __syncthreads();
  }
  int run = acc - s;
  lofs[t * 4 + 0] = run; run += h0;
  lofs[t * 4 + 1] = run; run += h1;
  lofs[t * 4 + 2] = run; run += h2;
  lofs[t * 4 + 3] = run;
  __syncthreads();
  #pragma unroll
  for (int k = 0; k < 4; ++k) {
    int j = t * 4 + k;
    if (j < bn) off[nb0 + j] = e0 + lofs[j];
  }
  __syncthreads();
  for (int e = e0 + t; e < e1; e += 256) {
    unsigned p = ebuf[e];
    int dl = p >> 18;
    int r = atomicAdd(&lofs[dl], 1);
    csr[e0 + r] = (int)(p & 0x3FFFFu);
  }
}

__global__ void k_bounds(const int* __restrict__ batch, int* __restrict__ gstart, int n, int G) {
  int i = blockIdx.x * 256 + threadIdx.x;
  if (i >= n) return;
  int b = batch[i];
  if (i == 0) { for (int g = 0; g <= b; ++g) gstart[g] = 0; }
  else { int pb = batch[i - 1]; for (int g = pb + 1; g <= b; ++g) gstart[g] = i; }
  if (i == n - 1) { for (int g = b + 1; g <= G; ++g) gstart[g] = n; }
}

// ---------------- GIN1a: gather x (6ch) + Linear(6->64) + relu -> t1 (bf16) ----------------
__global__ __launch_bounds__(256) void k_gin1a(const float* __restrict__ x,
    const int* __restrict__ off, const int* __restrict__ csr,
    const float* __restrict__ W1, const float* __restrict__ b1,
    ushort_t* __restrict__ t1, int n) {
  int t = threadIdx.x, w = t >> 6, lane = t & 63;
  int nd = lane >> 3, sl = lane & 7;
  int i = blockIdx.x * 32 + w * 8 + nd;

  float w1r[FIN];
  #pragma unroll
  for (int k = 0; k < FIN; ++k) w1r[k] = W1[k * 64 + lane];
  float bb1 = b1[lane];

  float a0 = 0, a1 = 0, a2 = 0, a3 = 0, a4 = 0, a5 = 0;
  if (i < n) {
    int e0 = off[i], e1 = off[i + 1];
    for (int e = e0 + sl; e < e1; e += 8) {
      const float* xr = x + (size_t)csr[e] * FIN;
      a0 += xr[0]; a1 += xr[1]; a2 += xr[2]; a3 += xr[3]; a4 += xr[4]; a5 += xr[5];
    }
    if (sl == 0) {
      const float* xi = x + (size_t)i * FIN;
      a0 += xi[0]; a1 += xi[1]; a2 += xi[2]; a3 += xi[3]; a4 += xi[4]; a5 += xi[5];
    }
  }
  #pragma unroll
  for (int m = 1; m < 8; m <<= 1) {
    a0 += __shfl_xor(a0, m); a1 += __shfl_xor(a1, m); a2 += __shfl_xor(a2, m);
    a3 += __shfl_xor(a3, m); a4 += __shfl_xor(a4, m); a5 += __shfl_xor(a5, m);
  }
  __shared__ float sh[4][8][FIN];
  if (sl < FIN) {
    float v = (sl == 0) ? a0 : (sl == 1) ? a1 : (sl == 2) ? a2 : (sl == 3) ? a3 : (sl == 4) ? a4 : a5;
    sh[w][nd][sl] = v;
  }
  #pragma unroll
  for (int nd2 = 0; nd2 < 8; ++nd2) {
    int node = blockIdx.x * 32 + w * 8 + nd2;
    if (node >= n) break;
    float h = bb1;
    #pragma unroll
    for (int k = 0; k < FIN; ++k) h = fmaf(sh[w][nd2][k], w1r[k], h);
    h = fmaxf(h, 0.f);
    t1[(size_t)node * 64 + lane] = f2b(h);
  }
}

// ---------------- k_lin: h_raw = t1 @ W2 + b2 ----------------
__global__ __launch_bounds__(256) void k_lin(const ushort_t* __restrict__ in,
    const float* __restrict__ W, const float* __restrict__ b,
    float* __restrict__ out, int n) {
  __shared__ float sh[4][64];
  int t = threadIdx.x, w = t >> 6, lane = t & 63;
  float wr[64];
  #pragma unroll
  for (int k = 0; k < 64; ++k) wr[k] = W[k * 64 + lane];
  float bb = b[lane];
  int nw = gridDim.x * 4;
  int wid = blockIdx.x * 4 + w;
  const float4* s4 = (const float4*)(&sh[w][0]);
  float vcur = 0.f;
  if (wid < n) vcur = b2f(in[(size_t)wid * 64 + lane]);
  for (int i = wid; i < n; i += nw) {
    int inext = i + nw;
    float vnext = 0.f;
    if (inext < n) vnext = b2f(in[(size_t)inext * 64 + lane]);
    sh[w][lane] = vcur;
    float p0 = bb, p1 = 0, p2 = 0, p3 = 0;
    #pragma unroll
    for (int q = 0; q < 16; ++q) {
      float4 hv = s4[q];
      p0 = fmaf(hv.x, wr[4 * q + 0], p0);
      p1 = fmaf(hv.y, wr[4 * q + 1], p1);
      p2 = fmaf(hv.z, wr[4 * q + 2], p2);
      p3 = fmaf(hv.w, wr[4 * q + 3], p3);
    }
    out[(size_t)i * 64 + lane] = (p0 + p1) + (p2 + p3);
    vcur = vnext;
  }
}

// ---------------- k_agg64 ----------------
__global__ __launch_bounds__(256) void k_agg64(const ushort_t* __restrict__ hb,
    const int* __restrict__ off, const int* __restrict__ csr,
    ushort_t* __restrict__ aggb, int n) {
  int t = threadIdx.x, w = t >> 6, lane = t & 63;
  int i = blockIdx.x * 4 + w;
  if (i >= n) return;
  int grp = lane >> 4, sl = lane & 15;
  int e0 = off[i], e1 = off[i + 1];
  float a0 = 0, a1 = 0, a2 = 0, a3 = 0;
  int e = e0 + grp;
  for (; e + 4 < e1; e += 8) {
    int s0 = csr[e], s1 = csr[e + 4];
    uint2 u0 = *(const uint2*)(hb + (size_t)s0 * 64 + sl * 4);
    uint2 u1 = *(const uint2*)(hb + (size_t)s1 * 64 + sl * 4);
    a0 += blo(u0.x); a1 += bhi(u0.x); a2 += blo(u0.y); a3 += bhi(u0.y);
    a0 += blo(u1.x); a1 += bhi(u1.x); a2 += blo(u1.y); a3 += bhi(u1.y);
  }
  for (; e < e1; e += 4) {
    int s0 = csr[e];
    uint2 u0 = *(const uint2*)(hb + (size_t)s0 * 64 + sl * 4);
    a0 += blo(u0.x); a1 += bhi(u0.x); a2 += blo(u0.y); a3 += bhi(u0.y);
  }
  #pragma unroll
  for (int m = 16; m < 64; m <<= 1) {
    a0 += __shfl_xor(a0, m); a1 += __shfl_xor(a1, m);
    a2 += __shfl_xor(a2, m); a3 += __shfl_xor(a3, m);
  }
  if (grp == 0) {
    uint2 us = *(const uint2*)(hb + (size_t)i * 64 + sl * 4);
    a0 += blo(us.x); a1 += bhi(us.x); a2 += blo(us.y); a3 += bhi(us.y);
    ushort4 o;
    o.x = f2b(a0); o.y = f2b(a1); o.z = f2b(a2); o.w = f2b(a3);
    *(ushort4*)(aggb + (size_t)i * 64 + sl * 4) = o;
  }
}

// ---------------- k_mlp2 ----------------
__global__ __launch_bounds__(256) void k_mlp2(const ushort_t* __restrict__ aggb,
    const float* __restrict__ W3, const float* __restrict__ b3,
    const float* __restrict__ W4, const float* __restrict__ b4,
    float* __restrict__ z, int n) {
  __shared__ float sh[4][64];
  int t = threadIdx.x, w = t >> 6, lane = t & 63;
  float w3r[64], w4r[64];
  #pragma unroll
  for (int k = 0; k < 64; ++k) { w3r[k] = W3[k * 64 + lane]; w4r[k] = W4[k * 64 + lane]; }
  float bb3 = b3[lane], bb4 = b4[lane];
  int nw = gridDim.x * 4;
  int wid = blockIdx.x * 4 + w;
  const float4* s4 = (const float4*)(&sh[w][0]);
  float vcur = 0.f;
  if (wid < n) vcur = b2f(aggb[(size_t)wid * 64 + lane]);
  for (int i = wid; i < n; i += nw) {
    int inext = i + nw;
    float vnext = 0.f;
    if (inext < n) vnext = b2f(aggb[(size_t)inext * 64 + lane]);
    sh[w][lane] = vcur;
    float p0 = bb3, p1 = 0, p2 = 0, p3 = 0;
    #pragma unroll
    for (int q = 0; q < 16; ++q) {
      float4 hv = s4[q];
      p0 = fmaf(hv.x, w3r[4 * q + 0], p0);
      p1 = fmaf(hv.y, w3r[4 * q + 1], p1);
      p2 = fmaf(hv.z, w3r[4 * q + 2], p2);
      p3 = fmaf(hv.w, w3r[4 * q + 3], p3);
    }
    float h1 = fmaxf((p0 + p1) + (p2 + p3), 0.f);
    sh[w][lane] = h1;
    p0 = bb4; p1 = 0; p2 = 0; p3 = 0;
    #pragma unroll
    for (int q = 0; q < 16; ++q) {
      float4 hv = s4[q];
      p0 = fmaf(hv.x, w4r[4 * q + 0], p0);
      p1 = fmaf(hv.y, w4r[4 * q + 1], p1);
      p2 = fmaf(hv.z, w4r[4 * q + 2], p2);
      p3 = fmaf(hv.w, w4r[4 * q + 3], p3);
    }
    z[(size_t)i * 64 + lane] = (p0 + p1) + (p2 + p3);
    vcur = vnext;
  }
}

// ---------------- graph LayerNorm stats ----------------
__global__ __launch_bounds__(256) void k_ln_stats(const float* __restrict__ h,
    const int* __restrict__ gstart, float* __restrict__ gmean, float* __restrict__ ginv) {
  int g = blockIdx.x;
  int s0 = gstart[g], s1 = gstart[g + 1];
  size_t j0 = (size_t)s0 * 64, j1 = (size_t)s1 * 64;
  float s = 0.f, ss = 0.f;
  for (size_t j = j0 + threadIdx.x; j < j1; j += 256) {
    float v = h[j]; s += v; ss += v * v;
  }
  __shared__ float l1[256], l2[256];
  l1[threadIdx.x] = s; l2[threadIdx.x] = ss;
  __syncthreads();
  for (int o = 128; o > 0; o >>= 1) {
    if (threadIdx.x < o) { l1[threadIdx.x] += l1[threadIdx.x + o]; l2[threadIdx.x] += l2[threadIdx.x + o]; }
    __syncthreads();
  }
  if (threadIdx.x == 0) {
    float cnt = (float)(s1 - s0);
    float norm = fmaxf(cnt, 1.f) * 64.f;
    float mean = l1[0] / norm;
    float var = l2[0] / norm - mean * mean;
    var = fmaxf(var, 0.f);
    gmean[g] = mean;
    ginv[g] = rsqrtf(var + 1e-5f);
  }
}

// ---------------- LN apply + relu : fp32 -> bf16 ----------------
__global__ void k_ln_apply_relu(const float* __restrict__ h, const int* __restrict__ batch,
    const float* __restrict__ gmean, const float* __restrict__ ginv,
    const float* __restrict__ w, const float* __restrict__ bb,
    ushort_t* __restrict__ hbout, int n) {
  int tt = blockIdx.x * 256 + threadIdx.x;
  if (tt >= n * 16) return;
  int i = tt >> 4, q = tt & 15;
  int g = batch[i];
  float mean = gmean[g], inv = ginv[g];
  float4 v = *(const float4*)(h + (size_t)i * 64 + q * 4);
  float4 wv = *(const float4*)(w + q * 4);
  float4 bv = *(const float4*)(bb + q * 4);
  ushort4 o;
  o.x = f2b(fmaxf((v.x - mean) * inv * wv.x + bv.x, 0.f));
  o.y = f2b(fmaxf((v.y - mean) * inv * wv.y + bv.y, 0.f));
  o.z = f2b(fmaxf((v.z - mean) * inv * wv.z + bv.z, 0.f));
  o.w = f2b(fmaxf((v.w - mean) * inv * wv.w + bv.w, 0.f));
  *(ushort4*)(hbout + (size_t)i * 64 + q * 4) = o;
}

// ---------------- pool ----------------
__global__ __launch_bounds__(256) void k_pool(const float* __restrict__ z,
    const int* __restrict__ gstart, const float* __restrict__ gmean, const float* __restrict__ ginv,
    const float* __restrict__ w, const float* __restrict__ bb, float* __restrict__ emb) {
  int g = blockIdx.x;
  int s0 = gstart[g], s1 = gstart[g + 1];
  int t = threadIdx.x, c = t & 63, sub = t >> 6;
  float mean = gmean[g], inv = ginv[g], wc = w[c], bc = bb[c];
  float acc = 0.f;
  for (int i = s0 + sub; i < s1; i += 4) {
    float v = (z[(size_t)i * 64 + c] - mean) * inv * wc + bc;
    acc += fmaxf(v, 0.f);
  }
  __shared__ float lds[256];
  lds[t] = acc;
  __syncthreads();
  if (sub == 0) {
    float tot = lds[c] + lds[64 + c] + lds[128 + c] + lds[192 + c];
    float cnt = fmaxf((float)(s1 - s0), 1.f);
    emb[g * 64 + c] = tot + tot / cnt;
  }
}

// ---------------- head MLP ----------------
__global__ __launch_bounds__(128) void k_head(const float* __restrict__ emb1,
    const float* __restrict__ emb2, const float* __restrict__ d1, const float* __restrict__ d2,
    const float* __restrict__ Wf1, const float* __restrict__ bf1,
    const float* __restrict__ Wf2, const float* __restrict__ bf2,
    const float* __restrict__ Wo, const float* __restrict__ bo, float* __restrict__ out) {
  int g = blockIdx.x, t = threadIdx.x;
  __shared__ float v[138], h1s[128], h2s[64];
  if (t < 64) v[t] = emb1[g * 64 + t];
  else v[t] = emb2[g * 64 + (t - 64)];
  if (t < 5) v[128 + t] = d1[g * 5 + t];
  else if (t < 10) v[133 + (t - 5)] = d2[g * 5 + (t - 5)];
  __syncthreads();
  float a = bf1[t];
  for (int k = 0; k < 138; ++k) a = fmaf(v[k], Wf1[k * 128 + t], a);
  h1s[t] = fmaxf(a, 0.f);
  __syncthreads();
  if (t < 64) {
    float a2 = bf2[t];
    #pragma unroll 8
    for (int k = 0; k < 128; ++k) a2 = fmaf(h1s[k], Wf2[k * 64 + t], a2);
    h2s[t] = fmaxf(a2, 0.f);
  }
  __syncthreads();
  if (t == 0) {
    float s = bo[0];
    for (int k = 0; k < 64; ++k) s += h2s[k] * Wo[k];
    out[g] = s;
  }
}

extern "C" void kernel_launch(void* const* d_in, const int* in_sizes, int n_in,
                              void* d_out, int out_size, void* d_ws, size_t ws_size,
                              hipStream_t stream) {
  const float* x1     = (const float*)d_in[0];
  const int*   ei1    = (const int*)d_in[1];
  const int*   batch1 = (const int*)d_in[2];
  const float* x2     = (const float*)d_in[3];
  const int*   ei2    = (const int*)d_in[4];
  const int*   batch2 = (const int*)d_in[5];
  const float* d1     = (const float*)d_in[6];
  const float* d2     = (const float*)d_in[7];
  const float* W1  = (const float*)d_in[8],  *b1  = (const float*)d_in[9];
  const float* W2  = (const float*)d_in[10], *b2  = (const float*)d_in[11];
  const float* ln1w = (const float*)d_in[12], *ln1b = (const float*)d_in[13];
  const float* W3  = (const float*)d_in[14], *b3  = (const float*)d_in[15];
  const float* W4  = (const float*)d_in[16], *b4  = (const float*)d_in[17];
  const float* ln2w = (const float*)d_in[18], *ln2b = (const float*)d_in[19];
  const float* Wf1 = (const float*)d_in[20], *bf1 = (const float*)d_in[21];
  const float* Wf2 = (const float*)d_in[22], *bf2 = (const float*)d_in[23];
  const float* Wo  = (const float*)d_in[24], *bo  = (const float*)d_in[25];
  float* out = (float*)d_out;

  const int N = in_sizes[0] / FIN;
  const int G = in_sizes[6] / 5;
  const int E1 = in_sizes[1] / 2;
  const int E2 = in_sizes[4] / 2;
  const int Emax = (E1 > E2) ? E1 : E2;
  const int NBUK = (N + 1023) >> 10;   // <= 256 for N <= 262144

  char* p = (char*)d_ws;
  auto alloc = [&](size_t bytes) { void* r = p; p += (bytes + 255) & ~(size_t)255; return r; };
  int*      off    = (int*)alloc((size_t)(N + 1) * 4);
  int*      ecount = (int*)alloc(256 * 4);
  int*      ebase  = (int*)alloc(257 * 4);
  int*      ecur   = (int*)alloc(256 * 4);
  int*      csr    = (int*)alloc((size_t)Emax * 4);
  int*      gstart = (int*)alloc((size_t)(G + 1) * 4);
  float*    gmean  = (float*)alloc((size_t)G * 4);
  float*    ginv   = (float*)alloc((size_t)G * 4);
  ushort_t* t1     = (ushort_t*)alloc((size_t)N * 64 * 2);  // aliased: aggb
  float*    hraw   = (float*)alloc((size_t)N * 64 * 4);     // aliased: z, ebuf
  ushort_t* hb     = (ushort_t*)alloc((size_t)N * 64 * 2);
  float*    emb1   = (float*)alloc((size_t)G * 64 * 4);
  float*    emb2   = (float*)alloc((size_t)G * 64 * 4);
  ushort_t* aggb = t1;
  float*    z    = hraw;
  unsigned* ebuf = (unsigned*)hraw;   // build phase only; strictly precedes k_lin writes

  const int GRID_N  = (N + 255) / 256;
  const int GRID_W  = (N + 3) / 4;
  const int GRID_G1 = (N + 31) / 32;
  const int GRID_A  = (N * 16 + 255) / 256;

  auto run_graph = [&](const float* x, const int* ei, const int* batch, int E, float* emb) {
    const int* src = ei;
    const int* dst = ei + E;
    const int SCAT = (E + TILE - 1) / TILE;
    hipMemsetAsync(ecount, 0, (size_t)NBUK * 4, stream);
    k_bcount<<<SCAT, 256, 0, stream>>>(dst, ecount, E, NBUK);
    k_bscan<<<1, 256, 0, stream>>>(ecount, ebase, ecur, off, NBUK, N, E);
    k_bscatter<<<SCAT, 256, 0, stream>>>(src, dst, ecur, ebuf, E, NBUK);
    k_bcsr<<<NBUK, 256, 0, stream>>>(ebuf, ebase, off, csr, N);
    k_bounds<<<GRID_N, 256, 0, stream>>>(batch, gstart, N, G);

    k_gin1a<<<GRID_G1, 256, 0, stream>>>(x, off, csr, W1, b1, t1, N);
    k_lin<<<2048, 256, 0, stream>>>(t1, W2, b2, hraw, N);
    k_ln_stats<<<G, 256, 0, stream>>>(hraw, gstart, gmean, ginv);
    k_ln_apply_relu<<<GRID_A, 256, 0, stream>>>(hraw, batch, gmean, ginv, ln1w, ln1b, hb, N);
    k_agg64<<<GRID_W, 256, 0, stream>>>(hb, off, csr, aggb, N);
    k_mlp2<<<2048, 256, 0, stream>>>(aggb, W3, b3, W4, b4, z, N);
    k_ln_stats<<<G, 256, 0, stream>>>(z, gstart, gmean, ginv);
    k_pool<<<G, 256, 0, stream>>>(z, gstart, gmean, ginv, ln2w, ln2b, emb);
  };

  run_graph(x1, ei1, batch1, E1, emb1);
  run_graph(x2, ei2, batch2, E2, emb2);
  k_head<<<G, 128, 0, stream>>>(emb1, emb2, d1, d2, Wf1, bf1, Wf2, bf2, Wo, bo, out);
}

// Round 4
// 945.323 us; speedup vs baseline: 2.6943x; 1.1289x over previous
//
#include <hip/hip_runtime.h>

typedef unsigned short ushort_t;

#define FIN 6
#define CAP 20480      // per-bucket edge capacity (mean 16384 at E=4M, N=250k)

__device__ __forceinline__ float blo(unsigned u) { return __uint_as_float(u << 16); }
__device__ __forceinline__ float bhi(unsigned u) { return __uint_as_float(u & 0xffff0000u); }
__device__ __forceinline__ ushort_t f2b(float f) {
  unsigned u = __float_as_uint(f);
  unsigned r = (u + 0x7fffu + ((u >> 16) & 1u)) >> 16;
  return (ushort_t)r;
}
__device__ __forceinline__ float b2f(ushort_t s) { return __uint_as_float(((unsigned)s) << 16); }
__device__ __forceinline__ unsigned pk2(float lo, float hi) {
  return ((unsigned)f2b(hi) << 16) | (unsigned)f2b(lo);
}

// ================= bucketed CSR build =================
#define EPT 32
#define TILE 8192

__global__ void k_binit(int* __restrict__ ecur, int* __restrict__ off, int nbuk, int N, int E) {
  int t = threadIdx.x;
  if (t < nbuk) ecur[t] = t * CAP;
  if (t == 0) off[N] = E;
}

__global__ __launch_bounds__(256) void k_bscatter(const int* __restrict__ src,
    const int* __restrict__ dst, int* __restrict__ ecur,
    unsigned* __restrict__ ebuf, int E, int nbuk) {
  __shared__ int cnt[256];
  __shared__ int gbase[256];
  int t = threadIdx.x;
  cnt[t] = 0;
  __syncthreads();
  int base = blockIdx.x * TILE;
  unsigned pk[EPT];   // bucket | rank<<8
  unsigned pv[EPT];   // (dst&1023)<<18 | src
  #pragma unroll
  for (int k = 0; k < EPT; ++k) {
    int e = base + k * 256 + t;
    if (e < E) {
      int d = dst[e];
      int b = d >> 10;
      int r = atomicAdd(&cnt[b], 1);
      pk[k] = (unsigned)b | ((unsigned)r << 8);
      pv[k] = ((unsigned)(d & 1023) << 18) | (unsigned)src[e];
    } else {
      pk[k] = 0xFFFFFFFFu;
    }
  }
  __syncthreads();
  if (t < nbuk && cnt[t] > 0) gbase[t] = atomicAdd(&ecur[t], cnt[t]);
  __syncthreads();
  #pragma unroll
  for (int k = 0; k < EPT; ++k) {
    if (pk[k] != 0xFFFFFFFFu) {
      int b = pk[k] & 255;
      int r = pk[k] >> 8;
      ebuf[gbase[b] + r] = pv[k];
    }
  }
}

__global__ __launch_bounds__(256) void k_bscan2(const int* __restrict__ ecur,
    int* __restrict__ ebase, int nbuk) {
  __shared__ int lds[256];
  int t = threadIdx.x;
  int s = (t < nbuk) ? (ecur[t] - t * CAP) : 0;
  lds[t] = s; __syncthreads();
  int acc = s;
  for (int o = 1; o < 256; o <<= 1) {
    int add = (t >= o) ? lds[t - o] : 0;
    __syncthreads();
    acc += add; lds[t] = acc;
    __syncthreads();
  }
  if (t < nbuk) ebase[t] = acc - s;
}

__global__ __launch_bounds__(256) void k_bcsr(const unsigned* __restrict__ ebuf,
    const int* __restrict__ ecur, const int* __restrict__ ebase,
    int* __restrict__ off, int* __restrict__ csr, int N) {
  __shared__ int hist[1024];
  __shared__ int lofs[1024];
  __shared__ int sc[256];
  int b = blockIdx.x, t = threadIdx.x;
  int nb0 = b << 10;
  int bn = N - nb0; if (bn > 1024) bn = 1024;
  int s_beg = b * CAP, s_end = ecur[b];
  int base = ebase[b];
  #pragma unroll
  for (int k = 0; k < 4; ++k) hist[t * 4 + k] = 0;
  __syncthreads();
  for (int e = s_beg + t; e < s_end; e += 256) atomicAdd(&hist[ebuf[e] >> 18], 1);
  __syncthreads();
  int h0 = hist[t * 4 + 0], h1 = hist[t * 4 + 1], h2 = hist[t * 4 + 2], h3 = hist[t * 4 + 3];
  int s = h0 + h1 + h2 + h3;
  sc[t] = s; __syncthreads();
  int acc = s;
  for (int o = 1; o < 256; o <<= 1) {
    int add = (t >= o) ? sc[t - o] : 0;
    __syncthreads();
    acc += add; sc[t] = acc;
    __syncthreads();
  }
  int run = acc - s;
  lofs[t * 4 + 0] = run; run += h0;
  lofs[t * 4 + 1] = run; run += h1;
  lofs[t * 4 + 2] = run; run += h2;
  lofs[t * 4 + 3] = run;
  __syncthreads();
  #pragma unroll
  for (int k = 0; k < 4; ++k) {
    int j = t * 4 + k;
    if (j < bn) off[nb0 + j] = base + lofs[j];
  }
  __syncthreads();
  for (int e = s_beg + t; e < s_end; e += 256) {
    unsigned p = ebuf[e];
    int r = atomicAdd(&lofs[p >> 18], 1);
    csr[base + r] = (int)(p & 0x3FFFFu);
  }
}

__global__ void k_bounds(const int* __restrict__ batch, int* __restrict__ gstart, int n, int G) {
  int i = blockIdx.x * 256 + threadIdx.x;
  if (i >= n) return;
  int b = batch[i];
  if (i == 0) { for (int g = 0; g <= b; ++g) gstart[g] = 0; }
  else { int pb = batch[i - 1]; for (int g = pb + 1; g <= b; ++g) gstart[g] = i; }
  if (i == n - 1) { for (int g = b + 1; g <= G; ++g) gstart[g] = n; }
}

// ---------------- pack x fp32[N,6] -> bf16-padded uint4 rows [N,8ch] ----------------
__global__ void k_xpack(const float* __restrict__ x, unsigned* __restrict__ xb, int n) {
  int tt = blockIdx.x * 256 + threadIdx.x;
  if (tt >= n * 4) return;
  int i = tt >> 2, k = tt & 3;
  unsigned v = 0;
  if (k < 3) {
    float2 f = *(const float2*)(x + (size_t)i * 6 + k * 2);
    v = pk2(f.x, f.y);
  }
  xb[tt] = v;
}

// ---------------- GIN1a: gather xb + Linear(6->64) + relu -> t1 (bf16) ----------------
#define ACC6(u) { a0 += blo(u.x); a1 += bhi(u.x); a2 += blo(u.y); a3 += bhi(u.y); a4 += blo(u.z); a5 += bhi(u.z); }
__global__ __launch_bounds__(256) void k_gin1a(const uint4* __restrict__ xb4,
    const int* __restrict__ off, const int* __restrict__ csr,
    const float* __restrict__ W1, const float* __restrict__ b1,
    ushort_t* __restrict__ t1, int n) {
  int t = threadIdx.x, w = t >> 6, lane = t & 63;
  int nd = lane >> 3, sl = lane & 7;
  int i = blockIdx.x * 32 + w * 8 + nd;

  float w1r[FIN];
  #pragma unroll
  for (int k = 0; k < FIN; ++k) w1r[k] = W1[k * 64 + lane];
  float bb1 = b1[lane];

  float a0 = 0, a1 = 0, a2 = 0, a3 = 0, a4 = 0, a5 = 0;
  if (i < n) {
    int e0 = off[i], e1 = off[i + 1];
    int e = e0 + sl;
    for (; e + 8 < e1; e += 16) {
      uint4 u = xb4[csr[e]];
      uint4 v = xb4[csr[e + 8]];
      ACC6(u); ACC6(v);
    }
    if (e < e1) { uint4 u = xb4[csr[e]]; ACC6(u); }
    if (sl == 0) { uint4 u = xb4[i]; ACC6(u); }
  }
  #pragma unroll
  for (int m = 1; m < 8; m <<= 1) {
    a0 += __shfl_xor(a0, m); a1 += __shfl_xor(a1, m); a2 += __shfl_xor(a2, m);
    a3 += __shfl_xor(a3, m); a4 += __shfl_xor(a4, m); a5 += __shfl_xor(a5, m);
  }
  __shared__ float sh[4][8][FIN];
  if (sl < FIN) {
    float v = (sl == 0) ? a0 : (sl == 1) ? a1 : (sl == 2) ? a2 : (sl == 3) ? a3 : (sl == 4) ? a4 : a5;
    sh[w][nd][sl] = v;
  }
  #pragma unroll
  for (int nd2 = 0; nd2 < 8; ++nd2) {
    int node = blockIdx.x * 32 + w * 8 + nd2;
    if (node >= n) break;
    float h = bb1;
    #pragma unroll
    for (int k = 0; k < FIN; ++k) h = fmaf(sh[w][nd2][k], w1r[k], h);
    t1[(size_t)node * 64 + lane] = f2b(fmaxf(h, 0.f));
  }
}

// ---------------- k_lin: hr = t1 @ W2 + b2  (bf16 in, bf16 out) ----------------
__global__ __launch_bounds__(256) void k_lin(const ushort_t* __restrict__ in,
    const float* __restrict__ W, const float* __restrict__ b,
    ushort_t* __restrict__ out, int n) {
  __shared__ float sh[4][64];
  int t = threadIdx.x, w = t >> 6, lane = t & 63;
  float wr[64];
  #pragma unroll
  for (int k = 0; k < 64; ++k) wr[k] = W[k * 64 + lane];
  float bb = b[lane];
  int nw = gridDim.x * 4;
  int wid = blockIdx.x * 4 + w;
  const float4* s4 = (const float4*)(&sh[w][0]);
  float vcur = 0.f;
  if (wid < n) vcur = b2f(in[(size_t)wid * 64 + lane]);
  for (int i = wid; i < n; i += nw) {
    int inext = i + nw;
    float vnext = 0.f;
    if (inext < n) vnext = b2f(in[(size_t)inext * 64 + lane]);
    sh[w][lane] = vcur;
    float p0 = bb, p1 = 0, p2 = 0, p3 = 0;
    #pragma unroll
    for (int q = 0; q < 16; ++q) {
      float4 hv = s4[q];
      p0 = fmaf(hv.x, wr[4 * q + 0], p0);
      p1 = fmaf(hv.y, wr[4 * q + 1], p1);
      p2 = fmaf(hv.z, wr[4 * q + 2], p2);
      p3 = fmaf(hv.w, wr[4 * q + 3], p3);
    }
    out[(size_t)i * 64 + lane] = f2b((p0 + p1) + (p2 + p3));
    vcur = vnext;
  }
}

// ---------------- k_agg64: 8 slots x 8 lanes, uint4 rows, unroll2 ----------------
#define ACC8(u) { a0 += blo(u.x); a1 += bhi(u.x); a2 += blo(u.y); a3 += bhi(u.y); \
                  a4 += blo(u.z); a5 += bhi(u.z); a6 += blo(u.w); a7 += bhi(u.w); }
__global__ __launch_bounds__(256) void k_agg64(const ushort_t* __restrict__ hb,
    const int* __restrict__ off, const int* __restrict__ csr,
    ushort_t* __restrict__ aggb, int n) {
  int t = threadIdx.x, w = t >> 6, lane = t & 63;
  int i = blockIdx.x * 4 + w;
  if (i >= n) return;
  int grp = lane >> 3, sl = lane & 7;
  int e0 = off[i], e1 = off[i + 1];
  const uint4* hb4 = (const uint4*)hb;
  float a0 = 0, a1 = 0, a2 = 0, a3 = 0, a4 = 0, a5 = 0, a6 = 0, a7 = 0;
  int e = e0 + grp;
  for (; e + 8 < e1; e += 16) {
    int sa = csr[e], sb = csr[e + 8];
    uint4 ua = hb4[(size_t)sa * 8 + sl];
    uint4 ub = hb4[(size_t)sb * 8 + sl];
    ACC8(ua); ACC8(ub);
  }
  if (e < e1) {
    int sa = csr[e];
    uint4 ua = hb4[(size_t)sa * 8 + sl];
    ACC8(ua);
  }
  #pragma unroll
  for (int m = 8; m < 64; m <<= 1) {
    a0 += __shfl_xor(a0, m); a1 += __shfl_xor(a1, m); a2 += __shfl_xor(a2, m);
    a3 += __shfl_xor(a3, m); a4 += __shfl_xor(a4, m); a5 += __shfl_xor(a5, m);
    a6 += __shfl_xor(a6, m); a7 += __shfl_xor(a7, m);
  }
  if (grp == 0) {
    uint4 us = hb4[(size_t)i * 8 + sl];
    ACC8(us);
    uint4 o;
    o.x = pk2(a0, a1); o.y = pk2(a2, a3); o.z = pk2(a4, a5); o.w = pk2(a6, a7);
    ((uint4*)aggb)[(size_t)i * 8 + sl] = o;
  }
}

// ---------------- k_mlp2: zb = relu(aggb@W3+b3)@W4+b4  (bf16 in/out) ----------------
__global__ __launch_bounds__(256) void k_mlp2(const ushort_t* __restrict__ aggb,
    const float* __restrict__ W3, const float* __restrict__ b3,
    const float* __restrict__ W4, const float* __restrict__ b4,
    ushort_t* __restrict__ zb, int n) {
  __shared__ float sh[4][64];
  int t = threadIdx.x, w = t >> 6, lane = t & 63;
  float w3r[64], w4r[64];
  #pragma unroll
  for (int k = 0; k < 64; ++k) { w3r[k] = W3[k * 64 + lane]; w4r[k] = W4[k * 64 + lane]; }
  float bb3 = b3[lane], bb4 = b4[lane];
  int nw = gridDim.x * 4;
  int wid = blockIdx.x * 4 + w;
  const float4* s4 = (const float4*)(&sh[w][0]);
  float vcur = 0.f;
  if (wid < n) vcur = b2f(aggb[(size_t)wid * 64 + lane]);
  for (int i = wid; i < n; i += nw) {
    int inext = i + nw;
    float vnext = 0.f;
    if (inext < n) vnext = b2f(aggb[(size_t)inext * 64 + lane]);
    sh[w][lane] = vcur;
    float p0 = bb3, p1 = 0, p2 = 0, p3 = 0;
    #pragma unroll
    for (int q = 0; q < 16; ++q) {
      float4 hv = s4[q];
      p0 = fmaf(hv.x, w3r[4 * q + 0], p0);
      p1 = fmaf(hv.y, w3r[4 * q + 1], p1);
      p2 = fmaf(hv.z, w3r[4 * q + 2], p2);
      p3 = fmaf(hv.w, w3r[4 * q + 3], p3);
    }
    float h1 = fmaxf((p0 + p1) + (p2 + p3), 0.f);
    sh[w][lane] = h1;
    p0 = bb4; p1 = 0; p2 = 0; p3 = 0;
    #pragma unroll
    for (int q = 0; q < 16; ++q) {
      float4 hv = s4[q];
      p0 = fmaf(hv.x, w4r[4 * q + 0], p0);
      p1 = fmaf(hv.y, w4r[4 * q + 1], p1);
      p2 = fmaf(hv.z, w4r[4 * q + 2], p2);
      p3 = fmaf(hv.w, w4r[4 * q + 3], p3);
    }
    zb[(size_t)i * 64 + lane] = f2b((p0 + p1) + (p2 + p3));
    vcur = vnext;
  }
}

// ---------------- graph LayerNorm stats over bf16 rows ----------------
__global__ __launch_bounds__(256) void k_ln_statsb(const ushort_t* __restrict__ h,
    const int* __restrict__ gstart, float* __restrict__ gmean, float* __restrict__ ginv) {
  int g = blockIdx.x;
  int s0 = gstart[g], s1 = gstart[g + 1];
  const uint2* p2 = (const uint2*)h;
  size_t j0 = (size_t)s0 * 16, j1 = (size_t)s1 * 16;
  float s = 0.f, ss = 0.f;
  for (size_t j = j0 + threadIdx.x; j < j1; j += 256) {
    uint2 u = p2[j];
    float v0 = blo(u.x), v1 = bhi(u.x), v2 = blo(u.y), v3 = bhi(u.y);
    s += (v0 + v1) + (v2 + v3);
    ss += v0 * v0 + v1 * v1 + v2 * v2 + v3 * v3;
  }
  __shared__ float l1[256], l2[256];
  l1[threadIdx.x] = s; l2[threadIdx.x] = ss;
  __syncthreads();
  for (int o = 128; o > 0; o >>= 1) {
    if (threadIdx.x < o) { l1[threadIdx.x] += l1[threadIdx.x + o]; l2[threadIdx.x] += l2[threadIdx.x + o]; }
    __syncthreads();
  }
  if (threadIdx.x == 0) {
    float cnt = (float)(s1 - s0);
    float norm = fmaxf(cnt, 1.f) * 64.f;
    float mean = l1[0] / norm;
    float var = l2[0] / norm - mean * mean;
    var = fmaxf(var, 0.f);
    gmean[g] = mean;
    ginv[g] = rsqrtf(var + 1e-5f);
  }
}

// ---------------- LN apply + relu : bf16 -> bf16 ----------------
__global__ void k_ln_apply_relu(const ushort_t* __restrict__ hr, const int* __restrict__ batch,
    const float* __restrict__ gmean, const float* __restrict__ ginv,
    const float* __restrict__ w, const float* __restrict__ bb,
    ushort_t* __restrict__ hb, int n) {
  int tt = blockIdx.x * 256 + threadIdx.x;
  if (tt >= n * 8) return;
  int i = tt >> 3, q = tt & 7;
  int g = batch[i];
  float mean = gmean[g], inv = ginv[g];
  uint4 u = ((const uint4*)hr)[tt];
  float4 w0 = *(const float4*)(w + q * 8);
  float4 w1 = *(const float4*)(w + q * 8 + 4);
  float4 c0 = *(const float4*)(bb + q * 8);
  float4 c1 = *(const float4*)(bb + q * 8 + 4);
  uint4 o;
  o.x = pk2(fmaxf((blo(u.x) - mean) * inv * w0.x + c0.x, 0.f),
            fmaxf((bhi(u.x) - mean) * inv * w0.y + c0.y, 0.f));
  o.y = pk2(fmaxf((blo(u.y) - mean) * inv * w0.z + c0.z, 0.f),
            fmaxf((bhi(u.y) - mean) * inv * w0.w + c0.w, 0.f));
  o.z = pk2(fmaxf((blo(u.z) - mean) * inv * w1.x + c1.x, 0.f),
            fmaxf((bhi(u.z) - mean) * inv * w1.y + c1.y, 0.f));
  o.w = pk2(fmaxf((blo(u.w) - mean) * inv * w1.z + c1.z, 0.f),
            fmaxf((bhi(u.w) - mean) * inv * w1.w + c1.w, 0.f));
  ((uint4*)hb)[tt] = o;
}

// ---------------- pool: emb = sum(relu(ln2(zb))) + mean ----------------
__global__ __launch_bounds__(256) void k_pool(const ushort_t* __restrict__ zb,
    const int* __restrict__ gstart, const float* __restrict__ gmean, const float* __restrict__ ginv,
    const float* __restrict__ w, const float* __restrict__ bb, float* __restrict__ emb) {
  int g = blockIdx.x;
  int s0 = gstart[g], s1 = gstart[g + 1];
  int t = threadIdx.x, c2 = t & 31, sub = t >> 5;
  float mean = gmean[g], inv = ginv[g];
  float w0 = w[c2 * 2], w1 = w[c2 * 2 + 1], b0 = bb[c2 * 2], b1v = bb[c2 * 2 + 1];
  float acc0 = 0.f, acc1 = 0.f;
  const unsigned* zp = (const unsigned*)zb;
  for (int i = s0 + sub; i < s1; i += 8) {
    unsigned u = zp[(size_t)i * 32 + c2];
    acc0 += fmaxf((blo(u) - mean) * inv * w0 + b0, 0.f);
    acc1 += fmaxf((bhi(u) - mean) * inv * w1 + b1v, 0.f);
  }
  __shared__ float l0[256], l1[256];
  l0[t] = acc0; l1[t] = acc1;
  __syncthreads();
  if (sub == 0) {
    float t0 = 0.f, t1v = 0.f;
    #pragma unroll
    for (int s = 0; s < 8; ++s) { t0 += l0[s * 32 + c2]; t1v += l1[s * 32 + c2]; }
    float cnt = fmaxf((float)(s1 - s0), 1.f);
    emb[g * 64 + c2 * 2]     = t0 + t0 / cnt;
    emb[g * 64 + c2 * 2 + 1] = t1v + t1v / cnt;
  }
}

// ---------------- head MLP ----------------
__global__ __launch_bounds__(128) void k_head(const float* __restrict__ emb1,
    const float* __restrict__ emb2, const float* __restrict__ d1, const float* __restrict__ d2,
    const float* __restrict__ Wf1, const float* __restrict__ bf1,
    const float* __restrict__ Wf2, const float* __restrict__ bf2,
    const float* __restrict__ Wo, const float* __restrict__ bo, float* __restrict__ out) {
  int g = blockIdx.x, t = threadIdx.x;
  __shared__ float v[138], h1s[128], h2s[64];
  if (t < 64) v[t] = emb1[g * 64 + t];
  else v[t] = emb2[g * 64 + (t - 64)];
  if (t < 5) v[128 + t] = d1[g * 5 + t];
  else if (t < 10) v[133 + (t - 5)] = d2[g * 5 + (t - 5)];
  __syncthreads();
  float a = bf1[t];
  for (int k = 0; k < 138; ++k) a = fmaf(v[k], Wf1[k * 128 + t], a);
  h1s[t] = fmaxf(a, 0.f);
  __syncthreads();
  if (t < 64) {
    float a2 = bf2[t];
    #pragma unroll 8
    for (int k = 0; k < 128; ++k) a2 = fmaf(h1s[k], Wf2[k * 64 + t], a2);
    h2s[t] = fmaxf(a2, 0.f);
  }
  __syncthreads();
  if (t == 0) {
    float s = bo[0];
    for (int k = 0; k < 64; ++k) s += h2s[k] * Wo[k];
    out[g] = s;
  }
}

extern "C" void kernel_launch(void* const* d_in, const int* in_sizes, int n_in,
                              void* d_out, int out_size, void* d_ws, size_t ws_size,
                              hipStream_t stream) {
  const float* x1     = (const float*)d_in[0];
  const int*   ei1    = (const int*)d_in[1];
  const int*   batch1 = (const int*)d_in[2];
  const float* x2     = (const float*)d_in[3];
  const int*   ei2    = (const int*)d_in[4];
  const int*   batch2 = (const int*)d_in[5];
  const float* d1     = (const float*)d_in[6];
  const float* d2     = (const float*)d_in[7];
  const float* W1  = (const float*)d_in[8],  *b1  = (const float*)d_in[9];
  const float* W2  = (const float*)d_in[10], *b2  = (const float*)d_in[11];
  const float* ln1w = (const float*)d_in[12], *ln1b = (const float*)d_in[13];
  const float* W3  = (const float*)d_in[14], *b3  = (const float*)d_in[15];
  const float* W4  = (const float*)d_in[16], *b4  = (const float*)d_in[17];
  const float* ln2w = (const float*)d_in[18], *ln2b = (const float*)d_in[19];
  const float* Wf1 = (const float*)d_in[20], *bf1 = (const float*)d_in[21];
  const float* Wf2 = (const float*)d_in[22], *bf2 = (const float*)d_in[23];
  const float* Wo  = (const float*)d_in[24], *bo  = (const float*)d_in[25];
  float* out = (float*)d_out;

  const int N = in_sizes[0] / FIN;
  const int G = in_sizes[6] / 5;
  const int E1 = in_sizes[1] / 2;
  const int E2 = in_sizes[4] / 2;
  const int Emax = (E1 > E2) ? E1 : E2;
  const int NBUK = (N + 1023) >> 10;   // <= 256 (requires N <= 262144; src fits 18 bits)

  char* p = (char*)d_ws;
  auto alloc = [&](size_t bytes) { void* r = p; p += (bytes + 255) & ~(size_t)255; return r; };
  int*      off    = (int*)alloc((size_t)(N + 1) * 4);
  int*      ecur   = (int*)alloc(256 * 4);
  int*      ebase  = (int*)alloc(257 * 4);
  int*      csr    = (int*)alloc((size_t)Emax * 4);
  int*      gstart = (int*)alloc((size_t)(G + 1) * 4);
  float*    gmean  = (float*)alloc((size_t)G * 4);
  float*    ginv   = (float*)alloc((size_t)G * 4);
  unsigned* xb     = (unsigned*)alloc((size_t)N * 16);       // bf16x8 padded rows
  ushort_t* t1     = (ushort_t*)alloc((size_t)N * 64 * 2);   // aliased: aggb, ebuf
  ushort_t* hr     = (ushort_t*)alloc((size_t)N * 64 * 2);   // aliased: zb
  ushort_t* hb     = (ushort_t*)alloc((size_t)N * 64 * 2);
  float*    emb1   = (float*)alloc((size_t)G * 64 * 4);
  float*    emb2   = (float*)alloc((size_t)G * 64 * 4);
  ushort_t* aggb = t1;
  ushort_t* zb   = hr;
  unsigned* ebuf = (unsigned*)t1;   // CSR-build phase only; t1 written after bcsr

  const int GRID_N  = (N + 255) / 256;
  const int GRID_W  = (N + 3) / 4;
  const int GRID_G1 = (N + 31) / 32;
  const int GRID_A  = (N * 8 + 255) / 256;
  const int GRID_P  = (N * 4 + 255) / 256;

  auto run_graph = [&](const float* x, const int* ei, const int* batch, int E, float* emb) {
    const int* src = ei;
    const int* dst = ei + E;
    const int SCAT = (E + TILE - 1) / TILE;
    k_binit<<<1, 256, 0, stream>>>(ecur, off, NBUK, N, E);
    k_bscatter<<<SCAT, 256, 0, stream>>>(src, dst, ecur, ebuf, E, NBUK);
    k_bscan2<<<1, 256, 0, stream>>>(ecur, ebase, NBUK);
    k_bcsr<<<NBUK, 256, 0, stream>>>(ebuf, ecur, ebase, off, csr, N);
    k_bounds<<<GRID_N, 256, 0, stream>>>(batch, gstart, N, G);
    k_xpack<<<GRID_P, 256, 0, stream>>>(x, xb, N);

    k_gin1a<<<GRID_G1, 256, 0, stream>>>((const uint4*)xb, off, csr, W1, b1, t1, N);
    k_lin<<<2048, 256, 0, stream>>>(t1, W2, b2, hr, N);
    k_ln_statsb<<<G, 256, 0, stream>>>(hr, gstart, gmean, ginv);
    k_ln_apply_relu<<<GRID_A, 256, 0, stream>>>(hr, batch, gmean, ginv, ln1w, ln1b, hb, N);
    k_agg64<<<GRID_W, 256, 0, stream>>>(hb, off, csr, aggb, N);
    k_mlp2<<<2048, 256, 0, stream>>>(aggb, W3, b3, W4, b4, zb, N);
    k_ln_statsb<<<G, 256, 0, stream>>>(zb, gstart, gmean, ginv);
    k_pool<<<G, 256, 0, stream>>>(zb, gstart, gmean, ginv, ln2w, ln2b, emb);
  };

  run_graph(x1, ei1, batch1, E1, emb1);
  run_graph(x2, ei2, batch2, E2, emb2);
  k_head<<<G, 128, 0, stream>>>(emb1, emb2, d1, d2, Wf1, bf1, Wf2, bf2, Wo, bo, out);
}

// Round 5
// 653.024 us; speedup vs baseline: 3.9003x; 1.4476x over previous
//
#include <hip/hip_runtime.h>

typedef unsigned short ushort_t;
typedef __attribute__((ext_vector_type(8))) short bf16x8;
typedef __attribute__((ext_vector_type(4))) float f32x4;

#define FIN 6
#define CAP 20480      // per-bucket edge capacity (mean 16384 at E=4M, N=250k)

__device__ __forceinline__ float blo(unsigned u) { return __uint_as_float(u << 16); }
__device__ __forceinline__ float bhi(unsigned u) { return __uint_as_float(u & 0xffff0000u); }
__device__ __forceinline__ ushort_t f2b(float f) {
  unsigned u = __float_as_uint(f);
  unsigned r = (u + 0x7fffu + ((u >> 16) & 1u)) >> 16;
  return (ushort_t)r;
}
__device__ __forceinline__ float b2f(ushort_t s) { return __uint_as_float(((unsigned)s) << 16); }
__device__ __forceinline__ unsigned pk2(float lo, float hi) {
  return ((unsigned)f2b(hi) << 16) | (unsigned)f2b(lo);
}
union U4F { uint4 u; bf16x8 v; };
__device__ __forceinline__ bf16x8 asfrag(uint4 u) { U4F x; x.u = u; return x.v; }

// ================= bucketed CSR build =================
#define EPT 32
#define TILE 8192

__global__ void k_binit(int* __restrict__ ecur, int* __restrict__ off, int nbuk, int N, int E) {
  int t = threadIdx.x;
  if (t < nbuk) ecur[t] = t * CAP;
  if (t == 0) off[N] = E;
}

__global__ __launch_bounds__(256) void k_bscatter(const int* __restrict__ src,
    const int* __restrict__ dst, int* __restrict__ ecur,
    unsigned* __restrict__ ebuf, int E, int nbuk) {
  __shared__ int cnt[256];
  __shared__ int gbase[256];
  int t = threadIdx.x;
  cnt[t] = 0;
  __syncthreads();
  int base = blockIdx.x * TILE;
  unsigned pk[EPT];   // bucket | rank<<8
  unsigned pv[EPT];   // (dst&1023)<<18 | src
  #pragma unroll
  for (int k = 0; k < EPT; ++k) {
    int e = base + k * 256 + t;
    if (e < E) {
      int d = dst[e];
      int b = d >> 10;
      int r = atomicAdd(&cnt[b], 1);
      pk[k] = (unsigned)b | ((unsigned)r << 8);
      pv[k] = ((unsigned)(d & 1023) << 18) | (unsigned)src[e];
    } else {
      pk[k] = 0xFFFFFFFFu;
    }
  }
  __syncthreads();
  if (t < nbuk && cnt[t] > 0) gbase[t] = atomicAdd(&ecur[t], cnt[t]);
  __syncthreads();
  #pragma unroll
  for (int k = 0; k < EPT; ++k) {
    if (pk[k] != 0xFFFFFFFFu) {
      int b = pk[k] & 255;
      int r = pk[k] >> 8;
      ebuf[gbase[b] + r] = pv[k];
    }
  }
}

__global__ __launch_bounds__(256) void k_bscan2(const int* __restrict__ ecur,
    int* __restrict__ ebase, int nbuk) {
  __shared__ int lds[256];
  int t = threadIdx.x;
  int s = (t < nbuk) ? (ecur[t] - t * CAP) : 0;
  lds[t] = s; __syncthreads();
  int acc = s;
  for (int o = 1; o < 256; o <<= 1) {
    int add = (t >= o) ? lds[t - o] : 0;
    __syncthreads();
    acc += add; lds[t] = acc;
    __syncthreads();
  }
  if (t < nbuk) ebase[t] = acc - s;
}

__global__ __launch_bounds__(256) void k_bcsr(const unsigned* __restrict__ ebuf,
    const int* __restrict__ ecur, const int* __restrict__ ebase,
    int* __restrict__ off, int* __restrict__ csr, int N) {
  __shared__ int hist[1024];
  __shared__ int lofs[1024];
  __shared__ int sc[256];
  int b = blockIdx.x, t = threadIdx.x;
  int nb0 = b << 10;
  int bn = N - nb0; if (bn > 1024) bn = 1024;
  int s_beg = b * CAP, s_end = ecur[b];
  int base = ebase[b];
  #pragma unroll
  for (int k = 0; k < 4; ++k) hist[t * 4 + k] = 0;
  __syncthreads();
  for (int e = s_beg + t; e < s_end; e += 256) atomicAdd(&hist[ebuf[e] >> 18], 1);
  __syncthreads();
  int h0 = hist[t * 4 + 0], h1 = hist[t * 4 + 1], h2 = hist[t * 4 + 2], h3 = hist[t * 4 + 3];
  int s = h0 + h1 + h2 + h3;
  sc[t] = s; __syncthreads();
  int acc = s;
  for (int o = 1; o < 256; o <<= 1) {
    int add = (t >= o) ? sc[t - o] : 0;
    __syncthreads();
    acc += add; sc[t] = acc;
    __syncthreads();
  }
  int run = acc - s;
  lofs[t * 4 + 0] = run; run += h0;
  lofs[t * 4 + 1] = run; run += h1;
  lofs[t * 4 + 2] = run; run += h2;
  lofs[t * 4 + 3] = run;
  __syncthreads();
  #pragma unroll
  for (int k = 0; k < 4; ++k) {
    int j = t * 4 + k;
    if (j < bn) off[nb0 + j] = base + lofs[j];
  }
  __syncthreads();
  for (int e = s_beg + t; e < s_end; e += 256) {
    unsigned p = ebuf[e];
    int r = atomicAdd(&lofs[p >> 18], 1);
    csr[base + r] = (int)(p & 0x3FFFFu);
  }
}

__global__ void k_bounds(const int* __restrict__ batch, int* __restrict__ gstart, int n, int G) {
  int i = blockIdx.x * 256 + threadIdx.x;
  if (i >= n) return;
  int b = batch[i];
  if (i == 0) { for (int g = 0; g <= b; ++g) gstart[g] = 0; }
  else { int pb = batch[i - 1]; for (int g = pb + 1; g <= b; ++g) gstart[g] = i; }
  if (i == n - 1) { for (int g = b + 1; g <= G; ++g) gstart[g] = n; }
}

// ---------------- pack x fp32[N,6] -> bf16-padded uint4 rows [N,8ch] ----------------
__global__ void k_xpack(const float* __restrict__ x, unsigned* __restrict__ xb, int n) {
  int tt = blockIdx.x * 256 + threadIdx.x;
  if (tt >= n * 4) return;
  int i = tt >> 2, k = tt & 3;
  unsigned v = 0;
  if (k < 3) {
    float2 f = *(const float2*)(x + (size_t)i * 6 + k * 2);
    v = pk2(f.x, f.y);
  }
  xb[tt] = v;
}

// ---------------- pack weights into MFMA A-fragments (W^T) ----------------
// layout: wfrag[w][mt][kh][lane] (uint4 = 8 bf16); lane l: g=l>>4,c=l&15
// elems i: W[kh*32 + g*8 + i][mt*16 + c]
__global__ void k_wpack(const float* __restrict__ W2, const float* __restrict__ W3,
                        const float* __restrict__ W4, uint4* __restrict__ wfrag) {
  int idx = blockIdx.x * 256 + threadIdx.x;
  if (idx >= 3 * 512) return;
  int widx = idx >> 9, rem = idx & 511;
  int mt = rem >> 7, kh = (rem >> 6) & 1, l = rem & 63;
  int g = l >> 4, c = l & 15;
  const float* W = (widx == 0) ? W2 : (widx == 1) ? W3 : W4;
  int k0 = kh * 32 + g * 8;
  int col = mt * 16 + c;
  uint4 v;
  v.x = pk2(W[(k0 + 0) * 64 + col], W[(k0 + 1) * 64 + col]);
  v.y = pk2(W[(k0 + 2) * 64 + col], W[(k0 + 3) * 64 + col]);
  v.z = pk2(W[(k0 + 4) * 64 + col], W[(k0 + 5) * 64 + col]);
  v.w = pk2(W[(k0 + 6) * 64 + col], W[(k0 + 7) * 64 + col]);
  wfrag[idx] = v;
}

// ---------------- GIN1a: gather xb + Linear(6->64) + relu -> t1 (bf16) ----------------
#define ACC6(u) { a0 += blo(u.x); a1 += bhi(u.x); a2 += blo(u.y); a3 += bhi(u.y); a4 += blo(u.z); a5 += bhi(u.z); }
__global__ __launch_bounds__(256) void k_gin1a(const uint4* __restrict__ xb4,
    const int* __restrict__ off, const int* __restrict__ csr,
    const float* __restrict__ W1, const float* __restrict__ b1,
    ushort_t* __restrict__ t1, int n) {
  int t = threadIdx.x, w = t >> 6, lane = t & 63;
  int nd = lane >> 3, sl = lane & 7;
  int i = blockIdx.x * 32 + w * 8 + nd;

  float w1r[FIN];
  #pragma unroll
  for (int k = 0; k < FIN; ++k) w1r[k] = W1[k * 64 + lane];
  float bb1 = b1[lane];

  float a0 = 0, a1 = 0, a2 = 0, a3 = 0, a4 = 0, a5 = 0;
  if (i < n) {
    int e0 = off[i], e1 = off[i + 1];
    int e = e0 + sl;
    for (; e + 8 < e1; e += 16) {
      uint4 u = xb4[csr[e]];
      uint4 v = xb4[csr[e + 8]];
      ACC6(u); ACC6(v);
    }
    if (e < e1) { uint4 u = xb4[csr[e]]; ACC6(u); }
    if (sl == 0) { uint4 u = xb4[i]; ACC6(u); }
  }
  #pragma unroll
  for (int m = 1; m < 8; m <<= 1) {
    a0 += __shfl_xor(a0, m); a1 += __shfl_xor(a1, m); a2 += __shfl_xor(a2, m);
    a3 += __shfl_xor(a3, m); a4 += __shfl_xor(a4, m); a5 += __shfl_xor(a5, m);
  }
  __shared__ float sh[4][8][FIN];
  if (sl < FIN) {
    float v = (sl == 0) ? a0 : (sl == 1) ? a1 : (sl == 2) ? a2 : (sl == 3) ? a3 : (sl == 4) ? a4 : a5;
    sh[w][nd][sl] = v;
  }
  #pragma unroll
  for (int nd2 = 0; nd2 < 8; ++nd2) {
    int node = blockIdx.x * 32 + w * 8 + nd2;
    if (node >= n) break;
    float h = bb1;
    #pragma unroll
    for (int k = 0; k < FIN; ++k) h = fmaf(sh[w][nd2][k], w1r[k], h);
    t1[(size_t)node * 64 + lane] = f2b(fmaxf(h, 0.f));
  }
}

// ---------------- k_lin_mfma: out = in @ W + b  (bf16 in/out), 16 nodes/wave ----------------
// D^T formulation: D[out][node] = sum_k W[k][out]*in[node][k]; A-frag = packed W^T.
__global__ __launch_bounds__(256) void k_lin_mfma(const ushort_t* __restrict__ in,
    const uint4* __restrict__ wf, const float* __restrict__ bias,
    ushort_t* __restrict__ out, int n) {
  __shared__ __align__(16) ushort_t lds[4][16][72];
  int t = threadIdx.x, w = t >> 6, l = t & 63;
  int g = l >> 4, c = l & 15;
  bf16x8 af[4][2];
  #pragma unroll
  for (int mt = 0; mt < 4; ++mt)
    #pragma unroll
    for (int kh = 0; kh < 2; ++kh) af[mt][kh] = asfrag(wf[(mt * 2 + kh) * 64 + l]);
  float bs[4][4];
  #pragma unroll
  for (int mt = 0; mt < 4; ++mt)
    #pragma unroll
    for (int r = 0; r < 4; ++r) bs[mt][r] = bias[mt * 16 + 4 * g + r];

  int ntile = (n + 15) >> 4;
  for (int tau = blockIdx.x * 4 + w; tau < ntile; tau += gridDim.x * 4) {
    int nb = tau << 4;
    int row = nb + c; if (row >= n) row = n - 1;
    const uint4* rp = (const uint4*)(in + (size_t)row * 64);
    bf16x8 bf0 = asfrag(rp[g]);
    bf16x8 bf1 = asfrag(rp[g + 4]);
    f32x4 acc[4];
    #pragma unroll
    for (int mt = 0; mt < 4; ++mt) {
      acc[mt] = (f32x4){bs[mt][0], bs[mt][1], bs[mt][2], bs[mt][3]};
      acc[mt] = __builtin_amdgcn_mfma_f32_16x16x32_bf16(af[mt][0], bf0, acc[mt], 0, 0, 0);
      acc[mt] = __builtin_amdgcn_mfma_f32_16x16x32_bf16(af[mt][1], bf1, acc[mt], 0, 0, 0);
    }
    #pragma unroll
    for (int mt = 0; mt < 4; ++mt) {
      uint2 pv;
      pv.x = pk2(acc[mt][0], acc[mt][1]);
      pv.y = pk2(acc[mt][2], acc[mt][3]);
      *(uint2*)&lds[w][c][mt * 16 + 4 * g] = pv;
    }
    int n2 = l >> 2, ch = (l & 3) * 16;
    uint4 s0 = *(const uint4*)&lds[w][n2][ch];
    uint4 s1 = *(const uint4*)&lds[w][n2][ch + 8];
    int orow = nb + n2;
    if (orow < n) {
      uint4* op = (uint4*)(out + (size_t)orow * 64);
      op[(l & 3) * 2] = s0;
      op[(l & 3) * 2 + 1] = s1;
    }
  }
}

// ---------------- k_mlp2_mfma: z = relu(agg@W3+b3)@W4+b4 (bf16 in/out) ----------------
__global__ __launch_bounds__(256) void k_mlp2_mfma(const ushort_t* __restrict__ aggb,
    const uint4* __restrict__ wf3, const float* __restrict__ b3,
    const uint4* __restrict__ wf4, const float* __restrict__ b4,
    ushort_t* __restrict__ zb, int n) {
  __shared__ __align__(16) ushort_t lds[4][16][72];
  int t = threadIdx.x, w = t >> 6, l = t & 63;
  int g = l >> 4, c = l & 15;
  bf16x8 a3[4][2], a4[4][2];
  #pragma unroll
  for (int mt = 0; mt < 4; ++mt)
    #pragma unroll
    for (int kh = 0; kh < 2; ++kh) {
      a3[mt][kh] = asfrag(wf3[(mt * 2 + kh) * 64 + l]);
      a4[mt][kh] = asfrag(wf4[(mt * 2 + kh) * 64 + l]);
    }
  float bs3[4][4], bs4[4][4];
  #pragma unroll
  for (int mt = 0; mt < 4; ++mt)
    #pragma unroll
    for (int r = 0; r < 4; ++r) {
      bs3[mt][r] = b3[mt * 16 + 4 * g + r];
      bs4[mt][r] = b4[mt * 16 + 4 * g + r];
    }

  int ntile = (n + 15) >> 4;
  for (int tau = blockIdx.x * 4 + w; tau < ntile; tau += gridDim.x * 4) {
    int nb = tau << 4;
    int row = nb + c; if (row >= n) row = n - 1;
    const uint4* rp = (const uint4*)(aggb + (size_t)row * 64);
    bf16x8 bf0 = asfrag(rp[g]);
    bf16x8 bf1 = asfrag(rp[g + 4]);
    f32x4 acc[4];
    #pragma unroll
    for (int mt = 0; mt < 4; ++mt) {
      acc[mt] = (f32x4){bs3[mt][0], bs3[mt][1], bs3[mt][2], bs3[mt][3]};
      acc[mt] = __builtin_amdgcn_mfma_f32_16x16x32_bf16(a3[mt][0], bf0, acc[mt], 0, 0, 0);
      acc[mt] = __builtin_amdgcn_mfma_f32_16x16x32_bf16(a3[mt][1], bf1, acc[mt], 0, 0, 0);
    }
    // relu + stage h1 into LDS [node][chan]
    #pragma unroll
    for (int mt = 0; mt < 4; ++mt) {
      uint2 pv;
      pv.x = pk2(fmaxf(acc[mt][0], 0.f), fmaxf(acc[mt][1], 0.f));
      pv.y = pk2(fmaxf(acc[mt][2], 0.f), fmaxf(acc[mt][3], 0.f));
      *(uint2*)&lds[w][c][mt * 16 + 4 * g] = pv;
    }
    // layer 2 B-frags: lane reads its node's k-slice
    bf16x8 h0 = asfrag(*(const uint4*)&lds[w][c][8 * g]);
    bf16x8 h1 = asfrag(*(const uint4*)&lds[w][c][8 * g + 32]);
    f32x4 ac2[4];
    #pragma unroll
    for (int mt = 0; mt < 4; ++mt) {
      ac2[mt] = (f32x4){bs4[mt][0], bs4[mt][1], bs4[mt][2], bs4[mt][3]};
      ac2[mt] = __builtin_amdgcn_mfma_f32_16x16x32_bf16(a4[mt][0], h0, ac2[mt], 0, 0, 0);
      ac2[mt] = __builtin_amdgcn_mfma_f32_16x16x32_bf16(a4[mt][1], h1, ac2[mt], 0, 0, 0);
    }
    // stage z + coalesced store
    #pragma unroll
    for (int mt = 0; mt < 4; ++mt) {
      uint2 pv;
      pv.x = pk2(ac2[mt][0], ac2[mt][1]);
      pv.y = pk2(ac2[mt][2], ac2[mt][3]);
      *(uint2*)&lds[w][c][mt * 16 + 4 * g] = pv;
    }
    int n2 = l >> 2, ch = (l & 3) * 16;
    uint4 s0 = *(const uint4*)&lds[w][n2][ch];
    uint4 s1 = *(const uint4*)&lds[w][n2][ch + 8];
    int orow = nb + n2;
    if (orow < n) {
      uint4* op = (uint4*)(zb + (size_t)orow * 64);
      op[(l & 3) * 2] = s0;
      op[(l & 3) * 2 + 1] = s1;
    }
  }
}

// ---------------- k_agg64: 8 slots x 8 lanes, uint4 rows, unroll2 ----------------
#define ACC8(u) { a0 += blo(u.x); a1 += bhi(u.x); a2 += blo(u.y); a3 += bhi(u.y); \
                  a4 += blo(u.z); a5 += bhi(u.z); a6 += blo(u.w); a7 += bhi(u.w); }
__global__ __launch_bounds__(256) void k_agg64(const ushort_t* __restrict__ hb,
    const int* __restrict__ off, const int* __restrict__ csr,
    ushort_t* __restrict__ aggb, int n) {
  int t = threadIdx.x, w = t >> 6, lane = t & 63;
  int i = blockIdx.x * 4 + w;
  if (i >= n) return;
  int grp = lane >> 3, sl = lane & 7;
  int e0 = off[i], e1 = off[i + 1];
  const uint4* hb4 = (const uint4*)hb;
  float a0 = 0, a1 = 0, a2 = 0, a3 = 0, a4 = 0, a5 = 0, a6 = 0, a7 = 0;
  int e = e0 + grp;
  for (; e + 8 < e1; e += 16) {
    int sa = csr[e], sb = csr[e + 8];
    uint4 ua = hb4[(size_t)sa * 8 + sl];
    uint4 ub = hb4[(size_t)sb * 8 + sl];
    ACC8(ua); ACC8(ub);
  }
  if (e < e1) {
    int sa = csr[e];
    uint4 ua = hb4[(size_t)sa * 8 + sl];
    ACC8(ua);
  }
  #pragma unroll
  for (int m = 8; m < 64; m <<= 1) {
    a0 += __shfl_xor(a0, m); a1 += __shfl_xor(a1, m); a2 += __shfl_xor(a2, m);
    a3 += __shfl_xor(a3, m); a4 += __shfl_xor(a4, m); a5 += __shfl_xor(a5, m);
    a6 += __shfl_xor(a6, m); a7 += __shfl_xor(a7, m);
  }
  if (grp == 0) {
    uint4 us = hb4[(size_t)i * 8 + sl];
    ACC8(us);
    uint4 o;
    o.x = pk2(a0, a1); o.y = pk2(a2, a3); o.z = pk2(a4, a5); o.w = pk2(a6, a7);
    ((uint4*)aggb)[(size_t)i * 8 + sl] = o;
  }
}

// ---------------- graph LayerNorm stats over bf16 rows ----------------
__global__ __launch_bounds__(256) void k_ln_statsb(const ushort_t* __restrict__ h,
    const int* __restrict__ gstart, float* __restrict__ gmean, float* __restrict__ ginv) {
  int g = blockIdx.x;
  int s0 = gstart[g], s1 = gstart[g + 1];
  const uint2* p2 = (const uint2*)h;
  size_t j0 = (size_t)s0 * 16, j1 = (size_t)s1 * 16;
  float s = 0.f, ss = 0.f;
  for (size_t j = j0 + threadIdx.x; j < j1; j += 256) {
    uint2 u = p2[j];
    float v0 = blo(u.x), v1 = bhi(u.x), v2 = blo(u.y), v3 = bhi(u.y);
    s += (v0 + v1) + (v2 + v3);
    ss += v0 * v0 + v1 * v1 + v2 * v2 + v3 * v3;
  }
  __shared__ float l1[256], l2[256];
  l1[threadIdx.x] = s; l2[threadIdx.x] = ss;
  __syncthreads();
  for (int o = 128; o > 0; o >>= 1) {
    if (threadIdx.x < o) { l1[threadIdx.x] += l1[threadIdx.x + o]; l2[threadIdx.x] += l2[threadIdx.x + o]; }
    __syncthreads();
  }
  if (threadIdx.x == 0) {
    float cnt = (float)(s1 - s0);
    float norm = fmaxf(cnt, 1.f) * 64.f;
    float mean = l1[0] / norm;
    float var = l2[0] / norm - mean * mean;
    var = fmaxf(var, 0.f);
    gmean[g] = mean;
    ginv[g] = rsqrtf(var + 1e-5f);
  }
}

// ---------------- LN apply + relu : bf16 -> bf16 ----------------
__global__ void k_ln_apply_relu(const ushort_t* __restrict__ hr, const int* __restrict__ batch,
    const float* __restrict__ gmean, const float* __restrict__ ginv,
    const float* __restrict__ w, const float* __restrict__ bb,
    ushort_t* __restrict__ hb, int n) {
  int tt = blockIdx.x * 256 + threadIdx.x;
  if (tt >= n * 8) return;
  int i = tt >> 3, q = tt & 7;
  int g = batch[i];
  float mean = gmean[g], inv = ginv[g];
  uint4 u = ((const uint4*)hr)[tt];
  float4 w0 = *(const float4*)(w + q * 8);
  float4 w1 = *(const float4*)(w + q * 8 + 4);
  float4 c0 = *(const float4*)(bb + q * 8);
  float4 c1 = *(const float4*)(bb + q * 8 + 4);
  uint4 o;
  o.x = pk2(fmaxf((blo(u.x) - mean) * inv * w0.x + c0.x, 0.f),
            fmaxf((bhi(u.x) - mean) * inv * w0.y + c0.y, 0.f));
  o.y = pk2(fmaxf((blo(u.y) - mean) * inv * w0.z + c0.z, 0.f),
            fmaxf((bhi(u.y) - mean) * inv * w0.w + c0.w, 0.f));
  o.z = pk2(fmaxf((blo(u.z) - mean) * inv * w1.x + c1.x, 0.f),
            fmaxf((bhi(u.z) - mean) * inv * w1.y + c1.y, 0.f));
  o.w = pk2(fmaxf((blo(u.w) - mean) * inv * w1.z + c1.z, 0.f),
            fmaxf((bhi(u.w) - mean) * inv * w1.w + c1.w, 0.f));
  ((uint4*)hb)[tt] = o;
}

// ---------------- pool: emb = sum(relu(ln2(zb))) + mean ----------------
__global__ __launch_bounds__(256) void k_pool(const ushort_t* __restrict__ zb,
    const int* __restrict__ gstart, const float* __restrict__ gmean, const float* __restrict__ ginv,
    const float* __restrict__ w, const float* __restrict__ bb, float* __restrict__ emb) {
  int g = blockIdx.x;
  int s0 = gstart[g], s1 = gstart[g + 1];
  int t = threadIdx.x, c2 = t & 31, sub = t >> 5;
  float mean = gmean[g], inv = ginv[g];
  float w0 = w[c2 * 2], w1 = w[c2 * 2 + 1], b0 = bb[c2 * 2], b1v = bb[c2 * 2 + 1];
  float acc0 = 0.f, acc1 = 0.f;
  const unsigned* zp = (const unsigned*)zb;
  for (int i = s0 + sub; i < s1; i += 8) {
    unsigned u = zp[(size_t)i * 32 + c2];
    acc0 += fmaxf((blo(u) - mean) * inv * w0 + b0, 0.f);
    acc1 += fmaxf((bhi(u) - mean) * inv * w1 + b1v, 0.f);
  }
  __shared__ float l0[256], l1[256];
  l0[t] = acc0; l1[t] = acc1;
  __syncthreads();
  if (sub == 0) {
    float t0 = 0.f, t1v = 0.f;
    #pragma unroll
    for (int s = 0; s < 8; ++s) { t0 += l0[s * 32 + c2]; t1v += l1[s * 32 + c2]; }
    float cnt = fmaxf((float)(s1 - s0), 1.f);
    emb[g * 64 + c2 * 2]     = t0 + t0 / cnt;
    emb[g * 64 + c2 * 2 + 1] = t1v + t1v / cnt;
  }
}

// ---------------- head MLP ----------------
__global__ __launch_bounds__(128) void k_head(const float* __restrict__ emb1,
    const float* __restrict__ emb2, const float* __restrict__ d1, const float* __restrict__ d2,
    const float* __restrict__ Wf1, const float* __restrict__ bf1,
    const float* __restrict__ Wf2, const float* __restrict__ bf2,
    const float* __restrict__ Wo, const float* __restrict__ bo, float* __restrict__ out) {
  int g = blockIdx.x, t = threadIdx.x;
  __shared__ float v[138], h1s[128], h2s[64];
  if (t < 64) v[t] = emb1[g * 64 + t];
  else v[t] = emb2[g * 64 + (t - 64)];
  if (t < 5) v[128 + t] = d1[g * 5 + t];
  else if (t < 10) v[133 + (t - 5)] = d2[g * 5 + (t - 5)];
  __syncthreads();
  float a = bf1[t];
  for (int k = 0; k < 138; ++k) a = fmaf(v[k], Wf1[k * 128 + t], a);
  h1s[t] = fmaxf(a, 0.f);
  __syncthreads();
  if (t < 64) {
    float a2 = bf2[t];
    #pragma unroll 8
    for (int k = 0; k < 128; ++k) a2 = fmaf(h1s[k], Wf2[k * 64 + t], a2);
    h2s[t] = fmaxf(a2, 0.f);
  }
  __syncthreads();
  if (t == 0) {
    float s = bo[0];
    for (int k = 0; k < 64; ++k) s += h2s[k] * Wo[k];
    out[g] = s;
  }
}

extern "C" void kernel_launch(void* const* d_in, const int* in_sizes, int n_in,
                              void* d_out, int out_size, void* d_ws, size_t ws_size,
                              hipStream_t stream) {
  const float* x1     = (const float*)d_in[0];
  const int*   ei1    = (const int*)d_in[1];
  const int*   batch1 = (const int*)d_in[2];
  const float* x2     = (const float*)d_in[3];
  const int*   ei2    = (const int*)d_in[4];
  const int*   batch2 = (const int*)d_in[5];
  const float* d1     = (const float*)d_in[6];
  const float* d2     = (const float*)d_in[7];
  const float* W1  = (const float*)d_in[8],  *b1  = (const float*)d_in[9];
  const float* W2  = (const float*)d_in[10], *b2  = (const float*)d_in[11];
  const float* ln1w = (const float*)d_in[12], *ln1b = (const float*)d_in[13];
  const float* W3  = (const float*)d_in[14], *b3  = (const float*)d_in[15];
  const float* W4  = (const float*)d_in[16], *b4  = (const float*)d_in[17];
  const float* ln2w = (const float*)d_in[18], *ln2b = (const float*)d_in[19];
  const float* Wf1 = (const float*)d_in[20], *bf1 = (const float*)d_in[21];
  const float* Wf2 = (const float*)d_in[22], *bf2 = (const float*)d_in[23];
  const float* Wo  = (const float*)d_in[24], *bo  = (const float*)d_in[25];
  float* out = (float*)d_out;

  const int N = in_sizes[0] / FIN;
  const int G = in_sizes[6] / 5;
  const int E1 = in_sizes[1] / 2;
  const int E2 = in_sizes[4] / 2;
  const int Emax = (E1 > E2) ? E1 : E2;
  const int NBUK = (N + 1023) >> 10;   // <= 256 (requires N <= 262144; src fits 18 bits)

  char* p = (char*)d_ws;
  auto alloc = [&](size_t bytes) { void* r = p; p += (bytes + 255) & ~(size_t)255; return r; };
  int*      off    = (int*)alloc((size_t)(N + 1) * 4);
  int*      ecur   = (int*)alloc(256 * 4);
  int*      ebase  = (int*)alloc(257 * 4);
  int*      csr    = (int*)alloc((size_t)Emax * 4);
  int*      gstart = (int*)alloc((size_t)(G + 1) * 4);
  float*    gmean  = (float*)alloc((size_t)G * 4);
  float*    ginv   = (float*)alloc((size_t)G * 4);
  uint4*    wfrag  = (uint4*)alloc(3 * 512 * 16);            // W2,W3,W4 MFMA fragments
  unsigned* xb     = (unsigned*)alloc((size_t)N * 16);       // bf16x8 padded rows
  ushort_t* t1     = (ushort_t*)alloc((size_t)N * 64 * 2);   // aliased: aggb, ebuf
  ushort_t* hr     = (ushort_t*)alloc((size_t)N * 64 * 2);   // aliased: zb
  ushort_t* hb     = (ushort_t*)alloc((size_t)N * 64 * 2);
  float*    emb1   = (float*)alloc((size_t)G * 64 * 4);
  float*    emb2   = (float*)alloc((size_t)G * 64 * 4);
  ushort_t* aggb = t1;
  ushort_t* zb   = hr;
  unsigned* ebuf = (unsigned*)t1;   // CSR-build phase only; t1 written after bcsr

  const uint4* wf2 = wfrag;
  const uint4* wf3 = wfrag + 512;
  const uint4* wf4 = wfrag + 1024;

  const int GRID_N  = (N + 255) / 256;
  const int GRID_W  = (N + 3) / 4;
  const int GRID_G1 = (N + 31) / 32;
  const int GRID_A  = (N * 8 + 255) / 256;
  const int GRID_P  = (N * 4 + 255) / 256;

  k_wpack<<<6, 256, 0, stream>>>(W2, W3, W4, wfrag);

  auto run_graph = [&](const float* x, const int* ei, const int* batch, int E, float* emb) {
    const int* src = ei;
    const int* dst = ei + E;
    const int SCAT = (E + TILE - 1) / TILE;
    k_binit<<<1, 256, 0, stream>>>(ecur, off, NBUK, N, E);
    k_bscatter<<<SCAT, 256, 0, stream>>>(src, dst, ecur, ebuf, E, NBUK);
    k_bscan2<<<1, 256, 0, stream>>>(ecur, ebase, NBUK);
    k_bcsr<<<NBUK, 256, 0, stream>>>(ebuf, ecur, ebase, off, csr, N);
    k_bounds<<<GRID_N, 256, 0, stream>>>(batch, gstart, N, G);
    k_xpack<<<GRID_P, 256, 0, stream>>>(x, xb, N);

    k_gin1a<<<GRID_G1, 256, 0, stream>>>((const uint4*)xb, off, csr, W1, b1, t1, N);
    k_lin_mfma<<<2048, 256, 0, stream>>>(t1, wf2, b2, hr, N);
    k_ln_statsb<<<G, 256, 0, stream>>>(hr, gstart, gmean, ginv);
    k_ln_apply_relu<<<GRID_A, 256, 0, stream>>>(hr, batch, gmean, ginv, ln1w, ln1b, hb, N);
    k_agg64<<<GRID_W, 256, 0, stream>>>(hb, off, csr, aggb, N);
    k_mlp2_mfma<<<2048, 256, 0, stream>>>(aggb, wf3, b3, wf4, b4, zb, N);
    k_ln_statsb<<<G, 256, 0, stream>>>(zb, gstart, gmean, ginv);
    k_pool<<<G, 256, 0, stream>>>(zb, gstart, gmean, ginv, ln2w, ln2b, emb);
  };

  run_graph(x1, ei1, batch1, E1, emb1);
  run_graph(x2, ei2, batch2, E2, emb2);
  k_head<<<G, 128, 0, stream>>>(emb1, emb2, d1, d2, Wf1, bf1, Wf2, bf2, Wo, bo, out);
}

// Round 6
// 645.231 us; speedup vs baseline: 3.9475x; 1.0121x over previous
//
#include <hip/hip_runtime.h>

typedef unsigned short ushort_t;
typedef __attribute__((ext_vector_type(8))) short bf16x8;
typedef __attribute__((ext_vector_type(4))) float f32x4;

#define FIN 6
#define CAP 20480      // per-bucket edge capacity
#define LNCAP 384      // max nodes/graph staged in LDS

__device__ __forceinline__ float blo(unsigned u) { return __uint_as_float(u << 16); }
__device__ __forceinline__ float bhi(unsigned u) { return __uint_as_float(u & 0xffff0000u); }
__device__ __forceinline__ ushort_t f2b(float f) {
  unsigned u = __float_as_uint(f);
  unsigned r = (u + 0x7fffu + ((u >> 16) & 1u)) >> 16;
  return (ushort_t)r;
}
__device__ __forceinline__ float b2f(ushort_t s) { return __uint_as_float(((unsigned)s) << 16); }
__device__ __forceinline__ unsigned pk2(float lo, float hi) {
  return ((unsigned)f2b(hi) << 16) | (unsigned)f2b(lo);
}
union U4F { uint4 u; bf16x8 v; };
__device__ __forceinline__ bf16x8 asfrag(uint4 u) { U4F x; x.u = u; return x.v; }

// ================= bucketed CSR build =================
#define EPT 32
#define TILE 8192

__global__ void k_binit(int* __restrict__ ecur, int* __restrict__ off, int nbuk, int N, int E) {
  int t = threadIdx.x;
  if (t < nbuk) ecur[t] = t * CAP;
  if (t == 0) off[N] = E;
}

__global__ __launch_bounds__(256) void k_bscatter(const int* __restrict__ src,
    const int* __restrict__ dst, int* __restrict__ ecur,
    unsigned* __restrict__ ebuf, int E, int nbuk) {
  __shared__ int cnt[256];
  __shared__ int gbase[256];
  int t = threadIdx.x;
  cnt[t] = 0;
  __syncthreads();
  int base = blockIdx.x * TILE;
  unsigned pk[EPT];   // bucket | rank<<8
  unsigned pv[EPT];   // (dst&1023)<<18 | src
  #pragma unroll
  for (int k = 0; k < EPT; ++k) {
    int e = base + k * 256 + t;
    if (e < E) {
      int d = dst[e];
      int b = d >> 10;
      int r = atomicAdd(&cnt[b], 1);
      pk[k] = (unsigned)b | ((unsigned)r << 8);
      pv[k] = ((unsigned)(d & 1023) << 18) | (unsigned)src[e];
    } else {
      pk[k] = 0xFFFFFFFFu;
    }
  }
  __syncthreads();
  if (t < nbuk && cnt[t] > 0) gbase[t] = atomicAdd(&ecur[t], cnt[t]);
  __syncthreads();
  #pragma unroll
  for (int k = 0; k < EPT; ++k) {
    if (pk[k] != 0xFFFFFFFFu) {
      int b = pk[k] & 255;
      int r = pk[k] >> 8;
      ebuf[gbase[b] + r] = pv[k];
    }
  }
}

__global__ __launch_bounds__(256) void k_bscan2(const int* __restrict__ ecur,
    int* __restrict__ ebase, int nbuk) {
  __shared__ int lds[256];
  int t = threadIdx.x;
  int s = (t < nbuk) ? (ecur[t] - t * CAP) : 0;
  lds[t] = s; __syncthreads();
  int acc = s;
  for (int o = 1; o < 256; o <<= 1) {
    int add = (t >= o) ? lds[t - o] : 0;
    __syncthreads();
    acc += add; lds[t] = acc;
    __syncthreads();
  }
  if (t < nbuk) ebase[t] = acc - s;
}

__global__ __launch_bounds__(256) void k_bcsr(const unsigned* __restrict__ ebuf,
    const int* __restrict__ ecur, const int* __restrict__ ebase,
    int* __restrict__ off, int* __restrict__ csr, int N) {
  __shared__ int hist[1024];
  __shared__ int lofs[1024];
  __shared__ int sc[256];
  int b = blockIdx.x, t = threadIdx.x;
  int nb0 = b << 10;
  int bn = N - nb0; if (bn > 1024) bn = 1024;
  int s_beg = b * CAP, s_end = ecur[b];
  int base = ebase[b];
  #pragma unroll
  for (int k = 0; k < 4; ++k) hist[t * 4 + k] = 0;
  __syncthreads();
  for (int e = s_beg + t; e < s_end; e += 256) atomicAdd(&hist[ebuf[e] >> 18], 1);
  __syncthreads();
  int h0 = hist[t * 4 + 0], h1 = hist[t * 4 + 1], h2 = hist[t * 4 + 2], h3 = hist[t * 4 + 3];
  int s = h0 + h1 + h2 + h3;
  sc[t] = s; __syncthreads();
  int acc = s;
  for (int o = 1; o < 256; o <<= 1) {
    int add = (t >= o) ? sc[t - o] : 0;
    __syncthreads();
    acc += add; sc[t] = acc;
    __syncthreads();
  }
  int run = acc - s;
  lofs[t * 4 + 0] = run; run += h0;
  lofs[t * 4 + 1] = run; run += h1;
  lofs[t * 4 + 2] = run; run += h2;
  lofs[t * 4 + 3] = run;
  __syncthreads();
  #pragma unroll
  for (int k = 0; k < 4; ++k) {
    int j = t * 4 + k;
    if (j < bn) off[nb0 + j] = base + lofs[j];
  }
  __syncthreads();
  for (int e = s_beg + t; e < s_end; e += 256) {
    unsigned p = ebuf[e];
    int r = atomicAdd(&lofs[p >> 18], 1);
    csr[base + r] = (int)(p & 0x3FFFFu);
  }
}

// ---------------- prep: xpack (N*4 threads) + graph bounds (N threads) ----------------
__global__ void k_prep(const float* __restrict__ x, const int* __restrict__ batch,
                       unsigned* __restrict__ xb, int* __restrict__ gstart, int n, int G) {
  int tt = blockIdx.x * 256 + threadIdx.x;
  if (tt < n * 4) {
    int i = tt >> 2, k = tt & 3;
    unsigned v = 0;
    if (k < 3) {
      float2 f = *(const float2*)(x + (size_t)i * 6 + k * 2);
      v = pk2(f.x, f.y);
    }
    xb[tt] = v;
  }
  if (tt < n) {
    int b = batch[tt];
    if (tt == 0) { for (int g = 0; g <= b; ++g) gstart[g] = 0; }
    else { int pb = batch[tt - 1]; for (int g = pb + 1; g <= b; ++g) gstart[g] = tt; }
    if (tt == n - 1) { for (int g = b + 1; g <= G; ++g) gstart[g] = n; }
  }
}

// ---------------- pack weights into MFMA A-fragments (W^T) ----------------
__global__ void k_wpack(const float* __restrict__ W2, const float* __restrict__ W3,
                        const float* __restrict__ W4, uint4* __restrict__ wfrag) {
  int idx = blockIdx.x * 256 + threadIdx.x;
  if (idx >= 3 * 512) return;
  int widx = idx >> 9, rem = idx & 511;
  int mt = rem >> 7, kh = (rem >> 6) & 1, l = rem & 63;
  int g = l >> 4, c = l & 15;
  const float* W = (widx == 0) ? W2 : (widx == 1) ? W3 : W4;
  int k0 = kh * 32 + g * 8;
  int col = mt * 16 + c;
  uint4 v;
  v.x = pk2(W[(k0 + 0) * 64 + col], W[(k0 + 1) * 64 + col]);
  v.y = pk2(W[(k0 + 2) * 64 + col], W[(k0 + 3) * 64 + col]);
  v.z = pk2(W[(k0 + 4) * 64 + col], W[(k0 + 5) * 64 + col]);
  v.w = pk2(W[(k0 + 6) * 64 + col], W[(k0 + 7) * 64 + col]);
  wfrag[idx] = v;
}

// ---------------- GIN1 fused: gather x + Linear(6->64) + relu + MFMA Linear(64->64) -> hr ----------------
// 32 nodes/block; phase A: 4 waves x 8 nodes gather + 6->64 into LDS (bf16);
// phase B: waves 0,1 run 16x16x32 MFMA tiles + transpose store.
#define ACC6(u) { a0 += blo(u.x); a1 += bhi(u.x); a2 += blo(u.y); a3 += bhi(u.y); a4 += blo(u.z); a5 += bhi(u.z); }
__global__ __launch_bounds__(256) void k_gin1f(const uint4* __restrict__ xb4,
    const int* __restrict__ off, const int* __restrict__ csr,
    const float* __restrict__ W1, const float* __restrict__ b1,
    const uint4* __restrict__ wf2, const float* __restrict__ b2,
    ushort_t* __restrict__ hr, int n) {
  __shared__ __align__(16) ushort_t t1s[32][72];
  __shared__ float sh[4][8][FIN];
  int t = threadIdx.x, w = t >> 6, lane = t & 63;
  int nd = lane >> 3, sl = lane & 7;
  int nb0 = blockIdx.x * 32;
  int i = nb0 + w * 8 + nd;

  float w1r[FIN];
  #pragma unroll
  for (int k = 0; k < FIN; ++k) w1r[k] = W1[k * 64 + lane];
  float bb1 = b1[lane];

  float a0 = 0, a1 = 0, a2 = 0, a3 = 0, a4 = 0, a5 = 0;
  if (i < n) {
    int e0 = off[i], e1 = off[i + 1];
    int e = e0 + sl;
    for (; e + 8 < e1; e += 16) {
      uint4 u = xb4[csr[e]];
      uint4 v = xb4[csr[e + 8]];
      ACC6(u); ACC6(v);
    }
    if (e < e1) { uint4 u = xb4[csr[e]]; ACC6(u); }
    if (sl == 0) { uint4 u = xb4[i]; ACC6(u); }
  }
  #pragma unroll
  for (int m = 1; m < 8; m <<= 1) {
    a0 += __shfl_xor(a0, m); a1 += __shfl_xor(a1, m); a2 += __shfl_xor(a2, m);
    a3 += __shfl_xor(a3, m); a4 += __shfl_xor(a4, m); a5 += __shfl_xor(a5, m);
  }
  if (sl < FIN) {
    float v = (sl == 0) ? a0 : (sl == 1) ? a1 : (sl == 2) ? a2 : (sl == 3) ? a3 : (sl == 4) ? a4 : a5;
    sh[w][nd][sl] = v;
  }
  #pragma unroll
  for (int nd2 = 0; nd2 < 8; ++nd2) {
    float h = bb1;
    #pragma unroll
    for (int k = 0; k < FIN; ++k) h = fmaf(sh[w][nd2][k], w1r[k], h);
    t1s[w * 8 + nd2][lane] = f2b(fmaxf(h, 0.f));
  }
  __syncthreads();
  if (w < 2) {
    int g = lane >> 4, c = lane & 15;
    bf16x8 af[4][2];
    #pragma unroll
    for (int mt = 0; mt < 4; ++mt)
      #pragma unroll
      for (int kh = 0; kh < 2; ++kh) af[mt][kh] = asfrag(wf2[(mt * 2 + kh) * 64 + lane]);
    int r0 = w * 16 + c;
    bf16x8 bf0 = asfrag(*(const uint4*)&t1s[r0][8 * g]);
    bf16x8 bf1 = asfrag(*(const uint4*)&t1s[r0][8 * g + 32]);
    f32x4 acc[4];
    #pragma unroll
    for (int mt = 0; mt < 4; ++mt) {
      acc[mt] = (f32x4){b2[mt * 16 + 4 * g + 0], b2[mt * 16 + 4 * g + 1],
                        b2[mt * 16 + 4 * g + 2], b2[mt * 16 + 4 * g + 3]};
      acc[mt] = __builtin_amdgcn_mfma_f32_16x16x32_bf16(af[mt][0], bf0, acc[mt], 0, 0, 0);
      acc[mt] = __builtin_amdgcn_mfma_f32_16x16x32_bf16(af[mt][1], bf1, acc[mt], 0, 0, 0);
    }
    #pragma unroll
    for (int mt = 0; mt < 4; ++mt) {
      uint2 pv;
      pv.x = pk2(acc[mt][0], acc[mt][1]);
      pv.y = pk2(acc[mt][2], acc[mt][3]);
      *(uint2*)&t1s[r0][mt * 16 + 4 * g] = pv;
    }
    int n2 = lane >> 2, ch = (lane & 3) * 16;
    uint4 s0 = *(const uint4*)&t1s[w * 16 + n2][ch];
    uint4 s1 = *(const uint4*)&t1s[w * 16 + n2][ch + 8];
    int orow = nb0 + w * 16 + n2;
    if (orow < n) {
      uint4* op = (uint4*)(hr + (size_t)orow * 64);
      op[(lane & 3) * 2] = s0;
      op[(lane & 3) * 2 + 1] = s1;
    }
  }
}

// ---------------- k_agg64 (unchanged) ----------------
#define ACC8(u) { a0 += blo(u.x); a1 += bhi(u.x); a2 += blo(u.y); a3 += bhi(u.y); \
                  a4 += blo(u.z); a5 += bhi(u.z); a6 += blo(u.w); a7 += bhi(u.w); }
__global__ __launch_bounds__(256) void k_agg64(const ushort_t* __restrict__ hb,
    const int* __restrict__ off, const int* __restrict__ csr,
    ushort_t* __restrict__ aggb, int n) {
  int t = threadIdx.x, w = t >> 6, lane = t & 63;
  int i = blockIdx.x * 4 + w;
  if (i >= n) return;
  int grp = lane >> 3, sl = lane & 7;
  int e0 = off[i], e1 = off[i + 1];
  const uint4* hb4 = (const uint4*)hb;
  float a0 = 0, a1 = 0, a2 = 0, a3 = 0, a4 = 0, a5 = 0, a6 = 0, a7 = 0;
  int e = e0 + grp;
  for (; e + 8 < e1; e += 16) {
    int sa = csr[e], sb = csr[e + 8];
    uint4 ua = hb4[(size_t)sa * 8 + sl];
    uint4 ub = hb4[(size_t)sb * 8 + sl];
    ACC8(ua); ACC8(ub);
  }
  if (e < e1) {
    int sa = csr[e];
    uint4 ua = hb4[(size_t)sa * 8 + sl];
    ACC8(ua);
  }
  #pragma unroll
  for (int m = 8; m < 64; m <<= 1) {
    a0 += __shfl_xor(a0, m); a1 += __shfl_xor(a1, m); a2 += __shfl_xor(a2, m);
    a3 += __shfl_xor(a3, m); a4 += __shfl_xor(a4, m); a5 += __shfl_xor(a5, m);
    a6 += __shfl_xor(a6, m); a7 += __shfl_xor(a7, m);
  }
  if (grp == 0) {
    uint4 us = hb4[(size_t)i * 8 + sl];
    ACC8(us);
    uint4 o;
    o.x = pk2(a0, a1); o.y = pk2(a2, a3); o.z = pk2(a4, a5); o.w = pk2(a6, a7);
    ((uint4*)aggb)[(size_t)i * 8 + sl] = o;
  }
}

// ---------------- k_mlp2_mfma (unchanged) ----------------
__global__ __launch_bounds__(256) void k_mlp2_mfma(const ushort_t* __restrict__ aggb,
    const uint4* __restrict__ wf3, const float* __restrict__ b3,
    const uint4* __restrict__ wf4, const float* __restrict__ b4,
    ushort_t* __restrict__ zb, int n) {
  __shared__ __align__(16) ushort_t lds[4][16][72];
  int t = threadIdx.x, w = t >> 6, l = t & 63;
  int g = l >> 4, c = l & 15;
  bf16x8 a3[4][2], a4[4][2];
  #pragma unroll
  for (int mt = 0; mt < 4; ++mt)
    #pragma unroll
    for (int kh = 0; kh < 2; ++kh) {
      a3[mt][kh] = asfrag(wf3[(mt * 2 + kh) * 64 + l]);
      a4[mt][kh] = asfrag(wf4[(mt * 2 + kh) * 64 + l]);
    }
  float bs3[4][4], bs4[4][4];
  #pragma unroll
  for (int mt = 0; mt < 4; ++mt)
    #pragma unroll
    for (int r = 0; r < 4; ++r) {
      bs3[mt][r] = b3[mt * 16 + 4 * g + r];
      bs4[mt][r] = b4[mt * 16 + 4 * g + r];
    }
  int ntile = (n + 15) >> 4;
  for (int tau = blockIdx.x * 4 + w; tau < ntile; tau += gridDim.x * 4) {
    int nb = tau << 4;
    int row = nb + c; if (row >= n) row = n - 1;
    const uint4* rp = (const uint4*)(aggb + (size_t)row * 64);
    bf16x8 bf0 = asfrag(rp[g]);
    bf16x8 bf1 = asfrag(rp[g + 4]);
    f32x4 acc[4];
    #pragma unroll
    for (int mt = 0; mt < 4; ++mt) {
      acc[mt] = (f32x4){bs3[mt][0], bs3[mt][1], bs3[mt][2], bs3[mt][3]};
      acc[mt] = __builtin_amdgcn_mfma_f32_16x16x32_bf16(a3[mt][0], bf0, acc[mt], 0, 0, 0);
      acc[mt] = __builtin_amdgcn_mfma_f32_16x16x32_bf16(a3[mt][1], bf1, acc[mt], 0, 0, 0);
    }
    #pragma unroll
    for (int mt = 0; mt < 4; ++mt) {
      uint2 pv;
      pv.x = pk2(fmaxf(acc[mt][0], 0.f), fmaxf(acc[mt][1], 0.f));
      pv.y = pk2(fmaxf(acc[mt][2], 0.f), fmaxf(acc[mt][3], 0.f));
      *(uint2*)&lds[w][c][mt * 16 + 4 * g] = pv;
    }
    bf16x8 h0 = asfrag(*(const uint4*)&lds[w][c][8 * g]);
    bf16x8 h1 = asfrag(*(const uint4*)&lds[w][c][8 * g + 32]);
    f32x4 ac2[4];
    #pragma unroll
    for (int mt = 0; mt < 4; ++mt) {
      ac2[mt] = (f32x4){bs4[mt][0], bs4[mt][1], bs4[mt][2], bs4[mt][3]};
      ac2[mt] = __builtin_amdgcn_mfma_f32_16x16x32_bf16(a4[mt][0], h0, ac2[mt], 0, 0, 0);
      ac2[mt] = __builtin_amdgcn_mfma_f32_16x16x32_bf16(a4[mt][1], h1, ac2[mt], 0, 0, 0);
    }
    #pragma unroll
    for (int mt = 0; mt < 4; ++mt) {
      uint2 pv;
      pv.x = pk2(ac2[mt][0], ac2[mt][1]);
      pv.y = pk2(ac2[mt][2], ac2[mt][3]);
      *(uint2*)&lds[w][c][mt * 16 + 4 * g] = pv;
    }
    int n2 = l >> 2, ch = (l & 3) * 16;
    uint4 s0 = *(const uint4*)&lds[w][n2][ch];
    uint4 s1 = *(const uint4*)&lds[w][n2][ch + 8];
    int orow = nb + n2;
    if (orow < n) {
      uint4* op = (uint4*)(zb + (size_t)orow * 64);
      op[(l & 3) * 2] = s0;
      op[(l & 3) * 2 + 1] = s1;
    }
  }
}

// ---------------- LN1 fused: stats + apply + relu (block per graph, LDS-staged) ----------------
__global__ __launch_bounds__(256) void k_ln1(const ushort_t* __restrict__ hr,
    const int* __restrict__ gstart, const float* __restrict__ w, const float* __restrict__ bb,
    ushort_t* __restrict__ hb) {
  __shared__ uint4 st[LNCAP * 8];
  __shared__ float l1[256], l2[256];
  __shared__ float mm[2];
  int g = blockIdx.x, t = threadIdx.x;
  int s0 = gstart[g], s1 = gstart[g + 1], cnt = s1 - s0;
  const uint4* src = (const uint4*)hr + (size_t)s0 * 8;
  int nch = cnt * 8;
  bool fit = cnt <= LNCAP;
  float s = 0.f, ss = 0.f;
  for (int j = t; j < nch; j += 256) {
    uint4 u = src[j];
    if (fit) st[j] = u;
    float v0 = blo(u.x), v1 = bhi(u.x), v2 = blo(u.y), v3 = bhi(u.y);
    float v4 = blo(u.z), v5 = bhi(u.z), v6 = blo(u.w), v7 = bhi(u.w);
    s += ((v0 + v1) + (v2 + v3)) + ((v4 + v5) + (v6 + v7));
    ss += ((v0 * v0 + v1 * v1) + (v2 * v2 + v3 * v3)) + ((v4 * v4 + v5 * v5) + (v6 * v6 + v7 * v7));
  }
  l1[t] = s; l2[t] = ss;
  __syncthreads();
  for (int o = 128; o > 0; o >>= 1) {
    if (t < o) { l1[t] += l1[t + o]; l2[t] += l2[t + o]; }
    __syncthreads();
  }
  if (t == 0) {
    float cf = (float)cnt;
    float norm = fmaxf(cf, 1.f) * 64.f;
    float mean = l1[0] / norm;
    float var = fmaxf(l2[0] / norm - mean * mean, 0.f);
    mm[0] = mean; mm[1] = rsqrtf(var + 1e-5f);
  }
  __syncthreads();
  float mean = mm[0], inv = mm[1];
  uint4* dst = (uint4*)hb + (size_t)s0 * 8;
  for (int j = t; j < nch; j += 256) {
    uint4 u = fit ? st[j] : src[j];
    int q = j & 7;
    float4 w0 = *(const float4*)(w + q * 8);
    float4 w1 = *(const float4*)(w + q * 8 + 4);
    float4 c0 = *(const float4*)(bb + q * 8);
    float4 c1 = *(const float4*)(bb + q * 8 + 4);
    uint4 o;
    o.x = pk2(fmaxf((blo(u.x) - mean) * inv * w0.x + c0.x, 0.f),
              fmaxf((bhi(u.x) - mean) * inv * w0.y + c0.y, 0.f));
    o.y = pk2(fmaxf((blo(u.y) - mean) * inv * w0.z + c0.z, 0.f),
              fmaxf((bhi(u.y) - mean) * inv * w0.w + c0.w, 0.f));
    o.z = pk2(fmaxf((blo(u.z) - mean) * inv * w1.x + c1.x, 0.f),
              fmaxf((bhi(u.z) - mean) * inv * w1.y + c1.y, 0.f));
    o.w = pk2(fmaxf((blo(u.w) - mean) * inv * w1.z + c1.z, 0.f),
              fmaxf((bhi(u.w) - mean) * inv * w1.w + c1.w, 0.f));
    dst[j] = o;
  }
}

// ---------------- LN2 + pool fused: emb = sum(relu(ln2(zb))) * (1 + 1/cnt) ----------------
__global__ __launch_bounds__(256) void k_ln2pool(const ushort_t* __restrict__ zb,
    const int* __restrict__ gstart, const float* __restrict__ w, const float* __restrict__ bb,
    float* __restrict__ emb) {
  __shared__ unsigned st[LNCAP * 32];
  __shared__ float l1[256], l2[256];
  __shared__ float mm[2];
  int g = blockIdx.x, t = threadIdx.x;
  int s0 = gstart[g], s1 = gstart[g + 1], cnt = s1 - s0;
  const unsigned* src = (const unsigned*)zb + (size_t)s0 * 32;
  int nu = cnt * 32;
  bool fit = cnt <= LNCAP;
  float s = 0.f, ss = 0.f;
  for (int j = t; j < nu; j += 256) {
    unsigned u = src[j];
    if (fit) st[j] = u;
    float v0 = blo(u), v1 = bhi(u);
    s += v0 + v1;
    ss += v0 * v0 + v1 * v1;
  }
  l1[t] = s; l2[t] = ss;
  __syncthreads();
  for (int o = 128; o > 0; o >>= 1) {
    if (t < o) { l1[t] += l1[t + o]; l2[t] += l2[t + o]; }
    __syncthreads();
  }
  if (t == 0) {
    float cf = (float)cnt;
    float norm = fmaxf(cf, 1.f) * 64.f;
    float mean = l1[0] / norm;
    float var = fmaxf(l2[0] / norm - mean * mean, 0.f);
    mm[0] = mean; mm[1] = rsqrtf(var + 1e-5f);
  }
  __syncthreads();
  float mean = mm[0], inv = mm[1];
  int c2 = t & 31, sub = t >> 5;
  float w0 = w[c2 * 2], w1 = w[c2 * 2 + 1], b0 = bb[c2 * 2], b1v = bb[c2 * 2 + 1];
  float acc0 = 0.f, acc1 = 0.f;
  for (int i = sub; i < cnt; i += 8) {
    unsigned u = fit ? st[i * 32 + c2] : src[(size_t)i * 32 + c2];
    acc0 += fmaxf((blo(u) - mean) * inv * w0 + b0, 0.f);
    acc1 += fmaxf((bhi(u) - mean) * inv * w1 + b1v, 0.f);
  }
  __syncthreads();
  l1[t] = acc0; l2[t] = acc1;
  __syncthreads();
  if (sub == 0) {
    float t0 = 0.f, t1v = 0.f;
    #pragma unroll
    for (int sx = 0; sx < 8; ++sx) { t0 += l1[sx * 32 + c2]; t1v += l2[sx * 32 + c2]; }
    float cf = fmaxf((float)cnt, 1.f);
    emb[g * 64 + c2 * 2]     = t0 + t0 / cf;
    emb[g * 64 + c2 * 2 + 1] = t1v + t1v / cf;
  }
}

// ---------------- head MLP ----------------
__global__ __launch_bounds__(128) void k_head(const float* __restrict__ emb1,
    const float* __restrict__ emb2, const float* __restrict__ d1, const float* __restrict__ d2,
    const float* __restrict__ Wf1, const float* __restrict__ bf1,
    const float* __restrict__ Wf2, const float* __restrict__ bf2,
    const float* __restrict__ Wo, const float* __restrict__ bo, float* __restrict__ out) {
  int g = blockIdx.x, t = threadIdx.x;
  __shared__ float v[138], h1s[128], h2s[64];
  if (t < 64) v[t] = emb1[g * 64 + t];
  else v[t] = emb2[g * 64 + (t - 64)];
  if (t < 5) v[128 + t] = d1[g * 5 + t];
  else if (t < 10) v[133 + (t - 5)] = d2[g * 5 + (t - 5)];
  __syncthreads();
  float a = bf1[t];
  for (int k = 0; k < 138; ++k) a = fmaf(v[k], Wf1[k * 128 + t], a);
  h1s[t] = fmaxf(a, 0.f);
  __syncthreads();
  if (t < 64) {
    float a2 = bf2[t];
    #pragma unroll 8
    for (int k = 0; k < 128; ++k) a2 = fmaf(h1s[k], Wf2[k * 64 + t], a2);
    h2s[t] = fmaxf(a2, 0.f);
  }
  __syncthreads();
  if (t == 0) {
    float s = bo[0];
    for (int k = 0; k < 64; ++k) s += h2s[k] * Wo[k];
    out[g] = s;
  }
}

extern "C" void kernel_launch(void* const* d_in, const int* in_sizes, int n_in,
                              void* d_out, int out_size, void* d_ws, size_t ws_size,
                              hipStream_t stream) {
  const float* x1     = (const float*)d_in[0];
  const int*   ei1    = (const int*)d_in[1];
  const int*   batch1 = (const int*)d_in[2];
  const float* x2     = (const float*)d_in[3];
  const int*   ei2    = (const int*)d_in[4];
  const int*   batch2 = (const int*)d_in[5];
  const float* d1     = (const float*)d_in[6];
  const float* d2     = (const float*)d_in[7];
  const float* W1  = (const float*)d_in[8],  *b1  = (const float*)d_in[9];
  const float* W2  = (const float*)d_in[10], *b2  = (const float*)d_in[11];
  const float* ln1w = (const float*)d_in[12], *ln1b = (const float*)d_in[13];
  const float* W3  = (const float*)d_in[14], *b3  = (const float*)d_in[15];
  const float* W4  = (const float*)d_in[16], *b4  = (const float*)d_in[17];
  const float* ln2w = (const float*)d_in[18], *ln2b = (const float*)d_in[19];
  const float* Wf1 = (const float*)d_in[20], *bf1 = (const float*)d_in[21];
  const float* Wf2 = (const float*)d_in[22], *bf2 = (const float*)d_in[23];
  const float* Wo  = (const float*)d_in[24], *bo  = (const float*)d_in[25];
  float* out = (float*)d_out;

  const int N = in_sizes[0] / FIN;
  const int G = in_sizes[6] / 5;
  const int E1 = in_sizes[1] / 2;
  const int E2 = in_sizes[4] / 2;
  const int Emax = (E1 > E2) ? E1 : E2;
  const int NBUK = (N + 1023) >> 10;   // <= 256 (requires N <= 262144; src fits 18 bits)

  char* p = (char*)d_ws;
  auto alloc = [&](size_t bytes) { void* r = p; p += (bytes + 255) & ~(size_t)255; return r; };
  int*      off    = (int*)alloc((size_t)(N + 1) * 4);
  int*      ecur   = (int*)alloc(256 * 4);
  int*      ebase  = (int*)alloc(257 * 4);
  int*      csr    = (int*)alloc((size_t)Emax * 4);
  int*      gstart = (int*)alloc((size_t)(G + 1) * 4);
  uint4*    wfrag  = (uint4*)alloc(3 * 512 * 16);            // W2,W3,W4 MFMA fragments
  unsigned* xb     = (unsigned*)alloc((size_t)N * 16);       // bf16x8 padded rows
  ushort_t* hr     = (ushort_t*)alloc((size_t)N * 64 * 2);   // aliased: aggb
  ushort_t* hb     = (ushort_t*)alloc((size_t)N * 64 * 2);   // aliased: ebuf, zb
  float*    emb1   = (float*)alloc((size_t)G * 64 * 4);
  float*    emb2   = (float*)alloc((size_t)G * 64 * 4);
  ushort_t* aggb = hr;              // agg64 runs after hr consumed by ln1
  ushort_t* zb   = hb;              // mlp2 runs after hb consumed by agg64
  unsigned* ebuf = (unsigned*)hb;   // CSR-build phase only; hb written after bcsr

  const uint4* wf2 = wfrag;
  const uint4* wf3 = wfrag + 512;
  const uint4* wf4 = wfrag + 1024;

  const int GRID_W  = (N + 3) / 4;
  const int GRID_F  = (N + 31) / 32;
  const int GRID_P  = (N * 4 + 255) / 256;

  k_wpack<<<6, 256, 0, stream>>>(W2, W3, W4, wfrag);

  auto run_graph = [&](const float* x, const int* ei, const int* batch, int E, float* emb) {
    const int* src = ei;
    const int* dst = ei + E;
    const int SCAT = (E + TILE - 1) / TILE;
    k_binit<<<1, 256, 0, stream>>>(ecur, off, NBUK, N, E);
    k_bscatter<<<SCAT, 256, 0, stream>>>(src, dst, ecur, ebuf, E, NBUK);
    k_bscan2<<<1, 256, 0, stream>>>(ecur, ebase, NBUK);
    k_bcsr<<<NBUK, 256, 0, stream>>>(ebuf, ecur, ebase, off, csr, N);
    k_prep<<<GRID_P, 256, 0, stream>>>(x, batch, xb, gstart, N, G);

    k_gin1f<<<GRID_F, 256, 0, stream>>>((const uint4*)xb, off, csr, W1, b1, wf2, b2, hr, N);
    k_ln1<<<G, 256, 0, stream>>>(hr, gstart, ln1w, ln1b, hb);
    k_agg64<<<GRID_W, 256, 0, stream>>>(hb, off, csr, aggb, N);
    k_mlp2_mfma<<<2048, 256, 0, stream>>>(aggb, wf3, b3, wf4, b4, zb, N);
    k_ln2pool<<<G, 256, 0, stream>>>(zb, gstart, ln2w, ln2b, emb);
  };

  run_graph(x1, ei1, batch1, E1, emb1);
  run_graph(x2, ei2, batch2, E2, emb2);
  k_head<<<G, 128, 0, stream>>>(emb1, emb2, d1, d2, Wf1, bf1, Wf2, bf2, Wo, bo, out);
}

// Round 7
// 555.753 us; speedup vs baseline: 4.5830x; 1.1610x over previous
//
#include <hip/hip_runtime.h>

typedef unsigned short ushort_t;
typedef __attribute__((ext_vector_type(8))) short bf16x8;
typedef __attribute__((ext_vector_type(4))) float f32x4;

#define FIN 6
#define CAP 20480      // per-bucket edge capacity (mean 16384 at E=8M, 489 buckets)
#define LNCAP 384      // max nodes/graph staged in LDS

__device__ __forceinline__ float blo(unsigned u) { return __uint_as_float(u << 16); }
__device__ __forceinline__ float bhi(unsigned u) { return __uint_as_float(u & 0xffff0000u); }
__device__ __forceinline__ ushort_t f2b(float f) {
  unsigned u = __float_as_uint(f);
  unsigned r = (u + 0x7fffu + ((u >> 16) & 1u)) >> 16;
  return (ushort_t)r;
}
__device__ __forceinline__ unsigned pk2(float lo, float hi) {
  return ((unsigned)f2b(hi) << 16) | (unsigned)f2b(lo);
}
union U4F { uint4 u; bf16x8 v; };
__device__ __forceinline__ bf16x8 asfrag(uint4 u) { U4F x; x.u = u; return x.v; }

// ================= bucketed CSR build (both graphs, node ids offset) =================
#define EPT 16
#define TILE 8192      // 512 threads * EPT

__global__ __launch_bounds__(512) void k_binit(int* __restrict__ ecur, int* __restrict__ off,
                                               int nbuk, int N2, int Etot) {
  int t = threadIdx.x;
  if (t < nbuk) ecur[t] = t * CAP;
  if (t == 0) off[N2] = Etot;
}

__global__ __launch_bounds__(512) void k_bscatter(
    const int* __restrict__ src1, const int* __restrict__ dst1, int E1,
    const int* __restrict__ src2, const int* __restrict__ dst2, int E2,
    int* __restrict__ ecur, unsigned* __restrict__ ebuf, int N, int nbuk) {
  __shared__ int cnt[512];
  __shared__ int gbase[512];
  int t = threadIdx.x;
  cnt[t] = 0;
  __syncthreads();
  int tile = blockIdx.x;
  int T1 = (E1 + TILE - 1) / TILE;
  const int* srcp; const int* dstp; int Elim, ofs, base;
  if (tile < T1) { srcp = src1; dstp = dst1; Elim = E1; ofs = 0; base = tile * TILE; }
  else { srcp = src2; dstp = dst2; Elim = E2; ofs = N; base = (tile - T1) * TILE; }
  unsigned pk[EPT];   // bucket(9) | rank<<9
  unsigned pv[EPT];   // dstLocal(10)<<19 | src(19)
  #pragma unroll
  for (int k = 0; k < EPT; ++k) {
    int e = base + k * 512 + t;
    if (e < Elim) {
      int d = dstp[e] + ofs;
      int b = d >> 10;
      int r = atomicAdd(&cnt[b], 1);
      pk[k] = (unsigned)b | ((unsigned)r << 9);
      pv[k] = ((unsigned)(d & 1023) << 19) | (unsigned)(srcp[e] + ofs);
    } else {
      pk[k] = 0xFFFFFFFFu;
    }
  }
  __syncthreads();
  if (t < nbuk && cnt[t] > 0) gbase[t] = atomicAdd(&ecur[t], cnt[t]);
  __syncthreads();
  #pragma unroll
  for (int k = 0; k < EPT; ++k) {
    if (pk[k] != 0xFFFFFFFFu) {
      int b = pk[k] & 511;
      int r = pk[k] >> 9;
      ebuf[gbase[b] + r] = pv[k];
    }
  }
}

__global__ __launch_bounds__(512) void k_bscan2(const int* __restrict__ ecur,
    int* __restrict__ ebase, int nbuk) {
  __shared__ int lds[512];
  int t = threadIdx.x;
  int s = (t < nbuk) ? (ecur[t] - t * CAP) : 0;
  lds[t] = s; __syncthreads();
  int acc = s;
  for (int o = 1; o < 512; o <<= 1) {
    int add = (t >= o) ? lds[t - o] : 0;
    __syncthreads();
    acc += add; lds[t] = acc;
    __syncthreads();
  }
  if (t < nbuk) ebase[t] = acc - s;
}

__global__ __launch_bounds__(256) void k_bcsr(const unsigned* __restrict__ ebuf,
    const int* __restrict__ ecur, const int* __restrict__ ebase,
    int* __restrict__ off, int* __restrict__ csr, int N2) {
  __shared__ int hist[1024];
  __shared__ int lofs[1024];
  __shared__ int sc[256];
  int b = blockIdx.x, t = threadIdx.x;
  int nb0 = b << 10;
  int bn = N2 - nb0; if (bn > 1024) bn = 1024;
  int s_beg = b * CAP, s_end = ecur[b];
  int base = ebase[b];
  #pragma unroll
  for (int k = 0; k < 4; ++k) hist[t * 4 + k] = 0;
  __syncthreads();
  for (int e = s_beg + t; e < s_end; e += 256) atomicAdd(&hist[ebuf[e] >> 19], 1);
  __syncthreads();
  int h0 = hist[t * 4 + 0], h1 = hist[t * 4 + 1], h2 = hist[t * 4 + 2], h3 = hist[t * 4 + 3];
  int s = h0 + h1 + h2 + h3;
  sc[t] = s; __syncthreads();
  int acc = s;
  for (int o = 1; o < 256; o <<= 1) {
    int add = (t >= o) ? sc[t - o] : 0;
    __syncthreads();
    acc += add; sc[t] = acc;
    __syncthreads();
  }
  int run = acc - s;
  lofs[t * 4 + 0] = run; run += h0;
  lofs[t * 4 + 1] = run; run += h1;
  lofs[t * 4 + 2] = run; run += h2;
  lofs[t * 4 + 3] = run;
  __syncthreads();
  #pragma unroll
  for (int k = 0; k < 4; ++k) {
    int j = t * 4 + k;
    if (j < bn) off[nb0 + j] = base + lofs[j];
  }
  __syncthreads();
  for (int e = s_beg + t; e < s_end; e += 256) {
    unsigned p = ebuf[e];
    int r = atomicAdd(&lofs[p >> 19], 1);
    csr[base + r] = (int)(p & 0x7FFFFu);
  }
}

// ---------------- prep: xpack both graphs + combined graph bounds ----------------
__global__ void k_prep(const float* __restrict__ x1, const float* __restrict__ x2,
                       const int* __restrict__ batch1, const int* __restrict__ batch2,
                       unsigned* __restrict__ xb, int* __restrict__ gstart,
                       int N, int G) {
  int N2 = 2 * N, G2 = 2 * G;
  int tt = blockIdx.x * 256 + threadIdx.x;
  if (tt < N2 * 4) {
    int i = tt >> 2, k = tt & 3;
    unsigned v = 0;
    if (k < 3) {
      const float* xp = (i < N) ? (x1 + (size_t)i * 6) : (x2 + (size_t)(i - N) * 6);
      float2 f = *(const float2*)(xp + k * 2);
      v = pk2(f.x, f.y);
    }
    xb[tt] = v;
  }
  if (tt < N2) {
    int i = tt;
    int b = (i < N) ? batch1[i] : (batch2[i - N] + G);
    if (i == 0) { for (int g = 0; g <= b; ++g) gstart[g] = 0; }
    else {
      int pb = (i - 1 < N) ? batch1[i - 1] : (batch2[i - 1 - N] + G);
      for (int g = pb + 1; g <= b; ++g) gstart[g] = i;
    }
    if (i == N2 - 1) { for (int g = b + 1; g <= G2; ++g) gstart[g] = N2; }
  }
}

// ---------------- pack weights into MFMA A-fragments (W^T) ----------------
__global__ void k_wpack(const float* __restrict__ W2, const float* __restrict__ W3,
                        const float* __restrict__ W4, uint4* __restrict__ wfrag) {
  int idx = blockIdx.x * 256 + threadIdx.x;
  if (idx >= 3 * 512) return;
  int widx = idx >> 9, rem = idx & 511;
  int mt = rem >> 7, kh = (rem >> 6) & 1, l = rem & 63;
  int g = l >> 4, c = l & 15;
  const float* W = (widx == 0) ? W2 : (widx == 1) ? W3 : W4;
  int k0 = kh * 32 + g * 8;
  int col = mt * 16 + c;
  uint4 v;
  v.x = pk2(W[(k0 + 0) * 64 + col], W[(k0 + 1) * 64 + col]);
  v.y = pk2(W[(k0 + 2) * 64 + col], W[(k0 + 3) * 64 + col]);
  v.z = pk2(W[(k0 + 4) * 64 + col], W[(k0 + 5) * 64 + col]);
  v.w = pk2(W[(k0 + 6) * 64 + col], W[(k0 + 7) * 64 + col]);
  wfrag[idx] = v;
}

// ---------------- GIN1 fused: gather x + Linear(6->64) + relu + MFMA Linear(64->64) ----------------
#define ACC6(u) { a0 += blo(u.x); a1 += bhi(u.x); a2 += blo(u.y); a3 += bhi(u.y); a4 += blo(u.z); a5 += bhi(u.z); }
__global__ __launch_bounds__(256) void k_gin1f(const uint4* __restrict__ xb4,
    const int* __restrict__ off, const int* __restrict__ csr,
    const float* __restrict__ W1, const float* __restrict__ b1,
    const uint4* __restrict__ wf2, const float* __restrict__ b2,
    ushort_t* __restrict__ hr, int n) {
  __shared__ __align__(16) ushort_t t1s[32][72];
  __shared__ float sh[4][8][FIN];
  int t = threadIdx.x, w = t >> 6, lane = t & 63;
  int nd = lane >> 3, sl = lane & 7;
  int nb0 = blockIdx.x * 32;
  int i = nb0 + w * 8 + nd;

  float w1r[FIN];
  #pragma unroll
  for (int k = 0; k < FIN; ++k) w1r[k] = W1[k * 64 + lane];
  float bb1 = b1[lane];

  float a0 = 0, a1 = 0, a2 = 0, a3 = 0, a4 = 0, a5 = 0;
  if (i < n) {
    int e0 = off[i], e1 = off[i + 1];
    int e = e0 + sl;
    for (; e + 8 < e1; e += 16) {
      uint4 u = xb4[csr[e]];
      uint4 v = xb4[csr[e + 8]];
      ACC6(u); ACC6(v);
    }
    if (e < e1) { uint4 u = xb4[csr[e]]; ACC6(u); }
    if (sl == 0) { uint4 u = xb4[i]; ACC6(u); }
  }
  #pragma unroll
  for (int m = 1; m < 8; m <<= 1) {
    a0 += __shfl_xor(a0, m); a1 += __shfl_xor(a1, m); a2 += __shfl_xor(a2, m);
    a3 += __shfl_xor(a3, m); a4 += __shfl_xor(a4, m); a5 += __shfl_xor(a5, m);
  }
  if (sl < FIN) {
    float v = (sl == 0) ? a0 : (sl == 1) ? a1 : (sl == 2) ? a2 : (sl == 3) ? a3 : (sl == 4) ? a4 : a5;
    sh[w][nd][sl] = v;
  }
  #pragma unroll
  for (int nd2 = 0; nd2 < 8; ++nd2) {
    float h = bb1;
    #pragma unroll
    for (int k = 0; k < FIN; ++k) h = fmaf(sh[w][nd2][k], w1r[k], h);
    t1s[w * 8 + nd2][lane] = f2b(fmaxf(h, 0.f));
  }
  __syncthreads();
  if (w < 2) {
    int g = lane >> 4, c = lane & 15;
    bf16x8 af[4][2];
    #pragma unroll
    for (int mt = 0; mt < 4; ++mt)
      #pragma unroll
      for (int kh = 0; kh < 2; ++kh) af[mt][kh] = asfrag(wf2[(mt * 2 + kh) * 64 + lane]);
    int r0 = w * 16 + c;
    bf16x8 bf0 = asfrag(*(const uint4*)&t1s[r0][8 * g]);
    bf16x8 bf1 = asfrag(*(const uint4*)&t1s[r0][8 * g + 32]);
    f32x4 acc[4];
    #pragma unroll
    for (int mt = 0; mt < 4; ++mt) {
      acc[mt] = (f32x4){b2[mt * 16 + 4 * g + 0], b2[mt * 16 + 4 * g + 1],
                        b2[mt * 16 + 4 * g + 2], b2[mt * 16 + 4 * g + 3]};
      acc[mt] = __builtin_amdgcn_mfma_f32_16x16x32_bf16(af[mt][0], bf0, acc[mt], 0, 0, 0);
      acc[mt] = __builtin_amdgcn_mfma_f32_16x16x32_bf16(af[mt][1], bf1, acc[mt], 0, 0, 0);
    }
    #pragma unroll
    for (int mt = 0; mt < 4; ++mt) {
      uint2 pv;
      pv.x = pk2(acc[mt][0], acc[mt][1]);
      pv.y = pk2(acc[mt][2], acc[mt][3]);
      *(uint2*)&t1s[r0][mt * 16 + 4 * g] = pv;
    }
    int n2 = lane >> 2, ch = (lane & 3) * 16;
    uint4 s0 = *(const uint4*)&t1s[w * 16 + n2][ch];
    uint4 s1 = *(const uint4*)&t1s[w * 16 + n2][ch + 8];
    int orow = nb0 + w * 16 + n2;
    if (orow < n) {
      uint4* op = (uint4*)(hr + (size_t)orow * 64);
      op[(lane & 3) * 2] = s0;
      op[(lane & 3) * 2 + 1] = s1;
    }
  }
}

// ---------------- k_agg64: float2 packed accumulation ----------------
__device__ __forceinline__ float2 up2(unsigned v) { return make_float2(blo(v), bhi(v)); }
#define PACC(u) { float2 q0 = up2(u.x), q1 = up2(u.y), q2 = up2(u.z), q3 = up2(u.w); \
                  c0.x += q0.x; c0.y += q0.y; c1.x += q1.x; c1.y += q1.y; \
                  c2.x += q2.x; c2.y += q2.y; c3.x += q3.x; c3.y += q3.y; }
__global__ __launch_bounds__(256) void k_agg64(const ushort_t* __restrict__ hb,
    const int* __restrict__ off, const int* __restrict__ csr,
    ushort_t* __restrict__ aggb, int n) {
  int t = threadIdx.x, w = t >> 6, lane = t & 63;
  int i = blockIdx.x * 4 + w;
  if (i >= n) return;
  int grp = lane >> 3, sl = lane & 7;
  int e0 = off[i], e1 = off[i + 1];
  const uint4* hb4 = (const uint4*)hb;
  float2 c0 = {0, 0}, c1 = {0, 0}, c2 = {0, 0}, c3 = {0, 0};
  int e = e0 + grp;
  for (; e + 8 < e1; e += 16) {
    int sa = csr[e], sb = csr[e + 8];
    uint4 ua = hb4[(size_t)sa * 8 + sl];
    uint4 ub = hb4[(size_t)sb * 8 + sl];
    PACC(ua); PACC(ub);
  }
  if (e < e1) {
    int sa = csr[e];
    uint4 ua = hb4[(size_t)sa * 8 + sl];
    PACC(ua);
  }
  #pragma unroll
  for (int m = 8; m < 64; m <<= 1) {
    c0.x += __shfl_xor(c0.x, m); c0.y += __shfl_xor(c0.y, m);
    c1.x += __shfl_xor(c1.x, m); c1.y += __shfl_xor(c1.y, m);
    c2.x += __shfl_xor(c2.x, m); c2.y += __shfl_xor(c2.y, m);
    c3.x += __shfl_xor(c3.x, m); c3.y += __shfl_xor(c3.y, m);
  }
  if (grp == 0) {
    uint4 us = hb4[(size_t)i * 8 + sl];
    PACC(us);
    uint4 o;
    o.x = pk2(c0.x, c0.y); o.y = pk2(c1.x, c1.y);
    o.z = pk2(c2.x, c2.y); o.w = pk2(c3.x, c3.y);
    ((uint4*)aggb)[(size_t)i * 8 + sl] = o;
  }
}

// ---------------- k_mlp2_mfma ----------------
__global__ __launch_bounds__(256) void k_mlp2_mfma(const ushort_t* __restrict__ aggb,
    const uint4* __restrict__ wf3, const float* __restrict__ b3,
    const uint4* __restrict__ wf4, const float* __restrict__ b4,
    ushort_t* __restrict__ zb, int n) {
  __shared__ __align__(16) ushort_t lds[4][16][72];
  int t = threadIdx.x, w = t >> 6, l = t & 63;
  int g = l >> 4, c = l & 15;
  bf16x8 a3[4][2], a4[4][2];
  #pragma unroll
  for (int mt = 0; mt < 4; ++mt)
    #pragma unroll
    for (int kh = 0; kh < 2; ++kh) {
      a3[mt][kh] = asfrag(wf3[(mt * 2 + kh) * 64 + l]);
      a4[mt][kh] = asfrag(wf4[(mt * 2 + kh) * 64 + l]);
    }
  float bs3[4][4], bs4[4][4];
  #pragma unroll
  for (int mt = 0; mt < 4; ++mt)
    #pragma unroll
    for (int r = 0; r < 4; ++r) {
      bs3[mt][r] = b3[mt * 16 + 4 * g + r];
      bs4[mt][r] = b4[mt * 16 + 4 * g + r];
    }
  int ntile = (n + 15) >> 4;
  for (int tau = blockIdx.x * 4 + w; tau < ntile; tau += gridDim.x * 4) {
    int nb = tau << 4;
    int row = nb + c; if (row >= n) row = n - 1;
    const uint4* rp = (const uint4*)(aggb + (size_t)row * 64);
    bf16x8 bf0 = asfrag(rp[g]);
    bf16x8 bf1 = asfrag(rp[g + 4]);
    f32x4 acc[4];
    #pragma unroll
    for (int mt = 0; mt < 4; ++mt) {
      acc[mt] = (f32x4){bs3[mt][0], bs3[mt][1], bs3[mt][2], bs3[mt][3]};
      acc[mt] = __builtin_amdgcn_mfma_f32_16x16x32_bf16(a3[mt][0], bf0, acc[mt], 0, 0, 0);
      acc[mt] = __builtin_amdgcn_mfma_f32_16x16x32_bf16(a3[mt][1], bf1, acc[mt], 0, 0, 0);
    }
    #pragma unroll
    for (int mt = 0; mt < 4; ++mt) {
      uint2 pv;
      pv.x = pk2(fmaxf(acc[mt][0], 0.f), fmaxf(acc[mt][1], 0.f));
      pv.y = pk2(fmaxf(acc[mt][2], 0.f), fmaxf(acc[mt][3], 0.f));
      *(uint2*)&lds[w][c][mt * 16 + 4 * g] = pv;
    }
    bf16x8 h0 = asfrag(*(const uint4*)&lds[w][c][8 * g]);
    bf16x8 h1 = asfrag(*(const uint4*)&lds[w][c][8 * g + 32]);
    f32x4 ac2[4];
    #pragma unroll
    for (int mt = 0; mt < 4; ++mt) {
      ac2[mt] = (f32x4){bs4[mt][0], bs4[mt][1], bs4[mt][2], bs4[mt][3]};
      ac2[mt] = __builtin_amdgcn_mfma_f32_16x16x32_bf16(a4[mt][0], h0, ac2[mt], 0, 0, 0);
      ac2[mt] = __builtin_amdgcn_mfma_f32_16x16x32_bf16(a4[mt][1], h1, ac2[mt], 0, 0, 0);
    }
    #pragma unroll
    for (int mt = 0; mt < 4; ++mt) {
      uint2 pv;
      pv.x = pk2(ac2[mt][0], ac2[mt][1]);
      pv.y = pk2(ac2[mt][2], ac2[mt][3]);
      *(uint2*)&lds[w][c][mt * 16 + 4 * g] = pv;
    }
    int n2 = l >> 2, ch = (l & 3) * 16;
    uint4 s0 = *(const uint4*)&lds[w][n2][ch];
    uint4 s1 = *(const uint4*)&lds[w][n2][ch + 8];
    int orow = nb + n2;
    if (orow < n) {
      uint4* op = (uint4*)(zb + (size_t)orow * 64);
      op[(l & 3) * 2] = s0;
      op[(l & 3) * 2 + 1] = s1;
    }
  }
}

// ---------------- LN1 fused: stats + apply + relu (block per graph, in-place) ----------------
__global__ __launch_bounds__(256) void k_ln1(ushort_t* __restrict__ hr,
    const int* __restrict__ gstart, const float* __restrict__ w, const float* __restrict__ bb) {
  __shared__ uint4 st[LNCAP * 8];
  __shared__ float l1[256], l2[256];
  __shared__ float mm[2];
  int g = blockIdx.x, t = threadIdx.x;
  int s0 = gstart[g], s1 = gstart[g + 1], cnt = s1 - s0;
  uint4* src = (uint4*)hr + (size_t)s0 * 8;
  int nch = cnt * 8;
  bool fit = cnt <= LNCAP;
  float s = 0.f, ss = 0.f;
  for (int j = t; j < nch; j += 256) {
    uint4 u = src[j];
    if (fit) st[j] = u;
    float v0 = blo(u.x), v1 = bhi(u.x), v2 = blo(u.y), v3 = bhi(u.y);
    float v4 = blo(u.z), v5 = bhi(u.z), v6 = blo(u.w), v7 = bhi(u.w);
    s += ((v0 + v1) + (v2 + v3)) + ((v4 + v5) + (v6 + v7));
    ss += ((v0 * v0 + v1 * v1) + (v2 * v2 + v3 * v3)) + ((v4 * v4 + v5 * v5) + (v6 * v6 + v7 * v7));
  }
  l1[t] = s; l2[t] = ss;
  __syncthreads();
  for (int o = 128; o > 0; o >>= 1) {
    if (t < o) { l1[t] += l1[t + o]; l2[t] += l2[t + o]; }
    __syncthreads();
  }
  if (t == 0) {
    float cf = (float)cnt;
    float norm = fmaxf(cf, 1.f) * 64.f;
    float mean = l1[0] / norm;
    float var = fmaxf(l2[0] / norm - mean * mean, 0.f);
    mm[0] = mean; mm[1] = rsqrtf(var + 1e-5f);
  }
  __syncthreads();
  float mean = mm[0], inv = mm[1];
  for (int j = t; j < nch; j += 256) {
    uint4 u = fit ? st[j] : src[j];
    int q = j & 7;
    float4 w0 = *(const float4*)(w + q * 8);
    float4 w1 = *(const float4*)(w + q * 8 + 4);
    float4 c0 = *(const float4*)(bb + q * 8);
    float4 c1 = *(const float4*)(bb + q * 8 + 4);
    uint4 o;
    o.x = pk2(fmaxf((blo(u.x) - mean) * inv * w0.x + c0.x, 0.f),
              fmaxf((bhi(u.x) - mean) * inv * w0.y + c0.y, 0.f));
    o.y = pk2(fmaxf((blo(u.y) - mean) * inv * w0.z + c0.z, 0.f),
              fmaxf((bhi(u.y) - mean) * inv * w0.w + c0.w, 0.f));
    o.z = pk2(fmaxf((blo(u.z) - mean) * inv * w1.x + c1.x, 0.f),
              fmaxf((bhi(u.z) - mean) * inv * w1.y + c1.y, 0.f));
    o.w = pk2(fmaxf((blo(u.w) - mean) * inv * w1.z + c1.z, 0.f),
              fmaxf((bhi(u.w) - mean) * inv * w1.w + c1.w, 0.f));
    src[j] = o;
  }
}

// ---------------- LN2 + pool fused ----------------
__global__ __launch_bounds__(256) void k_ln2pool(const ushort_t* __restrict__ zb,
    const int* __restrict__ gstart, const float* __restrict__ w, const float* __restrict__ bb,
    float* __restrict__ emb) {
  __shared__ unsigned st[LNCAP * 32];
  __shared__ float l1[256], l2[256];
  __shared__ float mm[2];
  int g = blockIdx.x, t = threadIdx.x;
  int s0 = gstart[g], s1 = gstart[g + 1], cnt = s1 - s0;
  const unsigned* src = (const unsigned*)zb + (size_t)s0 * 32;
  int nu = cnt * 32;
  bool fit = cnt <= LNCAP;
  float s = 0.f, ss = 0.f;
  for (int j = t; j < nu; j += 256) {
    unsigned u = src[j];
    if (fit) st[j] = u;
    float v0 = blo(u), v1 = bhi(u);
    s += v0 + v1;
    ss += v0 * v0 + v1 * v1;
  }
  l1[t] = s; l2[t] = ss;
  __syncthreads();
  for (int o = 128; o > 0; o >>= 1) {
    if (t < o) { l1[t] += l1[t + o]; l2[t] += l2[t + o]; }
    __syncthreads();
  }
  if (t == 0) {
    float cf = (float)cnt;
    float norm = fmaxf(cf, 1.f) * 64.f;
    float mean = l1[0] / norm;
    float var = fmaxf(l2[0] / norm - mean * mean, 0.f);
    mm[0] = mean; mm[1] = rsqrtf(var + 1e-5f);
  }
  __syncthreads();
  float mean = mm[0], inv = mm[1];
  int c2 = t & 31, sub = t >> 5;
  float w0 = w[c2 * 2], w1 = w[c2 * 2 + 1], b0 = bb[c2 * 2], b1v = bb[c2 * 2 + 1];
  float acc0 = 0.f, acc1 = 0.f;
  for (int i = sub; i < cnt; i += 8) {
    unsigned u = fit ? st[i * 32 + c2] : src[(size_t)i * 32 + c2];
    acc0 += fmaxf((blo(u) - mean) * inv * w0 + b0, 0.f);
    acc1 += fmaxf((bhi(u) - mean) * inv * w1 + b1v, 0.f);
  }
  __syncthreads();
  l1[t] = acc0; l2[t] = acc1;
  __syncthreads();
  if (sub == 0) {
    float t0 = 0.f, t1v = 0.f;
    #pragma unroll
    for (int sx = 0; sx < 8; ++sx) { t0 += l1[sx * 32 + c2]; t1v += l2[sx * 32 + c2]; }
    float cf = fmaxf((float)cnt, 1.f);
    emb[g * 64 + c2 * 2]     = t0 + t0 / cf;
    emb[g * 64 + c2 * 2 + 1] = t1v + t1v / cf;
  }
}

// ---------------- head MLP ----------------
__global__ __launch_bounds__(128) void k_head(const float* __restrict__ emb1,
    const float* __restrict__ emb2, const float* __restrict__ d1, const float* __restrict__ d2,
    const float* __restrict__ Wf1, const float* __restrict__ bf1,
    const float* __restrict__ Wf2, const float* __restrict__ bf2,
    const float* __restrict__ Wo, const float* __restrict__ bo, float* __restrict__ out) {
  int g = blockIdx.x, t = threadIdx.x;
  __shared__ float v[138], h1s[128], h2s[64];
  if (t < 64) v[t] = emb1[g * 64 + t];
  else v[t] = emb2[g * 64 + (t - 64)];
  if (t < 5) v[128 + t] = d1[g * 5 + t];
  else if (t < 10) v[133 + (t - 5)] = d2[g * 5 + (t - 5)];
  __syncthreads();
  float a = bf1[t];
  for (int k = 0; k < 138; ++k) a = fmaf(v[k], Wf1[k * 128 + t], a);
  h1s[t] = fmaxf(a, 0.f);
  __syncthreads();
  if (t < 64) {
    float a2 = bf2[t];
    #pragma unroll 8
    for (int k = 0; k < 128; ++k) a2 = fmaf(h1s[k], Wf2[k * 64 + t], a2);
    h2s[t] = fmaxf(a2, 0.f);
  }
  __syncthreads();
  if (t == 0) {
    float s = bo[0];
    for (int k = 0; k < 64; ++k) s += h2s[k] * Wo[k];
    out[g] = s;
  }
}

extern "C" void kernel_launch(void* const* d_in, const int* in_sizes, int n_in,
                              void* d_out, int out_size, void* d_ws, size_t ws_size,
                              hipStream_t stream) {
  const float* x1     = (const float*)d_in[0];
  const int*   ei1    = (const int*)d_in[1];
  const int*   batch1 = (const int*)d_in[2];
  const float* x2     = (const float*)d_in[3];
  const int*   ei2    = (const int*)d_in[4];
  const int*   batch2 = (const int*)d_in[5];
  const float* d1     = (const float*)d_in[6];
  const float* d2     = (const float*)d_in[7];
  const float* W1  = (const float*)d_in[8],  *b1  = (const float*)d_in[9];
  const float* W2  = (const float*)d_in[10], *b2  = (const float*)d_in[11];
  const float* ln1w = (const float*)d_in[12], *ln1b = (const float*)d_in[13];
  const float* W3  = (const float*)d_in[14], *b3  = (const float*)d_in[15];
  const float* W4  = (const float*)d_in[16], *b4  = (const float*)d_in[17];
  const float* ln2w = (const float*)d_in[18], *ln2b = (const float*)d_in[19];
  const float* Wf1 = (const float*)d_in[20], *bf1 = (const float*)d_in[21];
  const float* Wf2 = (const float*)d_in[22], *bf2 = (const float*)d_in[23];
  const float* Wo  = (const float*)d_in[24], *bo  = (const float*)d_in[25];
  float* out = (float*)d_out;

  const int N = in_sizes[0] / FIN;
  const int G = in_sizes[6] / 5;
  const int E1 = in_sizes[1] / 2;
  const int E2 = in_sizes[4] / 2;
  const int N2 = 2 * N;
  const int Etot = E1 + E2;
  const int NBUK = (N2 + 1023) >> 10;   // <= 512 (requires 2N <= 524288)

  char* p = (char*)d_ws;
  auto alloc = [&](size_t bytes) { void* r = p; p += (bytes + 255) & ~(size_t)255; return r; };
  int*      off    = (int*)alloc((size_t)(N2 + 1) * 4);
  int*      ecur   = (int*)alloc(512 * 4);
  int*      ebase  = (int*)alloc(513 * 4);
  int*      csr    = (int*)alloc((size_t)Etot * 4);
  int*      gstart = (int*)alloc((size_t)(2 * G + 1) * 4);
  uint4*    wfrag  = (uint4*)alloc(3 * 512 * 16);
  ushort_t* bufA   = (ushort_t*)alloc((size_t)N2 * 64 * 2);  // hr -> (in-place LN) hb -> zb
  ushort_t* bufB   = (ushort_t*)alloc((size_t)N2 * 64 * 2);  // xb+ebuf -> aggb
  float*    emb    = (float*)alloc((size_t)2 * G * 64 * 4);

  unsigned* xb   = (unsigned*)bufB;                                  // N2*16 B = first 8 MB
  unsigned* ebuf = (unsigned*)((char*)bufB + (size_t)N2 * 16);       // CAP*NBUK*4 <= 42 MB
  ushort_t* hr   = bufA;
  ushort_t* aggb = bufB;
  ushort_t* zb   = bufA;

  const uint4* wf2 = wfrag;
  const uint4* wf3 = wfrag + 512;
  const uint4* wf4 = wfrag + 1024;

  const int SCAT   = (E1 + TILE - 1) / TILE + (E2 + TILE - 1) / TILE;
  const int GRID_F = (N2 + 31) / 32;
  const int GRID_W = (N2 + 3) / 4;
  const int GRID_P = (N2 * 4 + 255) / 256;

  k_wpack<<<6, 256, 0, stream>>>(W2, W3, W4, wfrag);
  k_binit<<<1, 512, 0, stream>>>(ecur, off, NBUK, N2, Etot);
  k_bscatter<<<SCAT, 512, 0, stream>>>(ei1, ei1 + E1, E1, ei2, ei2 + E2, E2, ecur, ebuf, N, NBUK);
  k_bscan2<<<1, 512, 0, stream>>>(ecur, ebase, NBUK);
  k_bcsr<<<NBUK, 256, 0, stream>>>(ebuf, ecur, ebase, off, csr, N2);
  k_prep<<<GRID_P, 256, 0, stream>>>(x1, x2, batch1, batch2, xb, gstart, N, G);

  k_gin1f<<<GRID_F, 256, 0, stream>>>((const uint4*)xb, off, csr, W1, b1, wf2, b2, hr, N2);
  k_ln1<<<2 * G, 256, 0, stream>>>(hr, gstart, ln1w, ln1b);
  k_agg64<<<GRID_W, 256, 0, stream>>>(hr, off, csr, aggb, N2);
  k_mlp2_mfma<<<2048, 256, 0, stream>>>(aggb, wf3, b3, wf4, b4, zb, N2);
  k_ln2pool<<<2 * G, 256, 0, stream>>>(zb, gstart, ln2w, ln2b, emb);

  k_head<<<G, 128, 0, stream>>>(emb, emb + (size_t)G * 64, d1, d2, Wf1, bf1, Wf2, bf2, Wo, bo, out);
}

// Round 8
// 553.807 us; speedup vs baseline: 4.5991x; 1.0035x over previous
//
#include <hip/hip_runtime.h>

typedef unsigned short ushort_t;
typedef __attribute__((ext_vector_type(8))) short bf16x8;
typedef __attribute__((ext_vector_type(4))) float f32x4;

#define FIN 6
#define CAP 20480      // per-bucket edge capacity (mean 16384 at E=8M, 489 buckets)
#define LNCAP 384      // max nodes/graph staged in LDS

__device__ __forceinline__ float blo(unsigned u) { return __uint_as_float(u << 16); }
__device__ __forceinline__ float bhi(unsigned u) { return __uint_as_float(u & 0xffff0000u); }
__device__ __forceinline__ ushort_t f2b(float f) {
  unsigned u = __float_as_uint(f);
  unsigned r = (u + 0x7fffu + ((u >> 16) & 1u)) >> 16;
  return (ushort_t)r;
}
__device__ __forceinline__ unsigned pk2(float lo, float hi) {
  return ((unsigned)f2b(hi) << 16) | (unsigned)f2b(lo);
}
union U4F { uint4 u; bf16x8 v; };
__device__ __forceinline__ bf16x8 asfrag(uint4 u) { U4F x; x.u = u; return x.v; }

// XCD-aware block swizzle: grid B (multiple of 8). XCDs 0-3 -> first half of
// work (graph1), XCDs 4-7 -> second half (graph2). blockIdx%8 is the XCD.
__device__ __forceinline__ int xcd_swz(int b, int B) {
  int xcd = b & 7, sub = b >> 3;
  int bpx = B >> 3;
  return (xcd >> 2) * (B >> 1) + (xcd & 3) * bpx + sub;
}

// ================= bucketed CSR build (both graphs, node ids offset) =================
#define EPT 16
#define TILE 8192      // 512 threads * EPT

// wpack (blocks 0-5) + binit (block 6)
__global__ __launch_bounds__(256) void k_wpack(const float* __restrict__ W2,
    const float* __restrict__ W3, const float* __restrict__ W4, uint4* __restrict__ wfrag,
    int* __restrict__ ecur, int* __restrict__ off, int nbuk, int N2, int Etot) {
  if (blockIdx.x == 6) {
    int t = threadIdx.x;
    if (t < nbuk) ecur[t] = t * CAP;
    if (t + 256 < nbuk) ecur[t + 256] = (t + 256) * CAP;
    if (t == 0) off[N2] = Etot;
    return;
  }
  int idx = blockIdx.x * 256 + threadIdx.x;
  if (idx >= 3 * 512) return;
  int widx = idx >> 9, rem = idx & 511;
  int mt = rem >> 7, kh = (rem >> 6) & 1, l = rem & 63;
  int g = l >> 4, c = l & 15;
  const float* W = (widx == 0) ? W2 : (widx == 1) ? W3 : W4;
  int k0 = kh * 32 + g * 8;
  int col = mt * 16 + c;
  uint4 v;
  v.x = pk2(W[(k0 + 0) * 64 + col], W[(k0 + 1) * 64 + col]);
  v.y = pk2(W[(k0 + 2) * 64 + col], W[(k0 + 3) * 64 + col]);
  v.z = pk2(W[(k0 + 4) * 64 + col], W[(k0 + 5) * 64 + col]);
  v.w = pk2(W[(k0 + 6) * 64 + col], W[(k0 + 7) * 64 + col]);
  wfrag[idx] = v;
}

__global__ __launch_bounds__(512) void k_bscatter(
    const int* __restrict__ src1, const int* __restrict__ dst1, int E1,
    const int* __restrict__ src2, const int* __restrict__ dst2, int E2,
    int* __restrict__ ecur, unsigned* __restrict__ ebuf, int N, int nbuk) {
  __shared__ int cnt[512];
  __shared__ int gbase[512];
  int t = threadIdx.x;
  cnt[t] = 0;
  __syncthreads();
  int tile = blockIdx.x;
  int T1 = (E1 + TILE - 1) / TILE;
  const int* srcp; const int* dstp; int Elim, ofs, base;
  if (tile < T1) { srcp = src1; dstp = dst1; Elim = E1; ofs = 0; base = tile * TILE; }
  else { srcp = src2; dstp = dst2; Elim = E2; ofs = N; base = (tile - T1) * TILE; }
  unsigned pk[EPT];   // bucket(9) | rank<<9
  unsigned pv[EPT];   // dstLocal(10)<<19 | src(19)
  #pragma unroll
  for (int k = 0; k < EPT; ++k) {
    int e = base + k * 512 + t;
    if (e < Elim) {
      int d = dstp[e] + ofs;
      int b = d >> 10;
      int r = atomicAdd(&cnt[b], 1);
      pk[k] = (unsigned)b | ((unsigned)r << 9);
      pv[k] = ((unsigned)(d & 1023) << 19) | (unsigned)(srcp[e] + ofs);
    } else {
      pk[k] = 0xFFFFFFFFu;
    }
  }
  __syncthreads();
  if (t < nbuk && cnt[t] > 0) gbase[t] = atomicAdd(&ecur[t], cnt[t]);
  __syncthreads();
  #pragma unroll
  for (int k = 0; k < EPT; ++k) {
    if (pk[k] != 0xFFFFFFFFu) {
      int b = pk[k] & 511;
      int r = pk[k] >> 9;
      ebuf[gbase[b] + r] = pv[k];
    }
  }
}

__global__ __launch_bounds__(512) void k_bscan2(const int* __restrict__ ecur,
    int* __restrict__ ebase, int nbuk) {
  __shared__ int lds[512];
  int t = threadIdx.x;
  int s = (t < nbuk) ? (ecur[t] - t * CAP) : 0;
  lds[t] = s; __syncthreads();
  int acc = s;
  for (int o = 1; o < 512; o <<= 1) {
    int add = (t >= o) ? lds[t - o] : 0;
    __syncthreads();
    acc += add; lds[t] = acc;
    __syncthreads();
  }
  if (t < nbuk) ebase[t] = acc - s;
}

__global__ __launch_bounds__(256) void k_bcsr(const unsigned* __restrict__ ebuf,
    const int* __restrict__ ecur, const int* __restrict__ ebase,
    int* __restrict__ off, int* __restrict__ csr, int N2) {
  __shared__ int hist[1024];
  __shared__ int lofs[1024];
  __shared__ int sc[256];
  int b = blockIdx.x, t = threadIdx.x;
  int nb0 = b << 10;
  int bn = N2 - nb0; if (bn > 1024) bn = 1024;
  int s_beg = b * CAP, s_end = ecur[b];
  int base = ebase[b];
  #pragma unroll
  for (int k = 0; k < 4; ++k) hist[t * 4 + k] = 0;
  __syncthreads();
  for (int e = s_beg + t; e < s_end; e += 256) atomicAdd(&hist[ebuf[e] >> 19], 1);
  __syncthreads();
  int h0 = hist[t * 4 + 0], h1 = hist[t * 4 + 1], h2 = hist[t * 4 + 2], h3 = hist[t * 4 + 3];
  int s = h0 + h1 + h2 + h3;
  sc[t] = s; __syncthreads();
  int acc = s;
  for (int o = 1; o < 256; o <<= 1) {
    int add = (t >= o) ? sc[t - o] : 0;
    __syncthreads();
    acc += add; sc[t] = acc;
    __syncthreads();
  }
  int run = acc - s;
  lofs[t * 4 + 0] = run; run += h0;
  lofs[t * 4 + 1] = run; run += h1;
  lofs[t * 4 + 2] = run; run += h2;
  lofs[t * 4 + 3] = run;
  __syncthreads();
  #pragma unroll
  for (int k = 0; k < 4; ++k) {
    int j = t * 4 + k;
    if (j < bn) off[nb0 + j] = base + lofs[j];
  }
  __syncthreads();
  for (int e = s_beg + t; e < s_end; e += 256) {
    unsigned p = ebuf[e];
    int r = atomicAdd(&lofs[p >> 19], 1);
    csr[base + r] = (int)(p & 0x7FFFFu);
  }
}

// ---------------- prep: xpack both graphs + combined graph bounds ----------------
__global__ void k_prep(const float* __restrict__ x1, const float* __restrict__ x2,
                       const int* __restrict__ batch1, const int* __restrict__ batch2,
                       unsigned* __restrict__ xb, int* __restrict__ gstart,
                       int N, int G) {
  int N2 = 2 * N, G2 = 2 * G;
  int tt = blockIdx.x * 256 + threadIdx.x;
  if (tt < N2 * 4) {
    int i = tt >> 2, k = tt & 3;
    unsigned v = 0;
    if (k < 3) {
      const float* xp = (i < N) ? (x1 + (size_t)i * 6) : (x2 + (size_t)(i - N) * 6);
      float2 f = *(const float2*)(xp + k * 2);
      v = pk2(f.x, f.y);
    }
    xb[tt] = v;
  }
  if (tt < N2) {
    int i = tt;
    int b = (i < N) ? batch1[i] : (batch2[i - N] + G);
    if (i == 0) { for (int g = 0; g <= b; ++g) gstart[g] = 0; }
    else {
      int pb = (i - 1 < N) ? batch1[i - 1] : (batch2[i - 1 - N] + G);
      for (int g = pb + 1; g <= b; ++g) gstart[g] = i;
    }
    if (i == N2 - 1) { for (int g = b + 1; g <= G2; ++g) gstart[g] = N2; }
  }
}

// ---------------- GIN1 fused: gather x + Linear(6->64) + relu + MFMA Linear(64->64) ----------------
#define ACC6(u) { a0 += blo(u.x); a1 += bhi(u.x); a2 += blo(u.y); a3 += bhi(u.y); a4 += blo(u.z); a5 += bhi(u.z); }
__global__ __launch_bounds__(256) void k_gin1f(const uint4* __restrict__ xb4,
    const int* __restrict__ off, const int* __restrict__ csr,
    const float* __restrict__ W1, const float* __restrict__ b1,
    const uint4* __restrict__ wf2, const float* __restrict__ b2,
    ushort_t* __restrict__ hr, int n) {
  __shared__ __align__(16) ushort_t t1s[32][72];
  __shared__ float sh[4][8][FIN];
  int t = threadIdx.x, w = t >> 6, lane = t & 63;
  int nd = lane >> 3, sl = lane & 7;
  int blk = xcd_swz(blockIdx.x, gridDim.x);
  int nb0 = blk * 32;
  int i = nb0 + w * 8 + nd;

  float w1r[FIN];
  #pragma unroll
  for (int k = 0; k < FIN; ++k) w1r[k] = W1[k * 64 + lane];
  float bb1 = b1[lane];

  float a0 = 0, a1 = 0, a2 = 0, a3 = 0, a4 = 0, a5 = 0;
  if (i < n) {
    int e0 = off[i], e1 = off[i + 1];
    int e = e0 + sl;
    for (; e + 8 < e1; e += 16) {
      uint4 u = xb4[csr[e]];
      uint4 v = xb4[csr[e + 8]];
      ACC6(u); ACC6(v);
    }
    if (e < e1) { uint4 u = xb4[csr[e]]; ACC6(u); }
    if (sl == 0) { uint4 u = xb4[i]; ACC6(u); }
  }
  #pragma unroll
  for (int m = 1; m < 8; m <<= 1) {
    a0 += __shfl_xor(a0, m); a1 += __shfl_xor(a1, m); a2 += __shfl_xor(a2, m);
    a3 += __shfl_xor(a3, m); a4 += __shfl_xor(a4, m); a5 += __shfl_xor(a5, m);
  }
  if (sl < FIN) {
    float v = (sl == 0) ? a0 : (sl == 1) ? a1 : (sl == 2) ? a2 : (sl == 3) ? a3 : (sl == 4) ? a4 : a5;
    sh[w][nd][sl] = v;
  }
  #pragma unroll
  for (int nd2 = 0; nd2 < 8; ++nd2) {
    float h = bb1;
    #pragma unroll
    for (int k = 0; k < FIN; ++k) h = fmaf(sh[w][nd2][k], w1r[k], h);
    t1s[w * 8 + nd2][lane] = f2b(fmaxf(h, 0.f));
  }
  __syncthreads();
  if (w < 2) {
    int g = lane >> 4, c = lane & 15;
    bf16x8 af[4][2];
    #pragma unroll
    for (int mt = 0; mt < 4; ++mt)
      #pragma unroll
      for (int kh = 0; kh < 2; ++kh) af[mt][kh] = asfrag(wf2[(mt * 2 + kh) * 64 + lane]);
    int r0 = w * 16 + c;
    bf16x8 bf0 = asfrag(*(const uint4*)&t1s[r0][8 * g]);
    bf16x8 bf1 = asfrag(*(const uint4*)&t1s[r0][8 * g + 32]);
    f32x4 acc[4];
    #pragma unroll
    for (int mt = 0; mt < 4; ++mt) {
      acc[mt] = (f32x4){b2[mt * 16 + 4 * g + 0], b2[mt * 16 + 4 * g + 1],
                        b2[mt * 16 + 4 * g + 2], b2[mt * 16 + 4 * g + 3]};
      acc[mt] = __builtin_amdgcn_mfma_f32_16x16x32_bf16(af[mt][0], bf0, acc[mt], 0, 0, 0);
      acc[mt] = __builtin_amdgcn_mfma_f32_16x16x32_bf16(af[mt][1], bf1, acc[mt], 0, 0, 0);
    }
    #pragma unroll
    for (int mt = 0; mt < 4; ++mt) {
      uint2 pv;
      pv.x = pk2(acc[mt][0], acc[mt][1]);
      pv.y = pk2(acc[mt][2], acc[mt][3]);
      *(uint2*)&t1s[r0][mt * 16 + 4 * g] = pv;
    }
    int n2 = lane >> 2, ch = (lane & 3) * 16;
    uint4 s0 = *(const uint4*)&t1s[w * 16 + n2][ch];
    uint4 s1 = *(const uint4*)&t1s[w * 16 + n2][ch + 8];
    int orow = nb0 + w * 16 + n2;
    if (orow < n) {
      uint4* op = (uint4*)(hr + (size_t)orow * 64);
      op[(lane & 3) * 2] = s0;
      op[(lane & 3) * 2 + 1] = s1;
    }
  }
}

// ---------------- k_agg64: float2 packed accumulation + XCD swizzle ----------------
__device__ __forceinline__ float2 up2(unsigned v) { return make_float2(blo(v), bhi(v)); }
#define PACC(u) { float2 q0 = up2(u.x), q1 = up2(u.y), q2 = up2(u.z), q3 = up2(u.w); \
                  c0.x += q0.x; c0.y += q0.y; c1.x += q1.x; c1.y += q1.y; \
                  c2.x += q2.x; c2.y += q2.y; c3.x += q3.x; c3.y += q3.y; }
__global__ __launch_bounds__(256) void k_agg64(const ushort_t* __restrict__ hb,
    const int* __restrict__ off, const int* __restrict__ csr,
    ushort_t* __restrict__ aggb, int n) {
  int t = threadIdx.x, w = t >> 6, lane = t & 63;
  int blk = xcd_swz(blockIdx.x, gridDim.x);
  int i = blk * 4 + w;
  if (i >= n) return;
  int grp = lane >> 3, sl = lane & 7;
  int e0 = off[i], e1 = off[i + 1];
  const uint4* hb4 = (const uint4*)hb;
  float2 c0 = {0, 0}, c1 = {0, 0}, c2 = {0, 0}, c3 = {0, 0};
  int e = e0 + grp;
  for (; e + 8 < e1; e += 16) {
    int sa = csr[e], sb = csr[e + 8];
    uint4 ua = hb4[(size_t)sa * 8 + sl];
    uint4 ub = hb4[(size_t)sb * 8 + sl];
    PACC(ua); PACC(ub);
  }
  if (e < e1) {
    int sa = csr[e];
    uint4 ua = hb4[(size_t)sa * 8 + sl];
    PACC(ua);
  }
  #pragma unroll
  for (int m = 8; m < 64; m <<= 1) {
    c0.x += __shfl_xor(c0.x, m); c0.y += __shfl_xor(c0.y, m);
    c1.x += __shfl_xor(c1.x, m); c1.y += __shfl_xor(c1.y, m);
    c2.x += __shfl_xor(c2.x, m); c2.y += __shfl_xor(c2.y, m);
    c3.x += __shfl_xor(c3.x, m); c3.y += __shfl_xor(c3.y, m);
  }
  if (grp == 0) {
    uint4 us = hb4[(size_t)i * 8 + sl];
    PACC(us);
    uint4 o;
    o.x = pk2(c0.x, c0.y); o.y = pk2(c1.x, c1.y);
    o.z = pk2(c2.x, c2.y); o.w = pk2(c3.x, c3.y);
    ((uint4*)aggb)[(size_t)i * 8 + sl] = o;
  }
}

// ---------------- k_mlp2_mfma ----------------
__global__ __launch_bounds__(256) void k_mlp2_mfma(const ushort_t* __restrict__ aggb,
    const uint4* __restrict__ wf3, const float* __restrict__ b3,
    const uint4* __restrict__ wf4, const float* __restrict__ b4,
    ushort_t* __restrict__ zb, int n) {
  __shared__ __align__(16) ushort_t lds[4][16][72];
  int t = threadIdx.x, w = t >> 6, l = t & 63;
  int g = l >> 4, c = l & 15;
  bf16x8 a3[4][2], a4[4][2];
  #pragma unroll
  for (int mt = 0; mt < 4; ++mt)
    #pragma unroll
    for (int kh = 0; kh < 2; ++kh) {
      a3[mt][kh] = asfrag(wf3[(mt * 2 + kh) * 64 + l]);
      a4[mt][kh] = asfrag(wf4[(mt * 2 + kh) * 64 + l]);
    }
  float bs3[4][4], bs4[4][4];
  #pragma unroll
  for (int mt = 0; mt < 4; ++mt)
    #pragma unroll
    for (int r = 0; r < 4; ++r) {
      bs3[mt][r] = b3[mt * 16 + 4 * g + r];
      bs4[mt][r] = b4[mt * 16 + 4 * g + r];
    }
  int ntile = (n + 15) >> 4;
  for (int tau = blockIdx.x * 4 + w; tau < ntile; tau += gridDim.x * 4) {
    int nb = tau << 4;
    int row = nb + c; if (row >= n) row = n - 1;
    const uint4* rp = (const uint4*)(aggb + (size_t)row * 64);
    bf16x8 bf0 = asfrag(rp[g]);
    bf16x8 bf1 = asfrag(rp[g + 4]);
    f32x4 acc[4];
    #pragma unroll
    for (int mt = 0; mt < 4; ++mt) {
      acc[mt] = (f32x4){bs3[mt][0], bs3[mt][1], bs3[mt][2], bs3[mt][3]};
      acc[mt] = __builtin_amdgcn_mfma_f32_16x16x32_bf16(a3[mt][0], bf0, acc[mt], 0, 0, 0);
      acc[mt] = __builtin_amdgcn_mfma_f32_16x16x32_bf16(a3[mt][1], bf1, acc[mt], 0, 0, 0);
    }
    #pragma unroll
    for (int mt = 0; mt < 4; ++mt) {
      uint2 pv;
      pv.x = pk2(fmaxf(acc[mt][0], 0.f), fmaxf(acc[mt][1], 0.f));
      pv.y = pk2(fmaxf(acc[mt][2], 0.f), fmaxf(acc[mt][3], 0.f));
      *(uint2*)&lds[w][c][mt * 16 + 4 * g] = pv;
    }
    bf16x8 h0 = asfrag(*(const uint4*)&lds[w][c][8 * g]);
    bf16x8 h1 = asfrag(*(const uint4*)&lds[w][c][8 * g + 32]);
    f32x4 ac2[4];
    #pragma unroll
    for (int mt = 0; mt < 4; ++mt) {
      ac2[mt] = (f32x4){bs4[mt][0], bs4[mt][1], bs4[mt][2], bs4[mt][3]};
      ac2[mt] = __builtin_amdgcn_mfma_f32_16x16x32_bf16(a4[mt][0], h0, ac2[mt], 0, 0, 0);
      ac2[mt] = __builtin_amdgcn_mfma_f32_16x16x32_bf16(a4[mt][1], h1, ac2[mt], 0, 0, 0);
    }
    #pragma unroll
    for (int mt = 0; mt < 4; ++mt) {
      uint2 pv;
      pv.x = pk2(ac2[mt][0], ac2[mt][1]);
      pv.y = pk2(ac2[mt][2], ac2[mt][3]);
      *(uint2*)&lds[w][c][mt * 16 + 4 * g] = pv;
    }
    int n2 = l >> 2, ch = (l & 3) * 16;
    uint4 s0 = *(const uint4*)&lds[w][n2][ch];
    uint4 s1 = *(const uint4*)&lds[w][n2][ch + 8];
    int orow = nb + n2;
    if (orow < n) {
      uint4* op = (uint4*)(zb + (size_t)orow * 64);
      op[(l & 3) * 2] = s0;
      op[(l & 3) * 2 + 1] = s1;
    }
  }
}

// ---------------- LN1 fused: stats + apply + relu (block per graph, in-place) ----------------
__global__ __launch_bounds__(256) void k_ln1(ushort_t* __restrict__ hr,
    const int* __restrict__ gstart, const float* __restrict__ w, const float* __restrict__ bb) {
  __shared__ uint4 st[LNCAP * 8];
  __shared__ float l1[256], l2[256];
  __shared__ float mm[2];
  int g = blockIdx.x, t = threadIdx.x;
  int s0 = gstart[g], s1 = gstart[g + 1], cnt = s1 - s0;
  uint4* src = (uint4*)hr + (size_t)s0 * 8;
  int nch = cnt * 8;
  bool fit = cnt <= LNCAP;
  float s = 0.f, ss = 0.f;
  for (int j = t; j < nch; j += 256) {
    uint4 u = src[j];
    if (fit) st[j] = u;
    float v0 = blo(u.x), v1 = bhi(u.x), v2 = blo(u.y), v3 = bhi(u.y);
    float v4 = blo(u.z), v5 = bhi(u.z), v6 = blo(u.w), v7 = bhi(u.w);
    s += ((v0 + v1) + (v2 + v3)) + ((v4 + v5) + (v6 + v7));
    ss += ((v0 * v0 + v1 * v1) + (v2 * v2 + v3 * v3)) + ((v4 * v4 + v5 * v5) + (v6 * v6 + v7 * v7));
  }
  l1[t] = s; l2[t] = ss;
  __syncthreads();
  for (int o = 128; o > 0; o >>= 1) {
    if (t < o) { l1[t] += l1[t + o]; l2[t] += l2[t + o]; }
    __syncthreads();
  }
  if (t == 0) {
    float cf = (float)cnt;
    float norm = fmaxf(cf, 1.f) * 64.f;
    float mean = l1[0] / norm;
    float var = fmaxf(l2[0] / norm - mean * mean, 0.f);
    mm[0] = mean; mm[1] = rsqrtf(var + 1e-5f);
  }
  __syncthreads();
  float mean = mm[0], inv = mm[1];
  for (int j = t; j < nch; j += 256) {
    uint4 u = fit ? st[j] : src[j];
    int q = j & 7;
    float4 w0 = *(const float4*)(w + q * 8);
    float4 w1 = *(const float4*)(w + q * 8 + 4);
    float4 c0 = *(const float4*)(bb + q * 8);
    float4 c1 = *(const float4*)(bb + q * 8 + 4);
    uint4 o;
    o.x = pk2(fmaxf((blo(u.x) - mean) * inv * w0.x + c0.x, 0.f),
              fmaxf((bhi(u.x) - mean) * inv * w0.y + c0.y, 0.f));
    o.y = pk2(fmaxf((blo(u.y) - mean) * inv * w0.z + c0.z, 0.f),
              fmaxf((bhi(u.y) - mean) * inv * w0.w + c0.w, 0.f));
    o.z = pk2(fmaxf((blo(u.z) - mean) * inv * w1.x + c1.x, 0.f),
              fmaxf((bhi(u.z) - mean) * inv * w1.y + c1.y, 0.f));
    o.w = pk2(fmaxf((blo(u.w) - mean) * inv * w1.z + c1.z, 0.f),
              fmaxf((bhi(u.w) - mean) * inv * w1.w + c1.w, 0.f));
    src[j] = o;
  }
}

// ---------------- LN2 + pool fused ----------------
__global__ __launch_bounds__(256) void k_ln2pool(const ushort_t* __restrict__ zb,
    const int* __restrict__ gstart, const float* __restrict__ w, const float* __restrict__ bb,
    float* __restrict__ emb) {
  __shared__ unsigned st[LNCAP * 32];
  __shared__ float l1[256], l2[256];
  __shared__ float mm[2];
  int g = blockIdx.x, t = threadIdx.x;
  int s0 = gstart[g], s1 = gstart[g + 1], cnt = s1 - s0;
  const unsigned* src = (const unsigned*)zb + (size_t)s0 * 32;
  int nu = cnt * 32;
  bool fit = cnt <= LNCAP;
  float s = 0.f, ss = 0.f;
  for (int j = t; j < nu; j += 256) {
    unsigned u = src[j];
    if (fit) st[j] = u;
    float v0 = blo(u), v1 = bhi(u);
    s += v0 + v1;
    ss += v0 * v0 + v1 * v1;
  }
  l1[t] = s; l2[t] = ss;
  __syncthreads();
  for (int o = 128; o > 0; o >>= 1) {
    if (t < o) { l1[t] += l1[t + o]; l2[t] += l2[t + o]; }
    __syncthreads();
  }
  if (t == 0) {
    float cf = (float)cnt;
    float norm = fmaxf(cf, 1.f) * 64.f;
    float mean = l1[0] / norm;
    float var = fmaxf(l2[0] / norm - mean * mean, 0.f);
    mm[0] = mean; mm[1] = rsqrtf(var + 1e-5f);
  }
  __syncthreads();
  float mean = mm[0], inv = mm[1];
  int c2 = t & 31, sub = t >> 5;
  float w0 = w[c2 * 2], w1 = w[c2 * 2 + 1], b0 = bb[c2 * 2], b1v = bb[c2 * 2 + 1];
  float acc0 = 0.f, acc1 = 0.f;
  for (int i = sub; i < cnt; i += 8) {
    unsigned u = fit ? st[i * 32 + c2] : src[(size_t)i * 32 + c2];
    acc0 += fmaxf((blo(u) - mean) * inv * w0 + b0, 0.f);
    acc1 += fmaxf((bhi(u) - mean) * inv * w1 + b1v, 0.f);
  }
  __syncthreads();
  l1[t] = acc0; l2[t] = acc1;
  __syncthreads();
  if (sub == 0) {
    float t0 = 0.f, t1v = 0.f;
    #pragma unroll
    for (int sx = 0; sx < 8; ++sx) { t0 += l1[sx * 32 + c2]; t1v += l2[sx * 32 + c2]; }
    float cf = fmaxf((float)cnt, 1.f);
    emb[g * 64 + c2 * 2]     = t0 + t0 / cf;
    emb[g * 64 + c2 * 2 + 1] = t1v + t1v / cf;
  }
}

// ---------------- head MLP ----------------
__global__ __launch_bounds__(128) void k_head(const float* __restrict__ emb1,
    const float* __restrict__ emb2, const float* __restrict__ d1, const float* __restrict__ d2,
    const float* __restrict__ Wf1, const float* __restrict__ bf1,
    const float* __restrict__ Wf2, const float* __restrict__ bf2,
    const float* __restrict__ Wo, const float* __restrict__ bo, float* __restrict__ out) {
  int g = blockIdx.x, t = threadIdx.x;
  __shared__ float v[138], h1s[128], h2s[64];
  if (t < 64) v[t] = emb1[g * 64 + t];
  else v[t] = emb2[g * 64 + (t - 64)];
  if (t < 5) v[128 + t] = d1[g * 5 + t];
  else if (t < 10) v[133 + (t - 5)] = d2[g * 5 + (t - 5)];
  __syncthreads();
  float a = bf1[t];
  for (int k = 0; k < 138; ++k) a = fmaf(v[k], Wf1[k * 128 + t], a);
  h1s[t] = fmaxf(a, 0.f);
  __syncthreads();
  if (t < 64) {
    float a2 = bf2[t];
    #pragma unroll 8
    for (int k = 0; k < 128; ++k) a2 = fmaf(h1s[k], Wf2[k * 64 + t], a2);
    h2s[t] = fmaxf(a2, 0.f);
  }
  __syncthreads();
  if (t == 0) {
    float s = bo[0];
    for (int k = 0; k < 64; ++k) s += h2s[k] * Wo[k];
    out[g] = s;
  }
}

extern "C" void kernel_launch(void* const* d_in, const int* in_sizes, int n_in,
                              void* d_out, int out_size, void* d_ws, size_t ws_size,
                              hipStream_t stream) {
  const float* x1     = (const float*)d_in[0];
  const int*   ei1    = (const int*)d_in[1];
  const int*   batch1 = (const int*)d_in[2];
  const float* x2     = (const float*)d_in[3];
  const int*   ei2    = (const int*)d_in[4];
  const int*   batch2 = (const int*)d_in[5];
  const float* d1     = (const float*)d_in[6];
  const float* d2     = (const float*)d_in[7];
  const float* W1  = (const float*)d_in[8],  *b1  = (const float*)d_in[9];
  const float* W2  = (const float*)d_in[10], *b2  = (const float*)d_in[11];
  const float* ln1w = (const float*)d_in[12], *ln1b = (const float*)d_in[13];
  const float* W3  = (const float*)d_in[14], *b3  = (const float*)d_in[15];
  const float* W4  = (const float*)d_in[16], *b4  = (const float*)d_in[17];
  const float* ln2w = (const float*)d_in[18], *ln2b = (const float*)d_in[19];
  const float* Wf1 = (const float*)d_in[20], *bf1 = (const float*)d_in[21];
  const float* Wf2 = (const float*)d_in[22], *bf2 = (const float*)d_in[23];
  const float* Wo  = (const float*)d_in[24], *bo  = (const float*)d_in[25];
  float* out = (float*)d_out;

  const int N = in_sizes[0] / FIN;
  const int G = in_sizes[6] / 5;
  const int E1 = in_sizes[1] / 2;
  const int E2 = in_sizes[4] / 2;
  const int N2 = 2 * N;
  const int Etot = E1 + E2;
  const int NBUK = (N2 + 1023) >> 10;   // <= 512 (requires 2N <= 524288)

  char* p = (char*)d_ws;
  auto alloc = [&](size_t bytes) { void* r = p; p += (bytes + 255) & ~(size_t)255; return r; };
  int*      off    = (int*)alloc((size_t)(N2 + 1) * 4);
  int*      ecur   = (int*)alloc(512 * 4);
  int*      ebase  = (int*)alloc(513 * 4);
  int*      csr    = (int*)alloc((size_t)Etot * 4);
  int*      gstart = (int*)alloc((size_t)(2 * G + 1) * 4);
  uint4*    wfrag  = (uint4*)alloc(3 * 512 * 16);
  ushort_t* bufA   = (ushort_t*)alloc((size_t)N2 * 64 * 2);  // hr -> (in-place LN) -> zb
  ushort_t* bufB   = (ushort_t*)alloc((size_t)N2 * 64 * 2);  // xb+ebuf -> aggb
  float*    emb    = (float*)alloc((size_t)2 * G * 64 * 4);

  unsigned* xb   = (unsigned*)bufB;
  unsigned* ebuf = (unsigned*)((char*)bufB + (size_t)N2 * 16);
  ushort_t* hr   = bufA;
  ushort_t* aggb = bufB;
  ushort_t* zb   = bufA;

  const uint4* wf2 = wfrag;
  const uint4* wf3 = wfrag + 512;
  const uint4* wf4 = wfrag + 1024;

  const int SCAT   = (E1 + TILE - 1) / TILE + (E2 + TILE - 1) / TILE;
  const int GRID_F = (((N2 + 31) / 32) + 7) & ~7;   // multiple of 8 for xcd swizzle
  const int GRID_W = (((N2 + 3) / 4) + 7) & ~7;     // multiple of 8 for xcd swizzle
  const int GRID_P = (N2 * 4 + 255) / 256;

  k_wpack<<<7, 256, 0, stream>>>(W2, W3, W4, wfrag, ecur, off, NBUK, N2, Etot);
  k_bscatter<<<SCAT, 512, 0, stream>>>(ei1, ei1 + E1, E1, ei2, ei2 + E2, E2, ecur, ebuf, N, NBUK);
  k_bscan2<<<1, 512, 0, stream>>>(ecur, ebase, NBUK);
  k_bcsr<<<NBUK, 256, 0, stream>>>(ebuf, ecur, ebase, off, csr, N2);
  k_prep<<<GRID_P, 256, 0, stream>>>(x1, x2, batch1, batch2, xb, gstart, N, G);

  k_gin1f<<<GRID_F, 256, 0, stream>>>((const uint4*)xb, off, csr, W1, b1, wf2, b2, hr, N2);
  k_ln1<<<2 * G, 256, 0, stream>>>(hr, gstart, ln1w, ln1b);
  k_agg64<<<GRID_W, 256, 0, stream>>>(hr, off, csr, aggb, N2);
  k_mlp2_mfma<<<2048, 256, 0, stream>>>(aggb, wf3, b3, wf4, b4, zb, N2);
  k_ln2pool<<<2 * G, 256, 0, stream>>>(zb, gstart, ln2w, ln2b, emb);

  k_head<<<G, 128, 0, stream>>>(emb, emb + (size_t)G * 64, d1, d2, Wf1, bf1, Wf2, bf2, Wo, bo, out);
}